// Round 3
// baseline (1271.894 us; speedup 1.0000x reference)
//
#include <hip/hip_runtime.h>
#include <hip/hip_fp16.h>

#define NN  25000
#define EE  500000
#define BB  4
#define DD  32
#define R2C 474
#define LL  4
#define BD  128      // B*D
#define THD 416      // 13*D
#define EPSF 1e-6f
#define AP  164      // padded LDS A-row (164%32=4 -> conflict-free b128)
#define WVF 13312    // floats per layer of packed W (104 kg * 16 dp * 8)

// ---------------- CSR build ----------------
__global__ __launch_bounds__(256) void hist_kernel(const int* __restrict__ node_out,
                                                   const float* __restrict__ ew,
                                                   int* __restrict__ cnt,
                                                   float* __restrict__ wdeg) {
  int e = blockIdx.x * 256 + threadIdx.x;
  if (e < EE) {
    int d = node_out[e];
    atomicAdd(&cnt[d], 1);
    atomicAdd(&wdeg[d], ew[e]);
  }
}

__global__ __launch_bounds__(1024) void scan_kernel(const int* __restrict__ cnt,
                                                    int* __restrict__ rowp,
                                                    const float* __restrict__ wdeg,
                                                    float* __restrict__ stats,
                                                    float* __restrict__ cntf) {
  __shared__ int   part[1024];
  __shared__ float fpart[1024];
  int t = threadIdx.x;
  const int per = (NN + 1023) / 1024;   // 25
  int beg = t * per, end = min(beg + per, NN);
  int s = 0; float ls = 0.f;
  for (int i = beg; i < end; ++i) { s += cnt[i]; ls += logf(wdeg[i] + 1.0f); }
  part[t] = s; fpart[t] = ls;
  __syncthreads();
  for (int off = 1; off < 1024; off <<= 1) {
    int   v  = (t >= off) ? part[t - off]  : 0;
    float fv = (t >= off) ? fpart[t - off] : 0.f;
    __syncthreads();
    part[t] += v; fpart[t] += fv;
    __syncthreads();
  }
  int run = part[t] - s;
  for (int i = beg; i < end; ++i) {
    rowp[i] = run; run += cnt[i];
    cntf[i] = (float)(cnt[i] + 1);      // indeg + self entry
  }
  if (t == 1023) { rowp[NN] = part[1023]; stats[0] = fpart[1023]; }
}

__global__ __launch_bounds__(256) void scales_kernel(const float* __restrict__ wdeg,
                                                     const float* __restrict__ stats,
                                                     float* __restrict__ scales) {
  int n = blockIdx.x * 256 + threadIdx.x;
  if (n >= NN) return;
  float mean = stats[0] / (float)NN;
  float sc = logf(wdeg[n] + 1.0f) / mean;
  scales[n * 2 + 0] = sc;
  scales[n * 2 + 1] = 1.0f / fmaxf(sc, 0.01f);
}

// pack each edge as {node_in, relation, w_bits, 0}
__global__ __launch_bounds__(256) void scatter_kernel(const int* __restrict__ node_in,
                                                      const int* __restrict__ node_out,
                                                      const int* __restrict__ relation,
                                                      const float* __restrict__ ew,
                                                      const int* __restrict__ rowp,
                                                      int* __restrict__ fill,
                                                      int4* __restrict__ ep) {
  int e = blockIdx.x * 256 + threadIdx.x;
  if (e >= EE) return;
  int dn = node_out[e];
  int pos = rowp[dn] + atomicAdd(&fill[dn], 1);
  ep[pos] = make_int4(node_in[e], relation[e], __float_as_int(ew[e]), 0);
}

// query gather + boundary placement (h0 pre-zeroed by memset; fp16 zero == 0x0000)
__global__ __launch_bounds__(128) void init_kernel(const int* __restrict__ h_index,
                                                   const int* __restrict__ r_index,
                                                   const float* __restrict__ qemb,
                                                   float* __restrict__ query,
                                                   __half* __restrict__ h0) {
  int t = threadIdx.x; int b = t >> 5, d = t & 31;
  float qv = qemb[r_index[b] * DD + d];
  query[t] = qv;
  h0[h_index[b] * BD + t] = __float2half(qv);
}

// rel_in[r][b][d] = query[b] . rel_W[l][:, r*D+d] + rel_b[l][r*D+d]   (fp16 out)
__global__ __launch_bounds__(256) void relin_kernel(const float* __restrict__ query,
                                                    const float* __restrict__ relW,
                                                    const float* __restrict__ relB,
                                                    __half* __restrict__ relIn) {
  int o = blockIdx.x * 256 + threadIdx.x;
  if (o >= R2C * BD) return;
  int r = o >> 7; int b = (o >> 5) & 3; int d = o & 31;
  int col = r * DD + d;
  float acc = relB[col];
  #pragma unroll
  for (int k = 0; k < DD; ++k)
    acc = fmaf(query[b * DD + k], relW[(size_t)k * (R2C * DD) + col], acc);
  relIn[o] = __float2half(acc);
}

// Pack all L layers of lin_W into Wv: 4 slabs (hidden, sc0, sc1, sc2), k-order
// matching the LDS A-row, as float4 records [kgs][dp][j][c] for coalesced
// global_load_dwordx4 in the epilogue.
__global__ __launch_bounds__(256) void wvbuild_kernel(const float* __restrict__ linW,
                                                      float* __restrict__ Wv) {
  int idx = blockIdx.x * 256 + threadIdx.x;
  if (idx >= LL * WVF) return;
  int l = idx / WVF, r = idx % WVF;
  int c   = r & 3;
  int j   = (r >> 2) & 1;
  int dp  = (r >> 3) & 15;
  int kgs = r >> 7;                  // 0..103
  int m, kg;
  if (kgs < 8) { m = 0; kg = kgs; }
  else { m = 1 + (kgs - 8) / 32; kg = (kgs - 8) & 31; }
  int k = kg * 4 + c;
  int wrow;
  if (m == 0) wrow = k;              // hidden part, ref rows 0..31
  else {
    int si = k >> 5, df = k & 31;    // A-row order: k = si*32+df
    wrow = DD + (df * 4 + si) * 3 + (m - 1);
  }
  int d = dp * 2 + j;
  Wv[idx] = linW[(size_t)l * THD * DD + (size_t)wrow * DD + d];
}

// Fused layer: per-wave gather-reduce (fp16 rows, 2 slots/lane) + PNA stats
// + packed-W 416->32 linear with scale-slab combine + relu -> fp16 row.
// Each wave owns 2 nodes and a private LDS A region -> no block barriers.
__global__ __launch_bounds__(256) void layer_kernel(const __half2* __restrict__ hin2,
                                                    __half2* __restrict__ hout2,
                                                    const __half2* __restrict__ rel2,
                                                    const int4* __restrict__ ep,
                                                    const int* __restrict__ rowp,
                                                    const float* __restrict__ cntf,
                                                    const float* __restrict__ scales,
                                                    const float4* __restrict__ wv4,
                                                    const float* __restrict__ bias,
                                                    const int* __restrict__ h_index,
                                                    const float* __restrict__ query) {
  __shared__ float A[4][BB * AP];
  const int tid  = threadIdx.x;
  const int wid  = tid >> 6, lane = tid & 63;
  const int b    = lane >> 4, dp = lane & 15;
  const int d0   = dp * 2;
  const int s0   = lane * 2;            // global slot b*32+d0
  float* Ab = &A[wid][b * AP];
  const float q0 = query[s0], q1 = query[s0 + 1];
  const int   hb = h_index[b];
  const float bj0 = bias[d0], bj1 = bias[d0 + 1];

  const int nbase = blockIdx.x * 8 + wid * 2;
  #pragma unroll
  for (int ni = 0; ni < 2; ++ni) {
    const int n = nbase + ni;           // NN%8==0 -> always valid
    const int beg = rowp[n], end = rowp[n + 1];
    const float mb0 = (n == hb) ? q0 : 0.f;
    const float mb1 = (n == hb) ? q1 : 0.f;
    float sa0 = mb0, qa0 = mb0 * mb0, mx0 = mb0, mn0 = mb0;
    float sa1 = mb1, qa1 = mb1 * mb1, mx1 = mb1, mn1 = mb1;
    int p = beg;
    for (; p + 4 <= end; p += 4) {
      int4 e0 = ep[p];     int4 e1 = ep[p + 1];
      int4 e2 = ep[p + 2]; int4 e3 = ep[p + 3];
      __half2 h0v = hin2[(size_t)e0.x * 64 + lane];
      __half2 r0v = rel2[(size_t)e0.y * 64 + lane];
      __half2 h1v = hin2[(size_t)e1.x * 64 + lane];
      __half2 r1v = rel2[(size_t)e1.y * 64 + lane];
      __half2 h2v = hin2[(size_t)e2.x * 64 + lane];
      __half2 r2v = rel2[(size_t)e2.y * 64 + lane];
      __half2 h3v = hin2[(size_t)e3.x * 64 + lane];
      __half2 r3v = rel2[(size_t)e3.y * 64 + lane];
      float w0 = __int_as_float(e0.z), w1 = __int_as_float(e1.z);
      float w2 = __int_as_float(e2.z), w3 = __int_as_float(e3.z);
      float2 hf, rf; float m0, m1, mw0, mw1;
      hf = __half22float2(h0v); rf = __half22float2(r0v);
      m0 = rf.x * hf.x; mw0 = m0 * w0; m1 = rf.y * hf.y; mw1 = m1 * w0;
      sa0 += mw0; qa0 = fmaf(m0, mw0, qa0); mx0 = fmaxf(mx0, mw0); mn0 = fminf(mn0, mw0);
      sa1 += mw1; qa1 = fmaf(m1, mw1, qa1); mx1 = fmaxf(mx1, mw1); mn1 = fminf(mn1, mw1);
      hf = __half22float2(h1v); rf = __half22float2(r1v);
      m0 = rf.x * hf.x; mw0 = m0 * w1; m1 = rf.y * hf.y; mw1 = m1 * w1;
      sa0 += mw0; qa0 = fmaf(m0, mw0, qa0); mx0 = fmaxf(mx0, mw0); mn0 = fminf(mn0, mw0);
      sa1 += mw1; qa1 = fmaf(m1, mw1, qa1); mx1 = fmaxf(mx1, mw1); mn1 = fminf(mn1, mw1);
      hf = __half22float2(h2v); rf = __half22float2(r2v);
      m0 = rf.x * hf.x; mw0 = m0 * w2; m1 = rf.y * hf.y; mw1 = m1 * w2;
      sa0 += mw0; qa0 = fmaf(m0, mw0, qa0); mx0 = fmaxf(mx0, mw0); mn0 = fminf(mn0, mw0);
      sa1 += mw1; qa1 = fmaf(m1, mw1, qa1); mx1 = fmaxf(mx1, mw1); mn1 = fminf(mn1, mw1);
      hf = __half22float2(h3v); rf = __half22float2(r3v);
      m0 = rf.x * hf.x; mw0 = m0 * w3; m1 = rf.y * hf.y; mw1 = m1 * w3;
      sa0 += mw0; qa0 = fmaf(m0, mw0, qa0); mx0 = fmaxf(mx0, mw0); mn0 = fminf(mn0, mw0);
      sa1 += mw1; qa1 = fmaf(m1, mw1, qa1); mx1 = fmaxf(mx1, mw1); mn1 = fminf(mn1, mw1);
    }
    for (; p < end; ++p) {
      int4 e = ep[p];
      __half2 hv2 = hin2[(size_t)e.x * 64 + lane];
      __half2 rv2 = rel2[(size_t)e.y * 64 + lane];
      float w = __int_as_float(e.z);
      float2 hf = __half22float2(hv2), rf = __half22float2(rv2);
      float m0 = rf.x * hf.x, mw0 = m0 * w;
      float m1 = rf.y * hf.y, mw1 = m1 * w;
      sa0 += mw0; qa0 = fmaf(m0, mw0, qa0); mx0 = fmaxf(mx0, mw0); mn0 = fminf(mn0, mw0);
      sa1 += mw1; qa1 = fmaf(m1, mw1, qa1); mx1 = fmaxf(mx1, mw1); mn1 = fminf(mn1, mw1);
    }
    const float invc = 1.0f / cntf[n];
    const float mean0 = sa0 * invc, mean1 = sa1 * invc;
    const float sd0 = sqrtf(fmaxf(qa0 * invc - mean0 * mean0, EPSF));
    const float sd1 = sqrtf(fmaxf(qa1 * invc - mean1 * mean1, EPSF));
    float2 hf = __half22float2(hin2[(size_t)n * 64 + lane]);

    __builtin_amdgcn_wave_barrier();
    *(float2*)&Ab[d0]           = make_float2(hf.x, hf.y);
    *(float2*)&Ab[32 + 0 * 32 + d0] = make_float2(mean0, mean1);
    *(float2*)&Ab[32 + 1 * 32 + d0] = make_float2(mx0, mx1);
    *(float2*)&Ab[32 + 2 * 32 + d0] = make_float2(mn0, mn1);
    *(float2*)&Ab[32 + 3 * 32 + d0] = make_float2(sd0, sd1);
    __builtin_amdgcn_wave_barrier();   // LDS pipe is in-order per wave

    float aH0 = 0.f, aH1 = 0.f;
    float a00 = 0.f, a01 = 0.f, a10 = 0.f, a11 = 0.f, a20 = 0.f, a21 = 0.f;
    #pragma unroll
    for (int kg = 0; kg < 8; ++kg) {
      float4 av = *(const float4*)&Ab[kg * 4];
      const float4* wp = wv4 + ((size_t)(kg * 16 + dp) * 2);
      float4 w0 = wp[0], w1 = wp[1];
      aH0 = fmaf(av.x, w0.x, fmaf(av.y, w0.y, fmaf(av.z, w0.z, fmaf(av.w, w0.w, aH0))));
      aH1 = fmaf(av.x, w1.x, fmaf(av.y, w1.y, fmaf(av.z, w1.z, fmaf(av.w, w1.w, aH1))));
    }
    #pragma unroll 4
    for (int kg = 0; kg < 32; ++kg) {
      float4 av = *(const float4*)&Ab[32 + kg * 4];
      const float4* wp = wv4 + ((size_t)((8 + kg) * 16 + dp) * 2);
      float4 w00 = wp[0],    w01 = wp[1];
      float4 w10 = wp[1024], w11 = wp[1025];   // +32 kg slabs
      float4 w20 = wp[2048], w21 = wp[2049];
      a00 = fmaf(av.x, w00.x, fmaf(av.y, w00.y, fmaf(av.z, w00.z, fmaf(av.w, w00.w, a00))));
      a01 = fmaf(av.x, w01.x, fmaf(av.y, w01.y, fmaf(av.z, w01.z, fmaf(av.w, w01.w, a01))));
      a10 = fmaf(av.x, w10.x, fmaf(av.y, w10.y, fmaf(av.z, w10.z, fmaf(av.w, w10.w, a10))));
      a11 = fmaf(av.x, w11.x, fmaf(av.y, w11.y, fmaf(av.z, w11.z, fmaf(av.w, w11.w, a11))));
      a20 = fmaf(av.x, w20.x, fmaf(av.y, w20.y, fmaf(av.z, w20.z, fmaf(av.w, w20.w, a20))));
      a21 = fmaf(av.x, w21.x, fmaf(av.y, w21.y, fmaf(av.z, w21.z, fmaf(av.w, w21.w, a21))));
    }
    const float sc1 = scales[n * 2 + 0], sc2 = scales[n * 2 + 1];
    float o0 = fmaxf(bj0 + aH0 + a00 + sc1 * a10 + sc2 * a20, 0.f);
    float o1 = fmaxf(bj1 + aH1 + a01 + sc1 * a11 + sc2 * a21, 0.f);
    hout2[(size_t)n * 64 + lane] = __floats2half2_rn(o0, o1);
    __builtin_amdgcn_wave_barrier();
  }
}

// final MLP: [hidden(fp16), query] (64) -> relu(64) -> 1, out[b*N + n]
__global__ __launch_bounds__(128) void mlp_kernel(const __half* __restrict__ hinh,
                                                  const float* __restrict__ query,
                                                  const float* __restrict__ W1,
                                                  const float* __restrict__ b1,
                                                  const float* __restrict__ W2,
                                                  const float* __restrict__ b2,
                                                  float* __restrict__ out) {
  __shared__ float f2[BB][2 * DD];
  const int t = threadIdx.x;
  const int b = t >> 5, d = t & 31;
  const float qv = query[t];
  const float w2a = W2[d], w2b = W2[DD + d];
  const float b1a = b1[d], b1b = b1[DD + d];
  const float b2v = b2[0];
  const int NPBM = 8;
  int n0 = blockIdx.x * NPBM, n1 = min(n0 + NPBM, NN);
  for (int n = n0; n < n1; ++n) {
    f2[b][d]      = __half2float(hinh[(size_t)n * BD + t]);
    f2[b][DD + d] = qv;
    float a0 = b1a, a1 = b1b;
    #pragma unroll
    for (int i = 0; i < 2 * DD; ++i) {
      float v = f2[b][i];
      a0 = fmaf(v, W1[i * 2 * DD + d], a0);
      a1 = fmaf(v, W1[i * 2 * DD + DD + d], a1);
    }
    a0 = fmaxf(a0, 0.f); a1 = fmaxf(a1, 0.f);
    float part = a0 * w2a + a1 * w2b;
    #pragma unroll
    for (int off = 16; off > 0; off >>= 1) part += __shfl_down(part, off, 32);
    if (d == 0) out[b * NN + n] = part + b2v;
  }
}

extern "C" void kernel_launch(void* const* d_in, const int* in_sizes, int n_in,
                              void* d_out, int out_size, void* d_ws, size_t ws_size,
                              hipStream_t stream) {
  const int*   node_in  = (const int*)d_in[0];
  const int*   node_out = (const int*)d_in[1];
  const int*   relation = (const int*)d_in[2];
  const float* ew       = (const float*)d_in[3];
  const int*   h_index  = (const int*)d_in[4];
  const int*   r_index  = (const int*)d_in[5];
  const float* qemb     = (const float*)d_in[6];
  const float* relW     = (const float*)d_in[7];
  const float* relB     = (const float*)d_in[8];
  const float* linW     = (const float*)d_in[9];
  const float* linB     = (const float*)d_in[10];
  const float* W1       = (const float*)d_in[11];
  const float* b1       = (const float*)d_in[12];
  const float* W2       = (const float*)d_in[13];
  const float* b2       = (const float*)d_in[14];
  float* out = (float*)d_out;

  char* ws = (char*)d_ws;
  size_t off = 0;
  auto alloc = [&](size_t bytes) -> char* {
    char* p = ws + off;
    off += (bytes + 255) & ~(size_t)255;
    return p;
  };
  __half* h0    = (__half*)alloc((size_t)NN * BD * 2);
  __half* h1    = (__half*)alloc((size_t)NN * BD * 2);
  __half* relIn = (__half*)alloc((size_t)R2C * BD * 2);
  float*  Wv    = (float*) alloc((size_t)LL * WVF * 4);
  int4*   ep    = (int4*)  alloc((size_t)EE * 16);
  int*    rowp  = (int*)   alloc((size_t)(NN + 1) * 4);
  int*    cnti  = (int*)   alloc((size_t)NN * 4);
  int*    fill  = (int*)   alloc((size_t)NN * 4);
  float*  wdeg  = (float*) alloc((size_t)NN * 4);
  float*  cntf  = (float*) alloc((size_t)NN * 4);
  float*  scales= (float*) alloc((size_t)NN * 2 * 4);
  float*  query = (float*) alloc((size_t)BD * 4);
  float*  stats = (float*) alloc(256);

  hipMemsetAsync(cnti, 0, (size_t)NN * 4, stream);
  hipMemsetAsync(fill, 0, (size_t)NN * 4, stream);
  hipMemsetAsync(wdeg, 0, (size_t)NN * 4, stream);
  hipMemsetAsync(h0,   0, (size_t)NN * BD * 2, stream);

  hist_kernel   <<<(EE + 255) / 256, 256, 0, stream>>>(node_out, ew, cnti, wdeg);
  scan_kernel   <<<1, 1024, 0, stream>>>(cnti, rowp, wdeg, stats, cntf);
  scales_kernel <<<(NN + 255) / 256, 256, 0, stream>>>(wdeg, stats, scales);
  scatter_kernel<<<(EE + 255) / 256, 256, 0, stream>>>(node_in, node_out, relation, ew,
                                                       rowp, fill, ep);
  init_kernel   <<<1, 128, 0, stream>>>(h_index, r_index, qemb, query, h0);
  wvbuild_kernel<<<(LL * WVF + 255) / 256, 256, 0, stream>>>(linW, Wv);

  __half* hin = h0; __half* hout = h1;
  for (int l = 0; l < LL; ++l) {
    relin_kernel<<<(R2C * BD + 255) / 256, 256, 0, stream>>>(
        query, relW + (size_t)l * DD * R2C * DD, relB + (size_t)l * R2C * DD, relIn);
    layer_kernel<<<NN / 8, 256, 0, stream>>>(
        (const __half2*)hin, (__half2*)hout, (const __half2*)relIn, ep, rowp,
        cntf, scales, (const float4*)(Wv + (size_t)l * WVF),
        linB + (size_t)l * DD, h_index, query);
    __half* tmp = hin; hin = hout; hout = tmp;
  }
  mlp_kernel<<<(NN + 7) / 8, 128, 0, stream>>>(hin, query, W1, b1, W2, b2, out);
}

// Round 4
// 931.439 us; speedup vs baseline: 1.3655x; 1.3655x over previous
//
#include <hip/hip_runtime.h>
#include <hip/hip_fp16.h>

#define NN  25000
#define EE  500000
#define BB  4
#define DD  32
#define R2C 474
#define LL  4
#define BD  128      // B*D
#define THD 416      // 13*D
#define EPSF 1e-6f
#define NPB 2        // 12500 blocks x 2 waves = 25000 waves -> latency hiding
#define WG  104      // float4 groups per output column (416/4)
#define WVF (WG*DD*4) // 13312 floats per layer of packed W

// ---------------- CSR build ----------------
__global__ __launch_bounds__(256) void hist_kernel(const int* __restrict__ node_out,
                                                   const float* __restrict__ ew,
                                                   int* __restrict__ cnt,
                                                   float* __restrict__ wdeg) {
  int e = blockIdx.x * 256 + threadIdx.x;
  if (e < EE) {
    int d = node_out[e];
    atomicAdd(&cnt[d], 1);
    atomicAdd(&wdeg[d], ew[e]);
  }
}

__global__ __launch_bounds__(1024) void scan_kernel(const int* __restrict__ cnt,
                                                    int* __restrict__ rowp,
                                                    const float* __restrict__ wdeg,
                                                    float* __restrict__ stats,
                                                    float* __restrict__ cntf) {
  __shared__ int   part[1024];
  __shared__ float fpart[1024];
  int t = threadIdx.x;
  const int per = (NN + 1023) / 1024;   // 25
  int beg = t * per, end = min(beg + per, NN);
  int s = 0; float ls = 0.f;
  for (int i = beg; i < end; ++i) { s += cnt[i]; ls += logf(wdeg[i] + 1.0f); }
  part[t] = s; fpart[t] = ls;
  __syncthreads();
  for (int off = 1; off < 1024; off <<= 1) {
    int   v  = (t >= off) ? part[t - off]  : 0;
    float fv = (t >= off) ? fpart[t - off] : 0.f;
    __syncthreads();
    part[t] += v; fpart[t] += fv;
    __syncthreads();
  }
  int run = part[t] - s;
  for (int i = beg; i < end; ++i) {
    rowp[i] = run; run += cnt[i];
    cntf[i] = (float)(cnt[i] + 1);      // indeg + self entry
  }
  if (t == 1023) { rowp[NN] = part[1023]; stats[0] = fpart[1023]; }
}

__global__ __launch_bounds__(256) void scales_kernel(const float* __restrict__ wdeg,
                                                     const float* __restrict__ stats,
                                                     float* __restrict__ scales) {
  int n = blockIdx.x * 256 + threadIdx.x;
  if (n >= NN) return;
  float mean = stats[0] / (float)NN;
  float sc = logf(wdeg[n] + 1.0f) / mean;
  scales[n * 2 + 0] = sc;
  scales[n * 2 + 1] = 1.0f / fmaxf(sc, 0.01f);
}

// pack each edge as {node_in, relation, w_bits, 0}
__global__ __launch_bounds__(256) void scatter_kernel(const int* __restrict__ node_in,
                                                      const int* __restrict__ node_out,
                                                      const int* __restrict__ relation,
                                                      const float* __restrict__ ew,
                                                      const int* __restrict__ rowp,
                                                      int* __restrict__ fill,
                                                      int4* __restrict__ ep) {
  int e = blockIdx.x * 256 + threadIdx.x;
  if (e >= EE) return;
  int dn = node_out[e];
  int pos = rowp[dn] + atomicAdd(&fill[dn], 1);
  ep[pos] = make_int4(node_in[e], relation[e], __float_as_int(ew[e]), 0);
}

// query gather + boundary placement (h0 pre-zeroed; fp16 zero == 0x0000)
__global__ __launch_bounds__(128) void init_kernel(const int* __restrict__ h_index,
                                                   const int* __restrict__ r_index,
                                                   const float* __restrict__ qemb,
                                                   float* __restrict__ query,
                                                   __half* __restrict__ h0) {
  int t = threadIdx.x; int b = t >> 5, d = t & 31;
  float qv = qemb[r_index[b] * DD + d];
  query[t] = qv;
  h0[h_index[b] * BD + t] = __float2half(qv);
}

// rel_in[r][b][d] = query[b] . rel_W[l][:, r*D+d] + rel_b[l][r*D+d]   (fp16 out)
__global__ __launch_bounds__(256) void relin_kernel(const float* __restrict__ query,
                                                    const float* __restrict__ relW,
                                                    const float* __restrict__ relB,
                                                    __half* __restrict__ relIn) {
  int o = blockIdx.x * 256 + threadIdx.x;
  if (o >= R2C * BD) return;
  int r = o >> 7; int b = (o >> 5) & 3; int d = o & 31;
  int col = r * DD + d;
  float acc = relB[col];
  #pragma unroll
  for (int k = 0; k < DD; ++k)
    acc = fmaf(query[b * DD + k], relW[(size_t)k * (R2C * DD) + col], acc);
  relIn[o] = __float2half(acc);
}

// Pack lin_W as Wp[l][g][d] float4 where component c corresponds to LDS-order
// feature index kk = g*4+c.  kk<32 -> hidden slab (wrow=kk); else slot
// s=(kk-32)>>5 (= si*3+sc), df=kk&31, wrow = 32 + (df*4+si)*3 + sc.
__global__ __launch_bounds__(256) void wvbuild_kernel(const float* __restrict__ linW,
                                                      float* __restrict__ Wv) {
  int idx = blockIdx.x * 256 + threadIdx.x;
  if (idx >= LL * WVF) return;
  int c  = idx & 3;
  int d  = (idx >> 2) & 31;
  int g  = (idx >> 7) % WG;
  int l  = idx / WVF;
  int kk = g * 4 + c;
  int wrow;
  if (kk < 32) wrow = kk;
  else {
    int s = (kk - 32) >> 5, df = kk & 31;
    int si = s / 3, sc = s - si * 3;
    wrow = DD + (df * 4 + si) * 3 + sc;
  }
  Wv[idx] = linW[(size_t)l * THD * DD + (size_t)wrow * DD + d];
}

// Fused layer (R2 structure): 128 thr = one (b,d) slot each; per-thread fp16
// gather loads; PNA stats; feat13 in LDS (wave-private b-groups, no barriers);
// float4-packed-W epilogue: 104 coalesced dwordx4 W loads + 104 broadcast
// ds_read_b128 + 416 fp32 FMA per node-wave.
__global__ __launch_bounds__(128) void layer_kernel(const __half* __restrict__ hinh,
                                                    __half* __restrict__ houth,
                                                    const __half* __restrict__ relh,
                                                    const int4* __restrict__ ep,
                                                    const int* __restrict__ rowp,
                                                    const float* __restrict__ cntf,
                                                    const float* __restrict__ scales,
                                                    const float4* __restrict__ wp,
                                                    const float* __restrict__ bias,
                                                    const int* __restrict__ h_index,
                                                    const float* __restrict__ query) {
  __shared__ float feat13[BB][THD];
  const int t = threadIdx.x;
  const int b = t >> 5, d = t & 31;
  const float qv = query[t];
  const int   hb = h_index[b];
  const float bj = bias[d];
  float* fb = &feat13[b][0];
  int n0 = blockIdx.x * NPB;
  int n1 = min(n0 + NPB, NN);
  for (int n = n0; n < n1; ++n) {
    int beg = rowp[n], end = rowp[n + 1];
    float msgb = (n == hb) ? qv : 0.f;
    float s = msgb, q = msgb * msgb, mx = msgb, mn = msgb;
    float hs = __half2float(hinh[(size_t)n * BD + t]);
    int p = beg;
    for (; p + 4 <= end; p += 4) {
      int4 e0 = ep[p];     int4 e1 = ep[p + 1];
      int4 e2 = ep[p + 2]; int4 e3 = ep[p + 3];
      float hv0 = __half2float(hinh[(size_t)e0.x * BD + t]);
      float rv0 = __half2float(relh[(size_t)e0.y * BD + t]);
      float hv1 = __half2float(hinh[(size_t)e1.x * BD + t]);
      float rv1 = __half2float(relh[(size_t)e1.y * BD + t]);
      float hv2 = __half2float(hinh[(size_t)e2.x * BD + t]);
      float rv2 = __half2float(relh[(size_t)e2.y * BD + t]);
      float hv3 = __half2float(hinh[(size_t)e3.x * BD + t]);
      float rv3 = __half2float(relh[(size_t)e3.y * BD + t]);
      float m0 = rv0 * hv0, mw0 = m0 * __int_as_float(e0.z);
      float m1 = rv1 * hv1, mw1 = m1 * __int_as_float(e1.z);
      float m2 = rv2 * hv2, mw2 = m2 * __int_as_float(e2.z);
      float m3 = rv3 * hv3, mw3 = m3 * __int_as_float(e3.z);
      s += mw0; q = fmaf(m0, mw0, q); mx = fmaxf(mx, mw0); mn = fminf(mn, mw0);
      s += mw1; q = fmaf(m1, mw1, q); mx = fmaxf(mx, mw1); mn = fminf(mn, mw1);
      s += mw2; q = fmaf(m2, mw2, q); mx = fmaxf(mx, mw2); mn = fminf(mn, mw2);
      s += mw3; q = fmaf(m3, mw3, q); mx = fmaxf(mx, mw3); mn = fminf(mn, mw3);
    }
    for (; p < end; ++p) {
      int4 e = ep[p];
      float hv = __half2float(hinh[(size_t)e.x * BD + t]);
      float rv = __half2float(relh[(size_t)e.y * BD + t]);
      float m = rv * hv, mw = m * __int_as_float(e.z);
      s += mw; q = fmaf(m, mw, q); mx = fmaxf(mx, mw); mn = fminf(mn, mw);
    }
    float invc = 1.0f / cntf[n];
    float mean = s * invc;
    float sd   = sqrtf(fmaxf(q * invc - mean * mean, EPSF));
    float sc1 = scales[n * 2 + 0], sc2 = scales[n * 2 + 1];
    float fv4[4] = {mean, mx, mn, sd};
    __builtin_amdgcn_wave_barrier();
    fb[d] = hs;
    #pragma unroll
    for (int si = 0; si < 4; ++si) {
      float v = fv4[si];
      fb[DD + (si * 3 + 0) * 32 + d] = v;
      fb[DD + (si * 3 + 1) * 32 + d] = v * sc1;
      fb[DD + (si * 3 + 2) * 32 + d] = v * sc2;
    }
    __builtin_amdgcn_wave_barrier();
    float acc = bj;
    #pragma unroll 4
    for (int g = 0; g < WG; ++g) {
      float4 fv = *(const float4*)&fb[g * 4];       // broadcast ds_read_b128
      float4 wv = wp[g * DD + d];                   // coalesced 512B per 32 lanes
      acc = fmaf(fv.x, wv.x, fmaf(fv.y, wv.y, fmaf(fv.z, wv.z, fmaf(fv.w, wv.w, acc))));
    }
    houth[(size_t)n * BD + t] = __float2half(fmaxf(acc, 0.f));
    __builtin_amdgcn_wave_barrier();
  }
}

// final MLP: [hidden(fp16), query] (64) -> relu(64) -> 1, out[b*N + n]
__global__ __launch_bounds__(128) void mlp_kernel(const __half* __restrict__ hinh,
                                                  const float* __restrict__ query,
                                                  const float* __restrict__ W1,
                                                  const float* __restrict__ b1,
                                                  const float* __restrict__ W2,
                                                  const float* __restrict__ b2,
                                                  float* __restrict__ out) {
  __shared__ float f2[BB][2 * DD];
  const int t = threadIdx.x;
  const int b = t >> 5, d = t & 31;
  const float qv = query[t];
  const float w2a = W2[d], w2b = W2[DD + d];
  const float b1a = b1[d], b1b = b1[DD + d];
  const float b2v = b2[0];
  const int NPBM = 8;
  int n0 = blockIdx.x * NPBM, n1 = min(n0 + NPBM, NN);
  for (int n = n0; n < n1; ++n) {
    f2[b][d]      = __half2float(hinh[(size_t)n * BD + t]);
    f2[b][DD + d] = qv;
    float a0 = b1a, a1 = b1b;
    #pragma unroll
    for (int i = 0; i < 2 * DD; ++i) {
      float v = f2[b][i];
      a0 = fmaf(v, W1[i * 2 * DD + d], a0);
      a1 = fmaf(v, W1[i * 2 * DD + DD + d], a1);
    }
    a0 = fmaxf(a0, 0.f); a1 = fmaxf(a1, 0.f);
    float part = a0 * w2a + a1 * w2b;
    #pragma unroll
    for (int off = 16; off > 0; off >>= 1) part += __shfl_down(part, off, 32);
    if (d == 0) out[b * NN + n] = part + b2v;
  }
}

extern "C" void kernel_launch(void* const* d_in, const int* in_sizes, int n_in,
                              void* d_out, int out_size, void* d_ws, size_t ws_size,
                              hipStream_t stream) {
  const int*   node_in  = (const int*)d_in[0];
  const int*   node_out = (const int*)d_in[1];
  const int*   relation = (const int*)d_in[2];
  const float* ew       = (const float*)d_in[3];
  const int*   h_index  = (const int*)d_in[4];
  const int*   r_index  = (const int*)d_in[5];
  const float* qemb     = (const float*)d_in[6];
  const float* relW     = (const float*)d_in[7];
  const float* relB     = (const float*)d_in[8];
  const float* linW     = (const float*)d_in[9];
  const float* linB     = (const float*)d_in[10];
  const float* W1       = (const float*)d_in[11];
  const float* b1       = (const float*)d_in[12];
  const float* W2       = (const float*)d_in[13];
  const float* b2       = (const float*)d_in[14];
  float* out = (float*)d_out;

  char* ws = (char*)d_ws;
  size_t off = 0;
  auto alloc = [&](size_t bytes) -> char* {
    char* p = ws + off;
    off += (bytes + 255) & ~(size_t)255;
    return p;
  };
  __half* h0    = (__half*)alloc((size_t)NN * BD * 2);
  __half* h1    = (__half*)alloc((size_t)NN * BD * 2);
  __half* relIn = (__half*)alloc((size_t)R2C * BD * 2);
  float*  Wv    = (float*) alloc((size_t)LL * WVF * 4);
  int4*   ep    = (int4*)  alloc((size_t)EE * 16);
  int*    rowp  = (int*)   alloc((size_t)(NN + 1) * 4);
  int*    cnti  = (int*)   alloc((size_t)NN * 4);
  int*    fill  = (int*)   alloc((size_t)NN * 4);
  float*  wdeg  = (float*) alloc((size_t)NN * 4);
  float*  cntf  = (float*) alloc((size_t)NN * 4);
  float*  scales= (float*) alloc((size_t)NN * 2 * 4);
  float*  query = (float*) alloc((size_t)BD * 4);
  float*  stats = (float*) alloc(256);

  hipMemsetAsync(cnti, 0, (size_t)NN * 4, stream);
  hipMemsetAsync(fill, 0, (size_t)NN * 4, stream);
  hipMemsetAsync(wdeg, 0, (size_t)NN * 4, stream);
  hipMemsetAsync(h0,   0, (size_t)NN * BD * 2, stream);

  hist_kernel   <<<(EE + 255) / 256, 256, 0, stream>>>(node_out, ew, cnti, wdeg);
  scan_kernel   <<<1, 1024, 0, stream>>>(cnti, rowp, wdeg, stats, cntf);
  scales_kernel <<<(NN + 255) / 256, 256, 0, stream>>>(wdeg, stats, scales);
  scatter_kernel<<<(EE + 255) / 256, 256, 0, stream>>>(node_in, node_out, relation, ew,
                                                       rowp, fill, ep);
  init_kernel   <<<1, 128, 0, stream>>>(h_index, r_index, qemb, query, h0);
  wvbuild_kernel<<<(LL * WVF + 255) / 256, 256, 0, stream>>>(linW, Wv);

  __half* hin = h0; __half* hout = h1;
  for (int l = 0; l < LL; ++l) {
    relin_kernel<<<(R2C * BD + 255) / 256, 256, 0, stream>>>(
        query, relW + (size_t)l * DD * R2C * DD, relB + (size_t)l * R2C * DD, relIn);
    layer_kernel<<<(NN + NPB - 1) / NPB, 128, 0, stream>>>(
        hin, hout, relIn, ep, rowp, cntf, scales,
        (const float4*)(Wv + (size_t)l * WVF),
        linB + (size_t)l * DD, h_index, query);
    __half* tmp = hin; hin = hout; hout = tmp;
  }
  mlp_kernel<<<(NN + 7) / 8, 128, 0, stream>>>(hin, query, W1, b1, W2, b2, out);
}

// Round 5
// 814.088 us; speedup vs baseline: 1.5624x; 1.1442x over previous
//
#include <hip/hip_runtime.h>
#include <hip/hip_fp16.h>

#define NN  25000
#define EE  500000
#define BB  4
#define DD  32
#define R2C 474
#define LL  4
#define BD  128      // B*D
#define THD 416      // 13*D
#define EPSF 1e-6f
#define NPB 4        // nodes per block: epilogue W loads amortized over 4 nodes
#define RP  164      // padded raw-stat row (164%32=4 -> conflict-free)
#define WVF 13312    // floats per layer of packed W: (8 + 3*32) groups * 32d * 4

// ---------------- CSR build ----------------
__global__ __launch_bounds__(256) void hist_kernel(const int* __restrict__ node_out,
                                                   const float* __restrict__ ew,
                                                   int* __restrict__ cnt,
                                                   float* __restrict__ wdeg) {
  int e = blockIdx.x * 256 + threadIdx.x;
  if (e < EE) {
    int d = node_out[e];
    atomicAdd(&cnt[d], 1);
    atomicAdd(&wdeg[d], ew[e]);
  }
}

__global__ __launch_bounds__(1024) void scan_kernel(const int* __restrict__ cnt,
                                                    int* __restrict__ rowp,
                                                    const float* __restrict__ wdeg,
                                                    float* __restrict__ stats,
                                                    float* __restrict__ cntf) {
  __shared__ int   part[1024];
  __shared__ float fpart[1024];
  int t = threadIdx.x;
  const int per = (NN + 1023) / 1024;   // 25
  int beg = t * per, end = min(beg + per, NN);
  int s = 0; float ls = 0.f;
  for (int i = beg; i < end; ++i) { s += cnt[i]; ls += logf(wdeg[i] + 1.0f); }
  part[t] = s; fpart[t] = ls;
  __syncthreads();
  for (int off = 1; off < 1024; off <<= 1) {
    int   v  = (t >= off) ? part[t - off]  : 0;
    float fv = (t >= off) ? fpart[t - off] : 0.f;
    __syncthreads();
    part[t] += v; fpart[t] += fv;
    __syncthreads();
  }
  int run = part[t] - s;
  for (int i = beg; i < end; ++i) {
    rowp[i] = run; run += cnt[i];
    cntf[i] = (float)(cnt[i] + 1);      // indeg + self entry
  }
  if (t == 1023) { rowp[NN] = part[1023]; stats[0] = fpart[1023]; }
}

__global__ __launch_bounds__(256) void scales_kernel(const float* __restrict__ wdeg,
                                                     const float* __restrict__ stats,
                                                     float* __restrict__ scales) {
  int n = blockIdx.x * 256 + threadIdx.x;
  if (n >= NN) return;
  float mean = stats[0] / (float)NN;
  float sc = logf(wdeg[n] + 1.0f) / mean;
  scales[n * 2 + 0] = sc;
  scales[n * 2 + 1] = 1.0f / fmaxf(sc, 0.01f);
}

// pack each edge as {node_in, relation, w_bits, 0}
__global__ __launch_bounds__(256) void scatter_kernel(const int* __restrict__ node_in,
                                                      const int* __restrict__ node_out,
                                                      const int* __restrict__ relation,
                                                      const float* __restrict__ ew,
                                                      const int* __restrict__ rowp,
                                                      int* __restrict__ fill,
                                                      int4* __restrict__ ep) {
  int e = blockIdx.x * 256 + threadIdx.x;
  if (e >= EE) return;
  int dn = node_out[e];
  int pos = rowp[dn] + atomicAdd(&fill[dn], 1);
  ep[pos] = make_int4(node_in[e], relation[e], __float_as_int(ew[e]), 0);
}

// query gather + boundary placement (h0 pre-zeroed; fp16 zero == 0x0000)
__global__ __launch_bounds__(128) void init_kernel(const int* __restrict__ h_index,
                                                   const int* __restrict__ r_index,
                                                   const float* __restrict__ qemb,
                                                   float* __restrict__ query,
                                                   __half* __restrict__ h0) {
  int t = threadIdx.x; int b = t >> 5, d = t & 31;
  float qv = qemb[r_index[b] * DD + d];
  query[t] = qv;
  h0[h_index[b] * BD + t] = __float2half(qv);
}

// rel_in[r][b][d] = query[b] . rel_W[l][:, r*D+d] + rel_b[l][r*D+d]   (fp16 out)
__global__ __launch_bounds__(256) void relin_kernel(const float* __restrict__ query,
                                                    const float* __restrict__ relW,
                                                    const float* __restrict__ relB,
                                                    __half* __restrict__ relIn) {
  int o = blockIdx.x * 256 + threadIdx.x;
  if (o >= R2C * BD) return;
  int r = o >> 7; int b = (o >> 5) & 3; int d = o & 31;
  int col = r * DD + d;
  float acc = relB[col];
  #pragma unroll
  for (int k = 0; k < DD; ++k)
    acc = fmaf(query[b * DD + k], relW[(size_t)k * (R2C * DD) + col], acc);
  relIn[o] = __float2half(acc);
}

// Pack lin_W into slabs, float4 records [g][d][c], g in [0,104):
//   g<8:            hidden slab, k = g*4+c, wrow = k
//   g=8+m*32+kg:    scale slab m (0..2), q = kg*4+c, si=q>>5, df=q&31,
//                   wrow = 32 + (df*4+si)*3 + m
// Epilogue combines: out = accH + acc0 + sc1*acc1 + sc2*acc2
__global__ __launch_bounds__(256) void wvbuild_kernel(const float* __restrict__ linW,
                                                      float* __restrict__ Wv) {
  int idx = blockIdx.x * 256 + threadIdx.x;
  if (idx >= LL * WVF) return;
  int c = idx & 3;
  int d = (idx >> 2) & 31;
  int g = (idx >> 7) % 104;
  int l = idx / WVF;
  int wrow;
  if (g < 8) {
    wrow = g * 4 + c;
  } else {
    int gm = g - 8; int m = gm >> 5; int kg = gm & 31;
    int q = kg * 4 + c; int si = q >> 5, df = q & 31;
    wrow = DD + (df * 4 + si) * 3 + m;
  }
  Wv[idx] = linW[(size_t)l * THD * DD + (size_t)wrow * DD + d];
}

// Fused layer: phase 1 gathers PNA raw stats for NPB=4 nodes into LDS (fp32,
// padded rows, wave-private b-groups -> no block barrier); phase 2 is ONE
// shared pass over the 104 packed-W groups feeding 4 nodes' accumulators
// (W L1 traffic / 4 vs per-node epilogue). 32-bit index math in hot loops.
__global__ __launch_bounds__(128) void layer_kernel(const __half* __restrict__ hinh,
                                                    __half* __restrict__ houth,
                                                    const __half* __restrict__ relh,
                                                    const int4* __restrict__ ep,
                                                    const int* __restrict__ rowp,
                                                    const float* __restrict__ cntf,
                                                    const float* __restrict__ scales,
                                                    const float4* __restrict__ wp,
                                                    const float* __restrict__ bias,
                                                    const int* __restrict__ h_index,
                                                    const float* __restrict__ query) {
  __shared__ float raw[NPB * BB][RP];   // 16 rows x 164 floats = 10.5 KB
  const int t = threadIdx.x;
  const int b = t >> 5, d = t & 31;
  const float qv = query[t];
  const int   hb = h_index[b];
  const float bj = bias[d];
  const int n0 = blockIdx.x * NPB;      // NN % NPB == 0

  // ---- phase 1: gather-reduce stats for 4 nodes ----
  #pragma unroll 1
  for (int ni = 0; ni < NPB; ++ni) {
    const int n = n0 + ni;
    const int beg = rowp[n], end = rowp[n + 1];
    const float msgb = (n == hb) ? qv : 0.f;
    float s = msgb, q = msgb * msgb, mx = msgb, mn = msgb;
    const float hs = __half2float(hinh[(unsigned)n * BD + t]);
    int p = beg;
    const int pend = beg + ((end - beg) & ~3);
    if (p < pend) {
      int4 e0 = ep[p], e1 = ep[p + 1], e2 = ep[p + 2], e3 = ep[p + 3];
      for (;;) {
        // issue 8 gathers for current batch (32-bit offsets -> saddr form)
        float hv0 = __half2float(hinh[(unsigned)e0.x * BD + t]);
        float rv0 = __half2float(relh[(unsigned)e0.y * BD + t]);
        float hv1 = __half2float(hinh[(unsigned)e1.x * BD + t]);
        float rv1 = __half2float(relh[(unsigned)e1.y * BD + t]);
        float hv2 = __half2float(hinh[(unsigned)e2.x * BD + t]);
        float rv2 = __half2float(relh[(unsigned)e2.y * BD + t]);
        float hv3 = __half2float(hinh[(unsigned)e3.x * BD + t]);
        float rv3 = __half2float(relh[(unsigned)e3.y * BD + t]);
        // prefetch next ep batch while gathers are in flight
        const int pn = p + 4;
        int4 f0, f1, f2, f3;
        if (pn < pend) { f0 = ep[pn]; f1 = ep[pn + 1]; f2 = ep[pn + 2]; f3 = ep[pn + 3]; }
        float m0 = rv0 * hv0, mw0 = m0 * __int_as_float(e0.z);
        float m1 = rv1 * hv1, mw1 = m1 * __int_as_float(e1.z);
        float m2 = rv2 * hv2, mw2 = m2 * __int_as_float(e2.z);
        float m3 = rv3 * hv3, mw3 = m3 * __int_as_float(e3.z);
        s += mw0; q = fmaf(m0, mw0, q); mx = fmaxf(mx, mw0); mn = fminf(mn, mw0);
        s += mw1; q = fmaf(m1, mw1, q); mx = fmaxf(mx, mw1); mn = fminf(mn, mw1);
        s += mw2; q = fmaf(m2, mw2, q); mx = fmaxf(mx, mw2); mn = fminf(mn, mw2);
        s += mw3; q = fmaf(m3, mw3, q); mx = fmaxf(mx, mw3); mn = fminf(mn, mw3);
        p = pn;
        if (p >= pend) break;
        e0 = f0; e1 = f1; e2 = f2; e3 = f3;
      }
    }
    for (; p < end; ++p) {
      int4 e = ep[p];
      float hv = __half2float(hinh[(unsigned)e.x * BD + t]);
      float rv = __half2float(relh[(unsigned)e.y * BD + t]);
      float m = rv * hv, mw = m * __int_as_float(e.z);
      s += mw; q = fmaf(m, mw, q); mx = fmaxf(mx, mw); mn = fminf(mn, mw);
    }
    const float invc = 1.0f / cntf[n];
    const float mean = s * invc;
    const float sd   = sqrtf(fmaxf(q * invc - mean * mean, EPSF));
    float* rw = &raw[ni * BB + b][0];
    rw[d]               = hs;
    rw[32 + 0 * 32 + d] = mean;
    rw[32 + 1 * 32 + d] = mx;
    rw[32 + 2 * 32 + d] = mn;
    rw[32 + 3 * 32 + d] = sd;
  }
  __builtin_amdgcn_wave_barrier();

  // ---- phase 2: shared-W epilogue for 4 nodes ----
  float accH[NPB] = {0.f, 0.f, 0.f, 0.f};
  float acc0[NPB] = {0.f, 0.f, 0.f, 0.f};
  float acc1[NPB] = {0.f, 0.f, 0.f, 0.f};
  float acc2[NPB] = {0.f, 0.f, 0.f, 0.f};
  #pragma unroll
  for (int g = 0; g < 8; ++g) {
    float4 wv = wp[g * 32 + d];
    #pragma unroll
    for (int ni = 0; ni < NPB; ++ni) {
      float4 f = *(const float4*)&raw[ni * BB + b][g * 4];
      accH[ni] = fmaf(f.x, wv.x, fmaf(f.y, wv.y, fmaf(f.z, wv.z, fmaf(f.w, wv.w, accH[ni]))));
    }
  }
  #pragma unroll 2
  for (int kg = 0; kg < 32; ++kg) {
    float4 w0 = wp[256 + 0 * 1024 + kg * 32 + d];
    float4 w1 = wp[256 + 1 * 1024 + kg * 32 + d];
    float4 w2 = wp[256 + 2 * 1024 + kg * 32 + d];
    #pragma unroll
    for (int ni = 0; ni < NPB; ++ni) {
      float4 f = *(const float4*)&raw[ni * BB + b][32 + kg * 4];
      acc0[ni] = fmaf(f.x, w0.x, fmaf(f.y, w0.y, fmaf(f.z, w0.z, fmaf(f.w, w0.w, acc0[ni]))));
      acc1[ni] = fmaf(f.x, w1.x, fmaf(f.y, w1.y, fmaf(f.z, w1.z, fmaf(f.w, w1.w, acc1[ni]))));
      acc2[ni] = fmaf(f.x, w2.x, fmaf(f.y, w2.y, fmaf(f.z, w2.z, fmaf(f.w, w2.w, acc2[ni]))));
    }
  }
  #pragma unroll
  for (int ni = 0; ni < NPB; ++ni) {
    const int n = n0 + ni;
    const float sc1 = scales[n * 2 + 0], sc2 = scales[n * 2 + 1];
    float o = bj + accH[ni] + acc0[ni] + sc1 * acc1[ni] + sc2 * acc2[ni];
    houth[(unsigned)n * BD + t] = __float2half(fmaxf(o, 0.f));
  }
}

// final MLP: [hidden(fp16), query] (64) -> relu(64) -> 1, out[b*N + n]
__global__ __launch_bounds__(128) void mlp_kernel(const __half* __restrict__ hinh,
                                                  const float* __restrict__ query,
                                                  const float* __restrict__ W1,
                                                  const float* __restrict__ b1,
                                                  const float* __restrict__ W2,
                                                  const float* __restrict__ b2,
                                                  float* __restrict__ out) {
  __shared__ float f2[BB][2 * DD];
  const int t = threadIdx.x;
  const int b = t >> 5, d = t & 31;
  const float qv = query[t];
  const float w2a = W2[d], w2b = W2[DD + d];
  const float b1a = b1[d], b1b = b1[DD + d];
  const float b2v = b2[0];
  const int NPBM = 8;
  int n0 = blockIdx.x * NPBM, n1 = min(n0 + NPBM, NN);
  for (int n = n0; n < n1; ++n) {
    f2[b][d]      = __half2float(hinh[(unsigned)n * BD + t]);
    f2[b][DD + d] = qv;
    float a0 = b1a, a1 = b1b;
    #pragma unroll
    for (int i = 0; i < 2 * DD; ++i) {
      float v = f2[b][i];
      a0 = fmaf(v, W1[i * 2 * DD + d], a0);
      a1 = fmaf(v, W1[i * 2 * DD + DD + d], a1);
    }
    a0 = fmaxf(a0, 0.f); a1 = fmaxf(a1, 0.f);
    float part = a0 * w2a + a1 * w2b;
    #pragma unroll
    for (int off = 16; off > 0; off >>= 1) part += __shfl_down(part, off, 32);
    if (d == 0) out[b * NN + n] = part + b2v;
  }
}

extern "C" void kernel_launch(void* const* d_in, const int* in_sizes, int n_in,
                              void* d_out, int out_size, void* d_ws, size_t ws_size,
                              hipStream_t stream) {
  const int*   node_in  = (const int*)d_in[0];
  const int*   node_out = (const int*)d_in[1];
  const int*   relation = (const int*)d_in[2];
  const float* ew       = (const float*)d_in[3];
  const int*   h_index  = (const int*)d_in[4];
  const int*   r_index  = (const int*)d_in[5];
  const float* qemb     = (const float*)d_in[6];
  const float* relW     = (const float*)d_in[7];
  const float* relB     = (const float*)d_in[8];
  const float* linW     = (const float*)d_in[9];
  const float* linB     = (const float*)d_in[10];
  const float* W1       = (const float*)d_in[11];
  const float* b1       = (const float*)d_in[12];
  const float* W2       = (const float*)d_in[13];
  const float* b2       = (const float*)d_in[14];
  float* out = (float*)d_out;

  char* ws = (char*)d_ws;
  size_t off = 0;
  auto alloc = [&](size_t bytes) -> char* {
    char* p = ws + off;
    off += (bytes + 255) & ~(size_t)255;
    return p;
  };
  __half* h0    = (__half*)alloc((size_t)NN * BD * 2);
  __half* h1    = (__half*)alloc((size_t)NN * BD * 2);
  __half* relIn = (__half*)alloc((size_t)R2C * BD * 2);
  float*  Wv    = (float*) alloc((size_t)LL * WVF * 4);
  int4*   ep    = (int4*)  alloc((size_t)EE * 16);
  int*    rowp  = (int*)   alloc((size_t)(NN + 1) * 4);
  int*    cnti  = (int*)   alloc((size_t)NN * 4);
  int*    fill  = (int*)   alloc((size_t)NN * 4);
  float*  wdeg  = (float*) alloc((size_t)NN * 4);
  float*  cntf  = (float*) alloc((size_t)NN * 4);
  float*  scales= (float*) alloc((size_t)NN * 2 * 4);
  float*  query = (float*) alloc((size_t)BD * 4);
  float*  stats = (float*) alloc(256);

  hipMemsetAsync(cnti, 0, (size_t)NN * 4, stream);
  hipMemsetAsync(fill, 0, (size_t)NN * 4, stream);
  hipMemsetAsync(wdeg, 0, (size_t)NN * 4, stream);
  hipMemsetAsync(h0,   0, (size_t)NN * BD * 2, stream);

  hist_kernel   <<<(EE + 255) / 256, 256, 0, stream>>>(node_out, ew, cnti, wdeg);
  scan_kernel   <<<1, 1024, 0, stream>>>(cnti, rowp, wdeg, stats, cntf);
  scales_kernel <<<(NN + 255) / 256, 256, 0, stream>>>(wdeg, stats, scales);
  scatter_kernel<<<(EE + 255) / 256, 256, 0, stream>>>(node_in, node_out, relation, ew,
                                                       rowp, fill, ep);
  init_kernel   <<<1, 128, 0, stream>>>(h_index, r_index, qemb, query, h0);
  wvbuild_kernel<<<(LL * WVF + 255) / 256, 256, 0, stream>>>(linW, Wv);

  __half* hin = h0; __half* hout = h1;
  for (int l = 0; l < LL; ++l) {
    relin_kernel<<<(R2C * BD + 255) / 256, 256, 0, stream>>>(
        query, relW + (size_t)l * DD * R2C * DD, relB + (size_t)l * R2C * DD, relIn);
    layer_kernel<<<NN / NPB, 128, 0, stream>>>(
        hin, hout, relIn, ep, rowp, cntf, scales,
        (const float4*)(Wv + (size_t)l * WVF),
        linB + (size_t)l * DD, h_index, query);
    __half* tmp = hin; hin = hout; hout = tmp;
  }
  mlp_kernel<<<(NN + 7) / 8, 128, 0, stream>>>(hin, query, W1, b1, W2, b2, out);
}

// Round 6
// 604.860 us; speedup vs baseline: 2.1028x; 1.3459x over previous
//
#include <hip/hip_runtime.h>
#include <hip/hip_fp16.h>

#define NN  25000
#define EE  500000
#define BB  4
#define DD  32
#define LL  4
#define R2C 474
#define BD  128      // B*D
#define THD 416      // 13*D
#define EPSF 1e-6f
#define NPB 4        // nodes per linear block
#define RP  164      // padded raw-stat row (164%32=4 -> conflict-free b128)
#define WVF 13312    // floats per layer of packed W: (8 + 3*32) groups * 32d * 4

// ---------------- CSR build ----------------
__global__ __launch_bounds__(256) void hist_kernel(const int* __restrict__ node_out,
                                                   const float* __restrict__ ew,
                                                   int* __restrict__ cnt,
                                                   float* __restrict__ wdeg) {
  int e = blockIdx.x * 256 + threadIdx.x;
  if (e < EE) {
    int d = node_out[e];
    atomicAdd(&cnt[d], 1);
    atomicAdd(&wdeg[d], ew[e]);
  }
}

__global__ __launch_bounds__(1024) void scan_kernel(const int* __restrict__ cnt,
                                                    int* __restrict__ rowp,
                                                    const float* __restrict__ wdeg,
                                                    float* __restrict__ stats,
                                                    float* __restrict__ cntf) {
  __shared__ int   part[1024];
  __shared__ float fpart[1024];
  int t = threadIdx.x;
  const int per = (NN + 1023) / 1024;   // 25
  int beg = t * per, end = min(beg + per, NN);
  int s = 0; float ls = 0.f;
  for (int i = beg; i < end; ++i) { s += cnt[i]; ls += logf(wdeg[i] + 1.0f); }
  part[t] = s; fpart[t] = ls;
  __syncthreads();
  for (int off = 1; off < 1024; off <<= 1) {
    int   v  = (t >= off) ? part[t - off]  : 0;
    float fv = (t >= off) ? fpart[t - off] : 0.f;
    __syncthreads();
    part[t] += v; fpart[t] += fv;
    __syncthreads();
  }
  int run = part[t] - s;
  for (int i = beg; i < end; ++i) {
    rowp[i] = run; run += cnt[i];
    cntf[i] = (float)(cnt[i] + 1);      // indeg + self entry
  }
  if (t == 1023) { rowp[NN] = part[1023]; stats[0] = fpart[1023]; }
}

__global__ __launch_bounds__(256) void scales_kernel(const float* __restrict__ wdeg,
                                                     const float* __restrict__ stats,
                                                     float* __restrict__ scales) {
  int n = blockIdx.x * 256 + threadIdx.x;
  if (n >= NN) return;
  float mean = stats[0] / (float)NN;
  float sc = logf(wdeg[n] + 1.0f) / mean;
  scales[n * 2 + 0] = sc;
  scales[n * 2 + 1] = 1.0f / fmaxf(sc, 0.01f);
}

// pack each edge as {node_in, relation, w_bits, 0}
__global__ __launch_bounds__(256) void scatter_kernel(const int* __restrict__ node_in,
                                                      const int* __restrict__ node_out,
                                                      const int* __restrict__ relation,
                                                      const float* __restrict__ ew,
                                                      const int* __restrict__ rowp,
                                                      int* __restrict__ fill,
                                                      int4* __restrict__ ep) {
  int e = blockIdx.x * 256 + threadIdx.x;
  if (e >= EE) return;
  int dn = node_out[e];
  int pos = rowp[dn] + atomicAdd(&fill[dn], 1);
  ep[pos] = make_int4(node_in[e], relation[e], __float_as_int(ew[e]), 0);
}

// query gather + boundary placement (h0 pre-zeroed; fp16 zero == 0x0000)
__global__ __launch_bounds__(128) void init_kernel(const int* __restrict__ h_index,
                                                   const int* __restrict__ r_index,
                                                   const float* __restrict__ qemb,
                                                   float* __restrict__ query,
                                                   __half* __restrict__ h0) {
  int t = threadIdx.x; int b = t >> 5, d = t & 31;
  float qv = qemb[r_index[b] * DD + d];
  query[t] = qv;
  h0[h_index[b] * BD + t] = __float2half(qv);
}

// rel_in[r][b][d] = query[b] . rel_W[l][:, r*D+d] + rel_b[l][r*D+d]   (fp16 out)
__global__ __launch_bounds__(256) void relin_kernel(const float* __restrict__ query,
                                                    const float* __restrict__ relW,
                                                    const float* __restrict__ relB,
                                                    __half* __restrict__ relIn) {
  int o = blockIdx.x * 256 + threadIdx.x;
  if (o >= R2C * BD) return;
  int r = o >> 7; int b = (o >> 5) & 3; int d = o & 31;
  int col = r * DD + d;
  float acc = relB[col];
  #pragma unroll
  for (int k = 0; k < DD; ++k)
    acc = fmaf(query[b * DD + k], relW[(size_t)k * (R2C * DD) + col], acc);
  relIn[o] = __float2half(acc);
}

// Pack lin_W into slabs, float4 records [g][d][c], g in [0,104):
//   g<8:         hidden slab, k = g*4+c, wrow = k
//   g=8+m*32+kg: scale slab m (0..2), q = kg*4+c, si=q>>5, df=q&31,
//                wrow = 32 + (df*4+si)*3 + m
// Combine: out = accH + acc0 + sc1*acc1 + sc2*acc2
__global__ __launch_bounds__(256) void wvbuild_kernel(const float* __restrict__ linW,
                                                      float* __restrict__ Wv) {
  int idx = blockIdx.x * 256 + threadIdx.x;
  if (idx >= LL * WVF) return;
  int c = idx & 3;
  int d = (idx >> 2) & 31;
  int g = (idx >> 7) % 104;
  int l = idx / WVF;
  int wrow;
  if (g < 8) {
    wrow = g * 4 + c;
  } else {
    int gm = g - 8; int m = gm >> 5; int kg = gm & 31;
    int q = kg * 4 + c; int si = q >> 5, df = q & 31;
    wrow = DD + (df * 4 + si) * 3 + m;
  }
  Wv[idx] = linW[(size_t)l * THD * DD + (size_t)wrow * DD + c * 0 + d];
}

// ---------------- phase 1: gather-reduce PNA stats ----------------
// One 64-lane wave per node; each lane owns a half2 (2 of the 128 (b,d)
// slots), so one wave-load covers a whole row. No LDS, minimal VGPR ->
// max waves for latency hiding. Stats written fp16:
// statsH[n][s][128slots], s = {mean, max, min, std}.
__global__ __launch_bounds__(256) void gather_kernel(const __half2* __restrict__ hin2,
                                                     const __half2* __restrict__ rel2,
                                                     const int4* __restrict__ ep,
                                                     const int* __restrict__ rowp,
                                                     const float* __restrict__ cntf,
                                                     const int* __restrict__ h_index,
                                                     const float* __restrict__ query,
                                                     __half2* __restrict__ statsH) {
  const int lane = threadIdx.x & 63;
  const int n = blockIdx.x * 4 + (threadIdx.x >> 6);   // NN % 4 == 0
  const int b = lane >> 4;
  const int d0 = (lane & 15) * 2;
  const float q0 = query[b * 32 + d0], q1 = query[b * 32 + d0 + 1];
  const int hb = h_index[b];
  const int beg = rowp[n], end = rowp[n + 1];
  const float mb0 = (n == hb) ? q0 : 0.f;
  const float mb1 = (n == hb) ? q1 : 0.f;
  float sa0 = mb0, qa0 = mb0 * mb0, mx0 = mb0, mn0 = mb0;
  float sa1 = mb1, qa1 = mb1 * mb1, mx1 = mb1, mn1 = mb1;
  int p = beg;
  const int pend = beg + ((end - beg) & ~3);
  if (p < pend) {
    int4 e0 = ep[p], e1 = ep[p + 1], e2 = ep[p + 2], e3 = ep[p + 3];
    for (;;) {
      __half2 h0v = hin2[(unsigned)e0.x * 64 + lane];
      __half2 r0v = rel2[(unsigned)e0.y * 64 + lane];
      __half2 h1v = hin2[(unsigned)e1.x * 64 + lane];
      __half2 r1v = rel2[(unsigned)e1.y * 64 + lane];
      __half2 h2v = hin2[(unsigned)e2.x * 64 + lane];
      __half2 r2v = rel2[(unsigned)e2.y * 64 + lane];
      __half2 h3v = hin2[(unsigned)e3.x * 64 + lane];
      __half2 r3v = rel2[(unsigned)e3.y * 64 + lane];
      const int pn = p + 4;
      int4 f0, f1, f2, f3;
      if (pn < pend) { f0 = ep[pn]; f1 = ep[pn + 1]; f2 = ep[pn + 2]; f3 = ep[pn + 3]; }
      float2 hf, rf; float m0, m1, mw0, mw1, w;
      w = __int_as_float(e0.z);
      hf = __half22float2(h0v); rf = __half22float2(r0v);
      m0 = rf.x * hf.x; mw0 = m0 * w; m1 = rf.y * hf.y; mw1 = m1 * w;
      sa0 += mw0; qa0 = fmaf(m0, mw0, qa0); mx0 = fmaxf(mx0, mw0); mn0 = fminf(mn0, mw0);
      sa1 += mw1; qa1 = fmaf(m1, mw1, qa1); mx1 = fmaxf(mx1, mw1); mn1 = fminf(mn1, mw1);
      w = __int_as_float(e1.z);
      hf = __half22float2(h1v); rf = __half22float2(r1v);
      m0 = rf.x * hf.x; mw0 = m0 * w; m1 = rf.y * hf.y; mw1 = m1 * w;
      sa0 += mw0; qa0 = fmaf(m0, mw0, qa0); mx0 = fmaxf(mx0, mw0); mn0 = fminf(mn0, mw0);
      sa1 += mw1; qa1 = fmaf(m1, mw1, qa1); mx1 = fmaxf(mx1, mw1); mn1 = fminf(mn1, mw1);
      w = __int_as_float(e2.z);
      hf = __half22float2(h2v); rf = __half22float2(r2v);
      m0 = rf.x * hf.x; mw0 = m0 * w; m1 = rf.y * hf.y; mw1 = m1 * w;
      sa0 += mw0; qa0 = fmaf(m0, mw0, qa0); mx0 = fmaxf(mx0, mw0); mn0 = fminf(mn0, mw0);
      sa1 += mw1; qa1 = fmaf(m1, mw1, qa1); mx1 = fmaxf(mx1, mw1); mn1 = fminf(mn1, mw1);
      w = __int_as_float(e3.z);
      hf = __half22float2(h3v); rf = __half22float2(r3v);
      m0 = rf.x * hf.x; mw0 = m0 * w; m1 = rf.y * hf.y; mw1 = m1 * w;
      sa0 += mw0; qa0 = fmaf(m0, mw0, qa0); mx0 = fmaxf(mx0, mw0); mn0 = fminf(mn0, mw0);
      sa1 += mw1; qa1 = fmaf(m1, mw1, qa1); mx1 = fmaxf(mx1, mw1); mn1 = fminf(mn1, mw1);
      p = pn;
      if (p >= pend) break;
      e0 = f0; e1 = f1; e2 = f2; e3 = f3;
    }
  }
  for (; p < end; ++p) {
    int4 e = ep[p];
    __half2 hv = hin2[(unsigned)e.x * 64 + lane];
    __half2 rv = rel2[(unsigned)e.y * 64 + lane];
    float w = __int_as_float(e.z);
    float2 hf = __half22float2(hv), rf = __half22float2(rv);
    float m0 = rf.x * hf.x, mw0 = m0 * w;
    float m1 = rf.y * hf.y, mw1 = m1 * w;
    sa0 += mw0; qa0 = fmaf(m0, mw0, qa0); mx0 = fmaxf(mx0, mw0); mn0 = fminf(mn0, mw0);
    sa1 += mw1; qa1 = fmaf(m1, mw1, qa1); mx1 = fmaxf(mx1, mw1); mn1 = fminf(mn1, mw1);
  }
  const float invc = 1.0f / cntf[n];
  const float mean0 = sa0 * invc, mean1 = sa1 * invc;
  const float sd0 = sqrtf(fmaxf(qa0 * invc - mean0 * mean0, EPSF));
  const float sd1 = sqrtf(fmaxf(qa1 * invc - mean1 * mean1, EPSF));
  __half2* sp = statsH + (unsigned)n * 256 + lane;
  sp[0]   = __floats2half2_rn(mean0, mean1);
  sp[64]  = __floats2half2_rn(mx0, mx1);
  sp[128] = __floats2half2_rn(mn0, mn1);
  sp[192] = __floats2half2_rn(sd0, sd1);
}

// ---------------- phase 2: 416->32 linear (slab form) ----------------
// Stage stats+hidden for NPB=4 nodes into padded LDS, then one shared pass
// over the 104 packed-W float4 groups feeds 4 nodes x 4 slab accumulators.
__global__ __launch_bounds__(128) void linear_kernel(const __half* __restrict__ hinh,
                                                     __half* __restrict__ houth,
                                                     const __half* __restrict__ statsH,
                                                     const float* __restrict__ scales,
                                                     const float4* __restrict__ wp,
                                                     const float* __restrict__ bias) {
  __shared__ float raw[NPB * BB][RP];
  const int t = threadIdx.x;
  const int b = t >> 5, d = t & 31;
  const int n0 = blockIdx.x * NPB;      // NN % NPB == 0
  // stage hidden slab: 4 nodes x 128 halfs, 4 halfs/thread
  {
    const int n_ = t >> 5;
    const int c  = (t & 31) * 4;
    const int b_ = c >> 5, d_ = c & 31;
    const __half* hp = hinh + (unsigned)(n0 + n_) * BD + c;
    float4 hv = make_float4(__half2float(hp[0]), __half2float(hp[1]),
                            __half2float(hp[2]), __half2float(hp[3]));
    *(float4*)&raw[n_ * BB + b_][d_] = hv;
  }
  // stage stats: 4 nodes x 512 halfs = 2048 halfs, 16/thread (2 x 8-half chunks)
  #pragma unroll
  for (int it = 0; it < 2; ++it) {
    const int flat = (it * 128 + t) * 8;
    const int n_ = flat >> 9;
    const int r  = flat & 511;            // s*128 + slot
    const int s  = r >> 7, slot = r & 127;
    const int b_ = slot >> 5, d_ = slot & 31;
    const __half2* sp = (const __half2*)(statsH + (unsigned)(n0 + n_) * 512 + r);
    float2 v0 = __half22float2(sp[0]);
    float2 v1 = __half22float2(sp[1]);
    float2 v2 = __half22float2(sp[2]);
    float2 v3 = __half22float2(sp[3]);
    float* dst = &raw[n_ * BB + b_][32 + s * 32 + d_];
    *(float4*)dst       = make_float4(v0.x, v0.y, v1.x, v1.y);
    *(float4*)(dst + 4) = make_float4(v2.x, v2.y, v3.x, v3.y);
  }
  __syncthreads();

  float accH[NPB] = {0.f, 0.f, 0.f, 0.f};
  float acc0[NPB] = {0.f, 0.f, 0.f, 0.f};
  float acc1[NPB] = {0.f, 0.f, 0.f, 0.f};
  float acc2[NPB] = {0.f, 0.f, 0.f, 0.f};
  #pragma unroll
  for (int g = 0; g < 8; ++g) {
    float4 wv = wp[g * 32 + d];
    #pragma unroll
    for (int ni = 0; ni < NPB; ++ni) {
      float4 f = *(const float4*)&raw[ni * BB + b][g * 4];
      accH[ni] = fmaf(f.x, wv.x, fmaf(f.y, wv.y, fmaf(f.z, wv.z, fmaf(f.w, wv.w, accH[ni]))));
    }
  }
  #pragma unroll 2
  for (int kg = 0; kg < 32; ++kg) {
    float4 w0 = wp[256 + 0 * 1024 + kg * 32 + d];
    float4 w1 = wp[256 + 1 * 1024 + kg * 32 + d];
    float4 w2 = wp[256 + 2 * 1024 + kg * 32 + d];
    #pragma unroll
    for (int ni = 0; ni < NPB; ++ni) {
      float4 f = *(const float4*)&raw[ni * BB + b][32 + kg * 4];
      acc0[ni] = fmaf(f.x, w0.x, fmaf(f.y, w0.y, fmaf(f.z, w0.z, fmaf(f.w, w0.w, acc0[ni]))));
      acc1[ni] = fmaf(f.x, w1.x, fmaf(f.y, w1.y, fmaf(f.z, w1.z, fmaf(f.w, w1.w, acc1[ni]))));
      acc2[ni] = fmaf(f.x, w2.x, fmaf(f.y, w2.y, fmaf(f.z, w2.z, fmaf(f.w, w2.w, acc2[ni]))));
    }
  }
  const float bj = bias[d];
  #pragma unroll
  for (int ni = 0; ni < NPB; ++ni) {
    const int n = n0 + ni;
    const float sc1 = scales[n * 2 + 0], sc2 = scales[n * 2 + 1];
    float o = bj + accH[ni] + acc0[ni] + sc1 * acc1[ni] + sc2 * acc2[ni];
    houth[(unsigned)n * BD + t] = __float2half(fmaxf(o, 0.f));
  }
}

// final MLP: [hidden(fp16), query] (64) -> relu(64) -> 1, out[b*N + n]
__global__ __launch_bounds__(128) void mlp_kernel(const __half* __restrict__ hinh,
                                                  const float* __restrict__ query,
                                                  const float* __restrict__ W1,
                                                  const float* __restrict__ b1,
                                                  const float* __restrict__ W2,
                                                  const float* __restrict__ b2,
                                                  float* __restrict__ out) {
  __shared__ float f2[BB][2 * DD];
  const int t = threadIdx.x;
  const int b = t >> 5, d = t & 31;
  const float qv = query[t];
  const float w2a = W2[d], w2b = W2[DD + d];
  const float b1a = b1[d], b1b = b1[DD + d];
  const float b2v = b2[0];
  const int NPBM = 8;
  int n0 = blockIdx.x * NPBM, n1 = min(n0 + NPBM, NN);
  for (int n = n0; n < n1; ++n) {
    f2[b][d]      = __half2float(hinh[(unsigned)n * BD + t]);
    f2[b][DD + d] = qv;
    float a0 = b1a, a1 = b1b;
    #pragma unroll
    for (int i = 0; i < 2 * DD; ++i) {
      float v = f2[b][i];
      a0 = fmaf(v, W1[i * 2 * DD + d], a0);
      a1 = fmaf(v, W1[i * 2 * DD + DD + d], a1);
    }
    a0 = fmaxf(a0, 0.f); a1 = fmaxf(a1, 0.f);
    float part = a0 * w2a + a1 * w2b;
    #pragma unroll
    for (int off = 16; off > 0; off >>= 1) part += __shfl_down(part, off, 32);
    if (d == 0) out[b * NN + n] = part + b2v;
  }
}

extern "C" void kernel_launch(void* const* d_in, const int* in_sizes, int n_in,
                              void* d_out, int out_size, void* d_ws, size_t ws_size,
                              hipStream_t stream) {
  const int*   node_in  = (const int*)d_in[0];
  const int*   node_out = (const int*)d_in[1];
  const int*   relation = (const int*)d_in[2];
  const float* ew       = (const float*)d_in[3];
  const int*   h_index  = (const int*)d_in[4];
  const int*   r_index  = (const int*)d_in[5];
  const float* qemb     = (const float*)d_in[6];
  const float* relW     = (const float*)d_in[7];
  const float* relB     = (const float*)d_in[8];
  const float* linW     = (const float*)d_in[9];
  const float* linB     = (const float*)d_in[10];
  const float* W1       = (const float*)d_in[11];
  const float* b1       = (const float*)d_in[12];
  const float* W2       = (const float*)d_in[13];
  const float* b2       = (const float*)d_in[14];
  float* out = (float*)d_out;

  char* ws = (char*)d_ws;
  size_t off = 0;
  auto alloc = [&](size_t bytes) -> char* {
    char* p = ws + off;
    off += (bytes + 255) & ~(size_t)255;
    return p;
  };
  __half* h0     = (__half*)alloc((size_t)NN * BD * 2);
  __half* h1     = (__half*)alloc((size_t)NN * BD * 2);
  __half* relIn  = (__half*)alloc((size_t)R2C * BD * 2);
  __half* statsH = (__half*)alloc((size_t)NN * 512 * 2);
  float*  Wv     = (float*) alloc((size_t)LL * WVF * 4);
  int4*   ep     = (int4*)  alloc((size_t)EE * 16);
  int*    rowp   = (int*)   alloc((size_t)(NN + 1) * 4);
  int*    cnti   = (int*)   alloc((size_t)NN * 4);
  int*    fill   = (int*)   alloc((size_t)NN * 4);
  float*  wdeg   = (float*) alloc((size_t)NN * 4);
  float*  cntf   = (float*) alloc((size_t)NN * 4);
  float*  scales = (float*) alloc((size_t)NN * 2 * 4);
  float*  query  = (float*) alloc((size_t)BD * 4);
  float*  stats  = (float*) alloc(256);

  hipMemsetAsync(cnti, 0, (size_t)NN * 4, stream);
  hipMemsetAsync(fill, 0, (size_t)NN * 4, stream);
  hipMemsetAsync(wdeg, 0, (size_t)NN * 4, stream);
  hipMemsetAsync(h0,   0, (size_t)NN * BD * 2, stream);

  hist_kernel   <<<(EE + 255) / 256, 256, 0, stream>>>(node_out, ew, cnti, wdeg);
  scan_kernel   <<<1, 1024, 0, stream>>>(cnti, rowp, wdeg, stats, cntf);
  scales_kernel <<<(NN + 255) / 256, 256, 0, stream>>>(wdeg, stats, scales);
  scatter_kernel<<<(EE + 255) / 256, 256, 0, stream>>>(node_in, node_out, relation, ew,
                                                       rowp, fill, ep);
  init_kernel   <<<1, 128, 0, stream>>>(h_index, r_index, qemb, query, h0);
  wvbuild_kernel<<<(LL * WVF + 255) / 256, 256, 0, stream>>>(linW, Wv);

  __half* hin = h0; __half* hout = h1;
  for (int l = 0; l < LL; ++l) {
    relin_kernel<<<(R2C * BD + 255) / 256, 256, 0, stream>>>(
        query, relW + (size_t)l * DD * R2C * DD, relB + (size_t)l * R2C * DD, relIn);
    gather_kernel<<<NN / 4, 256, 0, stream>>>(
        (const __half2*)hin, (const __half2*)relIn, ep, rowp, cntf,
        h_index, query, (__half2*)statsH);
    linear_kernel<<<NN / NPB, 128, 0, stream>>>(
        hin, hout, statsH, scales, (const float4*)(Wv + (size_t)l * WVF),
        linB + (size_t)l * DD);
    __half* tmp = hin; hin = hout; hout = tmp;
  }
  mlp_kernel<<<(NN + 7) / 8, 128, 0, stream>>>(hin, query, W1, b1, W2, b2, out);
}

// Round 7
// 435.251 us; speedup vs baseline: 2.9222x; 1.3897x over previous
//
#include <hip/hip_runtime.h>
#include <hip/hip_fp16.h>

#define NN  25000
#define EE  500000
#define BB  4
#define DD  32
#define LL  4
#define R2C 474
#define BD  128      // B*D
#define THD 416      // 13*D
#define EPSF 1e-6f
#define WMH 13312    // halfs per layer of MFMA-packed W: 13 t * 2 nt * 64 * 8

typedef _Float16 half8 __attribute__((ext_vector_type(8)));
typedef float    f32x4 __attribute__((ext_vector_type(4)));

// ---------------- CSR build ----------------
__global__ __launch_bounds__(256) void hist_kernel(const int* __restrict__ node_out,
                                                   const float* __restrict__ ew,
                                                   int* __restrict__ cnt,
                                                   float* __restrict__ wdeg) {
  int e = blockIdx.x * 256 + threadIdx.x;
  if (e < EE) {
    int d = node_out[e];
    atomicAdd(&cnt[d], 1);
    atomicAdd(&wdeg[d], ew[e]);
  }
}

__global__ __launch_bounds__(1024) void scan_kernel(const int* __restrict__ cnt,
                                                    int* __restrict__ rowp,
                                                    const float* __restrict__ wdeg,
                                                    float* __restrict__ stats,
                                                    float* __restrict__ cntf) {
  __shared__ int   part[1024];
  __shared__ float fpart[1024];
  int t = threadIdx.x;
  const int per = (NN + 1023) / 1024;   // 25
  int beg = t * per, end = min(beg + per, NN);
  int s = 0; float ls = 0.f;
  for (int i = beg; i < end; ++i) { s += cnt[i]; ls += logf(wdeg[i] + 1.0f); }
  part[t] = s; fpart[t] = ls;
  __syncthreads();
  for (int off = 1; off < 1024; off <<= 1) {
    int   v  = (t >= off) ? part[t - off]  : 0;
    float fv = (t >= off) ? fpart[t - off] : 0.f;
    __syncthreads();
    part[t] += v; fpart[t] += fv;
    __syncthreads();
  }
  int run = part[t] - s;
  for (int i = beg; i < end; ++i) {
    rowp[i] = run; run += cnt[i];
    cntf[i] = (float)(cnt[i] + 1);      // indeg + self entry
  }
  if (t == 1023) { rowp[NN] = part[1023]; stats[0] = fpart[1023]; }
}

__global__ __launch_bounds__(256) void scales_kernel(const float* __restrict__ wdeg,
                                                     const float* __restrict__ stats,
                                                     float* __restrict__ scales) {
  int n = blockIdx.x * 256 + threadIdx.x;
  if (n >= NN) return;
  float mean = stats[0] / (float)NN;
  float sc = logf(wdeg[n] + 1.0f) / mean;
  scales[n * 2 + 0] = sc;
  scales[n * 2 + 1] = 1.0f / fmaxf(sc, 0.01f);
}

// pack each edge as {node_in, relation, w_bits, 0}
__global__ __launch_bounds__(256) void scatter_kernel(const int* __restrict__ node_in,
                                                      const int* __restrict__ node_out,
                                                      const int* __restrict__ relation,
                                                      const float* __restrict__ ew,
                                                      const int* __restrict__ rowp,
                                                      int* __restrict__ fill,
                                                      int4* __restrict__ ep) {
  int e = blockIdx.x * 256 + threadIdx.x;
  if (e >= EE) return;
  int dn = node_out[e];
  int pos = rowp[dn] + atomicAdd(&fill[dn], 1);
  ep[pos] = make_int4(node_in[e], relation[e], __float_as_int(ew[e]), 0);
}

// query gather + boundary placement (h0 pre-zeroed; fp16 zero == 0x0000)
__global__ __launch_bounds__(128) void init_kernel(const int* __restrict__ h_index,
                                                   const int* __restrict__ r_index,
                                                   const float* __restrict__ qemb,
                                                   float* __restrict__ query,
                                                   __half* __restrict__ h0) {
  int t = threadIdx.x; int b = t >> 5, d = t & 31;
  float qv = qemb[r_index[b] * DD + d];
  query[t] = qv;
  h0[h_index[b] * BD + t] = __float2half(qv);
}

// rel_in[r][b][d] = query[b] . rel_W[l][:, r*D+d] + rel_b[l][r*D+d]   (fp16 out)
__global__ __launch_bounds__(256) void relin_kernel(const float* __restrict__ query,
                                                    const float* __restrict__ relW,
                                                    const float* __restrict__ relB,
                                                    __half* __restrict__ relIn) {
  int o = blockIdx.x * 256 + threadIdx.x;
  if (o >= R2C * BD) return;
  int r = o >> 7; int b = (o >> 5) & 3; int d = o & 31;
  int col = r * DD + d;
  float acc = relB[col];
  #pragma unroll
  for (int k = 0; k < DD; ++k)
    acc = fmaf(query[b * DD + k], relW[(size_t)k * (R2C * DD) + col], acc);
  relIn[o] = __float2half(acc);
}

// Pack lin_W into MFMA B-fragment order, fp16:
// Wm[l][t][nt][lane][j]; k = t*32 + (lane>>4)*8 + j; n = nt*16 + (lane&15).
// Feature k-order: k<32 hidden (wrow=k); else kk=k-32: slab=kk>>7, s=(kk>>5)&3,
// dd=kk&31, wrow = 32 + (dd*4+s)*3 + slab.
__global__ __launch_bounds__(256) void wmbuild_kernel(const float* __restrict__ linW,
                                                      _Float16* __restrict__ Wm) {
  int idx = blockIdx.x * 256 + threadIdx.x;
  if (idx >= LL * WMH) return;
  int l = idx / WMH, rest = idx % WMH;
  int t = rest >> 10;
  int nt = (rest >> 9) & 1;
  int L = (rest >> 3) & 63;
  int j = rest & 7;
  int k = t * 32 + (L >> 4) * 8 + j;
  int n = nt * 16 + (L & 15);
  int wrow;
  if (k < 32) wrow = k;
  else {
    int kk = k - 32;
    int slab = kk >> 7, s = (kk >> 5) & 3, dd = kk & 31;
    wrow = DD + (dd * 4 + s) * 3 + slab;
  }
  Wm[idx] = (_Float16)linW[(size_t)l * THD * DD + (size_t)wrow * DD + n];
}

// ---------------- phase 1: gather-reduce PNA stats ----------------
// One 64-lane wave per node; lane owns a half2 (2 of 128 (b,d) slots).
// statsH[n][s][128slots] fp16, s = {mean, max, min, std}.
__global__ __launch_bounds__(256) void gather_kernel(const __half2* __restrict__ hin2,
                                                     const __half2* __restrict__ rel2,
                                                     const int4* __restrict__ ep,
                                                     const int* __restrict__ rowp,
                                                     const float* __restrict__ cntf,
                                                     const int* __restrict__ h_index,
                                                     const float* __restrict__ query,
                                                     __half2* __restrict__ statsH) {
  const int lane = threadIdx.x & 63;
  const int n = blockIdx.x * 4 + (threadIdx.x >> 6);   // NN % 4 == 0
  const int b = lane >> 4;
  const int d0 = (lane & 15) * 2;
  const float q0 = query[b * 32 + d0], q1 = query[b * 32 + d0 + 1];
  const int hb = h_index[b];
  const int beg = rowp[n], end = rowp[n + 1];
  const float mb0 = (n == hb) ? q0 : 0.f;
  const float mb1 = (n == hb) ? q1 : 0.f;
  float sa0 = mb0, qa0 = mb0 * mb0, mx0 = mb0, mn0 = mb0;
  float sa1 = mb1, qa1 = mb1 * mb1, mx1 = mb1, mn1 = mb1;
  int p = beg;
  const int pend = beg + ((end - beg) & ~3);
  if (p < pend) {
    int4 e0 = ep[p], e1 = ep[p + 1], e2 = ep[p + 2], e3 = ep[p + 3];
    for (;;) {
      __half2 h0v = hin2[(unsigned)e0.x * 64 + lane];
      __half2 r0v = rel2[(unsigned)e0.y * 64 + lane];
      __half2 h1v = hin2[(unsigned)e1.x * 64 + lane];
      __half2 r1v = rel2[(unsigned)e1.y * 64 + lane];
      __half2 h2v = hin2[(unsigned)e2.x * 64 + lane];
      __half2 r2v = rel2[(unsigned)e2.y * 64 + lane];
      __half2 h3v = hin2[(unsigned)e3.x * 64 + lane];
      __half2 r3v = rel2[(unsigned)e3.y * 64 + lane];
      const int pn = p + 4;
      int4 f0, f1, f2, f3;
      if (pn < pend) { f0 = ep[pn]; f1 = ep[pn + 1]; f2 = ep[pn + 2]; f3 = ep[pn + 3]; }
      float2 hf, rf; float m0, m1, mw0, mw1, w;
      w = __int_as_float(e0.z);
      hf = __half22float2(h0v); rf = __half22float2(r0v);
      m0 = rf.x * hf.x; mw0 = m0 * w; m1 = rf.y * hf.y; mw1 = m1 * w;
      sa0 += mw0; qa0 = fmaf(m0, mw0, qa0); mx0 = fmaxf(mx0, mw0); mn0 = fminf(mn0, mw0);
      sa1 += mw1; qa1 = fmaf(m1, mw1, qa1); mx1 = fmaxf(mx1, mw1); mn1 = fminf(mn1, mw1);
      w = __int_as_float(e1.z);
      hf = __half22float2(h1v); rf = __half22float2(r1v);
      m0 = rf.x * hf.x; mw0 = m0 * w; m1 = rf.y * hf.y; mw1 = m1 * w;
      sa0 += mw0; qa0 = fmaf(m0, mw0, qa0); mx0 = fmaxf(mx0, mw0); mn0 = fminf(mn0, mw0);
      sa1 += mw1; qa1 = fmaf(m1, mw1, qa1); mx1 = fmaxf(mx1, mw1); mn1 = fminf(mn1, mw1);
      w = __int_as_float(e2.z);
      hf = __half22float2(h2v); rf = __half22float2(r2v);
      m0 = rf.x * hf.x; mw0 = m0 * w; m1 = rf.y * hf.y; mw1 = m1 * w;
      sa0 += mw0; qa0 = fmaf(m0, mw0, qa0); mx0 = fmaxf(mx0, mw0); mn0 = fminf(mn0, mw0);
      sa1 += mw1; qa1 = fmaf(m1, mw1, qa1); mx1 = fmaxf(mx1, mw1); mn1 = fminf(mn1, mw1);
      w = __int_as_float(e3.z);
      hf = __half22float2(h3v); rf = __half22float2(r3v);
      m0 = rf.x * hf.x; mw0 = m0 * w; m1 = rf.y * hf.y; mw1 = m1 * w;
      sa0 += mw0; qa0 = fmaf(m0, mw0, qa0); mx0 = fmaxf(mx0, mw0); mn0 = fminf(mn0, mw0);
      sa1 += mw1; qa1 = fmaf(m1, mw1, qa1); mx1 = fmaxf(mx1, mw1); mn1 = fminf(mn1, mw1);
      p = pn;
      if (p >= pend) break;
      e0 = f0; e1 = f1; e2 = f2; e3 = f3;
    }
  }
  for (; p < end; ++p) {
    int4 e = ep[p];
    __half2 hv = hin2[(unsigned)e.x * 64 + lane];
    __half2 rv = rel2[(unsigned)e.y * 64 + lane];
    float w = __int_as_float(e.z);
    float2 hf = __half22float2(hv), rf = __half22float2(rv);
    float m0 = rf.x * hf.x, mw0 = m0 * w;
    float m1 = rf.y * hf.y, mw1 = m1 * w;
    sa0 += mw0; qa0 = fmaf(m0, mw0, qa0); mx0 = fmaxf(mx0, mw0); mn0 = fminf(mn0, mw0);
    sa1 += mw1; qa1 = fmaf(m1, mw1, qa1); mx1 = fmaxf(mx1, mw1); mn1 = fminf(mn1, mw1);
  }
  const float invc = 1.0f / cntf[n];
  const float mean0 = sa0 * invc, mean1 = sa1 * invc;
  const float sd0 = sqrtf(fmaxf(qa0 * invc - mean0 * mean0, EPSF));
  const float sd1 = sqrtf(fmaxf(qa1 * invc - mean1 * mean1, EPSF));
  __half2* sp = statsH + (unsigned)n * 256 + lane;
  sp[0]   = __floats2half2_rn(mean0, mean1);
  sp[64]  = __floats2half2_rn(mx0, mx1);
  sp[128] = __floats2half2_rn(mn0, mn1);
  sp[192] = __floats2half2_rn(sd0, sd1);
}

// ---------------- phase 2: 416->32 linear via MFMA ----------------
// One wave = 16-row tile (4 nodes x 4 queries). 13 K-steps of 32 features.
// A-fragment: lane L = row m=L&15 -> (n=nbase+(m>>2), b=m&3); 8 halfs loaded
// straight from hinh/statsH (aligned dwordx4), degree-scale folded in fp16.
// B-fragment: pre-packed Wm, 16B/lane/step, L1-resident.
// D: col=lane&15, row=(lane>>4)*4+reg  ->  bias+relu -> fp16 store.
__global__ __launch_bounds__(128) void mfma_linear_kernel(const _Float16* __restrict__ hinh,
                                                          __half* __restrict__ houth,
                                                          const _Float16* __restrict__ statsH,
                                                          const float* __restrict__ scales,
                                                          const _Float16* __restrict__ Wm,
                                                          const float* __restrict__ bias) {
  const int lane = threadIdx.x & 63;
  const int wid  = threadIdx.x >> 6;
  const int nbase = blockIdx.x * 8 + wid * 4;    // NN % 8 == 0
  const int m = lane & 15;
  const int q = lane >> 4;
  const int n = nbase + (m >> 2);
  const int b = m & 3;
  const _Float16 one = (_Float16)1.f;
  const _Float16 s1h = (_Float16)scales[n * 2 + 0];
  const _Float16 s2h = (_Float16)scales[n * 2 + 1];
  const _Float16* hsrc = hinh   + (unsigned)n * BD  + b * 32 + q * 8;
  const _Float16* ssrc = statsH + (unsigned)n * 512 + b * 32 + q * 8;

  f32x4 c0 = {0.f, 0.f, 0.f, 0.f};
  f32x4 c1 = {0.f, 0.f, 0.f, 0.f};
  #pragma unroll
  for (int t = 0; t < 13; ++t) {
    half8 a;
    if (t == 0) {
      a = *(const half8*)hsrc;
    } else {
      const int slab = (t - 1) >> 2, s = (t - 1) & 3;
      a = *(const half8*)(ssrc + s * 128);
      const _Float16 sc = (slab == 0) ? one : ((slab == 1) ? s1h : s2h);
      half8 sv = {sc, sc, sc, sc, sc, sc, sc, sc};
      a = a * sv;
    }
    half8 b0 = *(const half8*)(Wm + (unsigned)(t * 2 + 0) * 512 + lane * 8);
    half8 b1 = *(const half8*)(Wm + (unsigned)(t * 2 + 1) * 512 + lane * 8);
    c0 = __builtin_amdgcn_mfma_f32_16x16x32_f16(a, b0, c0, 0, 0, 0);
    c1 = __builtin_amdgcn_mfma_f32_16x16x32_f16(a, b1, c1, 0, 0, 0);
  }
  const int col = lane & 15;
  const float bj0 = bias[col], bj1 = bias[col + 16];
  #pragma unroll
  for (int i = 0; i < 4; ++i) {
    const int mr = q * 4 + i;
    const int nl = mr >> 2, bq = mr & 3;
    __half* dst = houth + (unsigned)(nbase + nl) * BD + bq * 32 + col;
    dst[0]  = __float2half(fmaxf(c0[i] + bj0, 0.f));
    dst[16] = __float2half(fmaxf(c1[i] + bj1, 0.f));
  }
}

// final MLP: [hidden(fp16), query] (64) -> relu(64) -> 1, out[b*N + n]
__global__ __launch_bounds__(128) void mlp_kernel(const __half* __restrict__ hinh,
                                                  const float* __restrict__ query,
                                                  const float* __restrict__ W1,
                                                  const float* __restrict__ b1,
                                                  const float* __restrict__ W2,
                                                  const float* __restrict__ b2,
                                                  float* __restrict__ out) {
  __shared__ float f2[BB][2 * DD];
  const int t = threadIdx.x;
  const int b = t >> 5, d = t & 31;
  const float qv = query[t];
  const float w2a = W2[d], w2b = W2[DD + d];
  const float b1a = b1[d], b1b = b1[DD + d];
  const float b2v = b2[0];
  const int NPBM = 8;
  int n0 = blockIdx.x * NPBM, n1 = min(n0 + NPBM, NN);
  for (int n = n0; n < n1; ++n) {
    f2[b][d]      = __half2float(hinh[(unsigned)n * BD + t]);
    f2[b][DD + d] = qv;
    float a0 = b1a, a1 = b1b;
    #pragma unroll
    for (int i = 0; i < 2 * DD; ++i) {
      float v = f2[b][i];
      a0 = fmaf(v, W1[i * 2 * DD + d], a0);
      a1 = fmaf(v, W1[i * 2 * DD + DD + d], a1);
    }
    a0 = fmaxf(a0, 0.f); a1 = fmaxf(a1, 0.f);
    float part = a0 * w2a + a1 * w2b;
    #pragma unroll
    for (int off = 16; off > 0; off >>= 1) part += __shfl_down(part, off, 32);
    if (d == 0) out[b * NN + n] = part + b2v;
  }
}

extern "C" void kernel_launch(void* const* d_in, const int* in_sizes, int n_in,
                              void* d_out, int out_size, void* d_ws, size_t ws_size,
                              hipStream_t stream) {
  const int*   node_in  = (const int*)d_in[0];
  const int*   node_out = (const int*)d_in[1];
  const int*   relation = (const int*)d_in[2];
  const float* ew       = (const float*)d_in[3];
  const int*   h_index  = (const int*)d_in[4];
  const int*   r_index  = (const int*)d_in[5];
  const float* qemb     = (const float*)d_in[6];
  const float* relW     = (const float*)d_in[7];
  const float* relB     = (const float*)d_in[8];
  const float* linW     = (const float*)d_in[9];
  const float* linB     = (const float*)d_in[10];
  const float* W1       = (const float*)d_in[11];
  const float* b1       = (const float*)d_in[12];
  const float* W2       = (const float*)d_in[13];
  const float* b2       = (const float*)d_in[14];
  float* out = (float*)d_out;

  char* ws = (char*)d_ws;
  size_t off = 0;
  auto alloc = [&](size_t bytes) -> char* {
    char* p = ws + off;
    off += (bytes + 255) & ~(size_t)255;
    return p;
  };
  __half*   h0     = (__half*)  alloc((size_t)NN * BD * 2);
  __half*   h1     = (__half*)  alloc((size_t)NN * BD * 2);
  __half*   relIn  = (__half*)  alloc((size_t)R2C * BD * 2);
  __half*   statsH = (__half*)  alloc((size_t)NN * 512 * 2);
  _Float16* Wm     = (_Float16*)alloc((size_t)LL * WMH * 2);
  int4*     ep     = (int4*)    alloc((size_t)EE * 16);
  int*      rowp   = (int*)     alloc((size_t)(NN + 1) * 4);
  int*      cnti   = (int*)     alloc((size_t)NN * 4);
  int*      fill   = (int*)     alloc((size_t)NN * 4);
  float*    wdeg   = (float*)   alloc((size_t)NN * 4);
  float*    cntf   = (float*)   alloc((size_t)NN * 4);
  float*    scales = (float*)   alloc((size_t)NN * 2 * 4);
  float*    query  = (float*)   alloc((size_t)BD * 4);
  float*    stats  = (float*)   alloc(256);

  hipMemsetAsync(cnti, 0, (size_t)NN * 4, stream);
  hipMemsetAsync(fill, 0, (size_t)NN * 4, stream);
  hipMemsetAsync(wdeg, 0, (size_t)NN * 4, stream);
  hipMemsetAsync(h0,   0, (size_t)NN * BD * 2, stream);

  hist_kernel   <<<(EE + 255) / 256, 256, 0, stream>>>(node_out, ew, cnti, wdeg);
  scan_kernel   <<<1, 1024, 0, stream>>>(cnti, rowp, wdeg, stats, cntf);
  scales_kernel <<<(NN + 255) / 256, 256, 0, stream>>>(wdeg, stats, scales);
  scatter_kernel<<<(EE + 255) / 256, 256, 0, stream>>>(node_in, node_out, relation, ew,
                                                       rowp, fill, ep);
  init_kernel   <<<1, 128, 0, stream>>>(h_index, r_index, qemb, query, h0);
  wmbuild_kernel<<<(LL * WMH + 255) / 256, 256, 0, stream>>>(linW, Wm);

  __half* hin = h0; __half* hout = h1;
  for (int l = 0; l < LL; ++l) {
    relin_kernel<<<(R2C * BD + 255) / 256, 256, 0, stream>>>(
        query, relW + (size_t)l * DD * R2C * DD, relB + (size_t)l * R2C * DD, relIn);
    gather_kernel<<<NN / 4, 256, 0, stream>>>(
        (const __half2*)hin, (const __half2*)relIn, ep, rowp, cntf,
        h_index, query, (__half2*)statsH);
    mfma_linear_kernel<<<NN / 8, 128, 0, stream>>>(
        (const _Float16*)hin, hout, (const _Float16*)statsH, scales,
        Wm + (size_t)l * WMH, linB + (size_t)l * DD);
    __half* tmp = hin; hin = hout; hout = tmp;
  }
  mlp_kernel<<<(NN + 7) / 8, 128, 0, stream>>>(hin, query, W1, b1, W2, b2, out);
}

// Round 8
// 366.704 us; speedup vs baseline: 3.4684x; 1.1869x over previous
//
#include <hip/hip_runtime.h>
#include <hip/hip_fp16.h>

#define NN  25000
#define EE  500000
#define BB  4
#define DD  32
#define LL  4
#define R2C 474
#define BD  128      // B*D
#define THD 416      // 13*D
#define EPSF 1e-6f
#define WMH 13312    // halfs per layer of MFMA-packed W: 13 t * 2 nt * 64 * 8

typedef _Float16 half8 __attribute__((ext_vector_type(8)));
typedef float    f32x4 __attribute__((ext_vector_type(4)));

// ---------------- histogram ----------------
__global__ __launch_bounds__(256) void hist_kernel(const int* __restrict__ node_out,
                                                   const float* __restrict__ ew,
                                                   int* __restrict__ cnt,
                                                   float* __restrict__ wdeg) {
  int e = blockIdx.x * 256 + threadIdx.x;
  if (e < EE) {
    int d = node_out[e];
    atomicAdd(&cnt[d], 1);
    atomicAdd(&wdeg[d], ew[e]);
  }
}

// ---------------- parallel segment allocation (order-free CSR) ----------------
// Segments need not be in node order -> atomic bump allocation replaces the
// serial prefix scan (was 60us single-block). Also computes cntf and the
// global sum of log(deg) via wave-aggregated float atomics.
__global__ __launch_bounds__(256) void prep_kernel(const int* __restrict__ cnt,
                                                   const float* __restrict__ wdeg,
                                                   int* __restrict__ base,
                                                   float* __restrict__ cntf,
                                                   int* __restrict__ gcnt,
                                                   float* __restrict__ logsum) {
  int n = blockIdx.x * 256 + threadIdx.x;
  if (n >= NN) return;
  int c = cnt[n];
  base[n] = atomicAdd(gcnt, c);
  cntf[n] = (float)(c + 1);             // indeg + self entry
  atomicAdd(logsum, logf(wdeg[n] + 1.0f));
}

__global__ __launch_bounds__(256) void scales_kernel(const float* __restrict__ wdeg,
                                                     const float* __restrict__ logsum,
                                                     float* __restrict__ scales) {
  int n = blockIdx.x * 256 + threadIdx.x;
  if (n >= NN) return;
  float mean = logsum[0] / (float)NN;
  float sc = logf(wdeg[n] + 1.0f) / mean;
  scales[n * 2 + 0] = sc;
  scales[n * 2 + 1] = 1.0f / fmaxf(sc, 0.01f);
}

// pack each edge as {node_in, relation, w_bits, 0}
__global__ __launch_bounds__(256) void scatter_kernel(const int* __restrict__ node_in,
                                                      const int* __restrict__ node_out,
                                                      const int* __restrict__ relation,
                                                      const float* __restrict__ ew,
                                                      const int* __restrict__ base,
                                                      int* __restrict__ fill,
                                                      int4* __restrict__ ep) {
  int e = blockIdx.x * 256 + threadIdx.x;
  if (e >= EE) return;
  int dn = node_out[e];
  int pos = base[dn] + atomicAdd(&fill[dn], 1);
  ep[pos] = make_int4(node_in[e], relation[e], __float_as_int(ew[e]), 0);
}

// query gather + boundary placement (h0 pre-zeroed; fp16 zero == 0x0000)
__global__ __launch_bounds__(128) void init_kernel(const int* __restrict__ h_index,
                                                   const int* __restrict__ r_index,
                                                   const float* __restrict__ qemb,
                                                   float* __restrict__ query,
                                                   __half* __restrict__ h0) {
  int t = threadIdx.x; int b = t >> 5, d = t & 31;
  float qv = qemb[r_index[b] * DD + d];
  query[t] = qv;
  h0[h_index[b] * BD + t] = __float2half(qv);
}

// rel_in for ALL layers upfront (depends only on query, not hidden):
// relIn[l][r][b][d] = query[b] . rel_W[l][:, r*D+d] + rel_b[l][r*D+d]  (fp16)
__global__ __launch_bounds__(256) void relin_all_kernel(const float* __restrict__ query,
                                                        const float* __restrict__ relW,
                                                        const float* __restrict__ relB,
                                                        __half* __restrict__ relIn) {
  int o = blockIdx.x * 256 + threadIdx.x;
  if (o >= LL * R2C * BD) return;
  int l = o / (R2C * BD);
  int rest = o % (R2C * BD);
  int r = rest >> 7, b = (rest >> 5) & 3, d = rest & 31;
  int col = r * DD + d;
  const float* W = relW + (size_t)l * DD * R2C * DD;
  float acc = relB[(size_t)l * R2C * DD + col];
  #pragma unroll
  for (int k = 0; k < DD; ++k)
    acc = fmaf(query[b * DD + k], W[(size_t)k * (R2C * DD) + col], acc);
  relIn[o] = __float2half(acc);
}

// Pack lin_W into MFMA B-fragment order, fp16:
// Wm[l][t][nt][lane][j]; k = t*32 + (lane>>4)*8 + j; n = nt*16 + (lane&15).
// Feature k-order: k<32 hidden (wrow=k); else kk=k-32: slab=kk>>7, s=(kk>>5)&3,
// dd=kk&31, wrow = 32 + (dd*4+s)*3 + slab.
__global__ __launch_bounds__(256) void wmbuild_kernel(const float* __restrict__ linW,
                                                      _Float16* __restrict__ Wm) {
  int idx = blockIdx.x * 256 + threadIdx.x;
  if (idx >= LL * WMH) return;
  int l = idx / WMH, rest = idx % WMH;
  int t = rest >> 10;
  int nt = (rest >> 9) & 1;
  int L = (rest >> 3) & 63;
  int j = rest & 7;
  int k = t * 32 + (L >> 4) * 8 + j;
  int n = nt * 16 + (L & 15);
  int wrow;
  if (k < 32) wrow = k;
  else {
    int kk = k - 32;
    int slab = kk >> 7, s = (kk >> 5) & 3, dd = kk & 31;
    wrow = DD + (dd * 4 + s) * 3 + slab;
  }
  Wm[idx] = (_Float16)linW[(size_t)l * THD * DD + (size_t)wrow * DD + n];
}

// ---------------- phase 1: gather-reduce PNA stats ----------------
// One 64-lane wave per node; lane owns a half2 (2 of 128 (b,d) slots).
// beg/cnt forced wave-uniform via readfirstlane -> ep[] fetches become
// scalar s_load (frees vmcnt slots for the hin/rel row gathers).
// statsH[n][s][128slots] fp16, s = {mean, max, min, std}.
__global__ __launch_bounds__(256) void gather_kernel(const __half2* __restrict__ hin2,
                                                     const __half2* __restrict__ rel2,
                                                     const int4* __restrict__ ep,
                                                     const int* __restrict__ base,
                                                     const int* __restrict__ cnt,
                                                     const float* __restrict__ cntf,
                                                     const int* __restrict__ h_index,
                                                     const float* __restrict__ query,
                                                     __half2* __restrict__ statsH) {
  const int lane = threadIdx.x & 63;
  const int n = blockIdx.x * 4 + (threadIdx.x >> 6);   // NN % 4 == 0
  const int b = lane >> 4;
  const int d0 = (lane & 15) * 2;
  const float q0 = query[b * 32 + d0], q1 = query[b * 32 + d0 + 1];
  const int hb = h_index[b];
  const int beg  = __builtin_amdgcn_readfirstlane(base[n]);
  const int cnn  = __builtin_amdgcn_readfirstlane(cnt[n]);
  const int end  = beg + cnn;
  const float mb0 = (n == hb) ? q0 : 0.f;
  const float mb1 = (n == hb) ? q1 : 0.f;
  float sa0 = mb0, qa0 = mb0 * mb0, mx0 = mb0, mn0 = mb0;
  float sa1 = mb1, qa1 = mb1 * mb1, mx1 = mb1, mn1 = mb1;
  int p = beg;
  const int pend = beg + (cnn & ~3);
  if (p < pend) {
    int4 e0 = ep[p], e1 = ep[p + 1], e2 = ep[p + 2], e3 = ep[p + 3];
    for (;;) {
      __half2 h0v = hin2[(unsigned)e0.x * 64 + lane];
      __half2 r0v = rel2[(unsigned)e0.y * 64 + lane];
      __half2 h1v = hin2[(unsigned)e1.x * 64 + lane];
      __half2 r1v = rel2[(unsigned)e1.y * 64 + lane];
      __half2 h2v = hin2[(unsigned)e2.x * 64 + lane];
      __half2 r2v = rel2[(unsigned)e2.y * 64 + lane];
      __half2 h3v = hin2[(unsigned)e3.x * 64 + lane];
      __half2 r3v = rel2[(unsigned)e3.y * 64 + lane];
      const int pn = p + 4;
      int4 f0, f1, f2, f3;
      if (pn < pend) { f0 = ep[pn]; f1 = ep[pn + 1]; f2 = ep[pn + 2]; f3 = ep[pn + 3]; }
      float2 hf, rf; float m0, m1, mw0, mw1, w;
      w = __int_as_float(e0.z);
      hf = __half22float2(h0v); rf = __half22float2(r0v);
      m0 = rf.x * hf.x; mw0 = m0 * w; m1 = rf.y * hf.y; mw1 = m1 * w;
      sa0 += mw0; qa0 = fmaf(m0, mw0, qa0); mx0 = fmaxf(mx0, mw0); mn0 = fminf(mn0, mw0);
      sa1 += mw1; qa1 = fmaf(m1, mw1, qa1); mx1 = fmaxf(mx1, mw1); mn1 = fminf(mn1, mw1);
      w = __int_as_float(e1.z);
      hf = __half22float2(h1v); rf = __half22float2(r1v);
      m0 = rf.x * hf.x; mw0 = m0 * w; m1 = rf.y * hf.y; mw1 = m1 * w;
      sa0 += mw0; qa0 = fmaf(m0, mw0, qa0); mx0 = fmaxf(mx0, mw0); mn0 = fminf(mn0, mw0);
      sa1 += mw1; qa1 = fmaf(m1, mw1, qa1); mx1 = fmaxf(mx1, mw1); mn1 = fminf(mn1, mw1);
      w = __int_as_float(e2.z);
      hf = __half22float2(h2v); rf = __half22float2(r2v);
      m0 = rf.x * hf.x; mw0 = m0 * w; m1 = rf.y * hf.y; mw1 = m1 * w;
      sa0 += mw0; qa0 = fmaf(m0, mw0, qa0); mx0 = fmaxf(mx0, mw0); mn0 = fminf(mn0, mw0);
      sa1 += mw1; qa1 = fmaf(m1, mw1, qa1); mx1 = fmaxf(mx1, mw1); mn1 = fminf(mn1, mw1);
      w = __int_as_float(e3.z);
      hf = __half22float2(h3v); rf = __half22float2(r3v);
      m0 = rf.x * hf.x; mw0 = m0 * w; m1 = rf.y * hf.y; mw1 = m1 * w;
      sa0 += mw0; qa0 = fmaf(m0, mw0, qa0); mx0 = fmaxf(mx0, mw0); mn0 = fminf(mn0, mw0);
      sa1 += mw1; qa1 = fmaf(m1, mw1, qa1); mx1 = fmaxf(mx1, mw1); mn1 = fminf(mn1, mw1);
      p = pn;
      if (p >= pend) break;
      e0 = f0; e1 = f1; e2 = f2; e3 = f3;
    }
  }
  for (; p < end; ++p) {
    int4 e = ep[p];
    __half2 hv = hin2[(unsigned)e.x * 64 + lane];
    __half2 rv = rel2[(unsigned)e.y * 64 + lane];
    float w = __int_as_float(e.z);
    float2 hf = __half22float2(hv), rf = __half22float2(rv);
    float m0 = rf.x * hf.x, mw0 = m0 * w;
    float m1 = rf.y * hf.y, mw1 = m1 * w;
    sa0 += mw0; qa0 = fmaf(m0, mw0, qa0); mx0 = fmaxf(mx0, mw0); mn0 = fminf(mn0, mw0);
    sa1 += mw1; qa1 = fmaf(m1, mw1, qa1); mx1 = fmaxf(mx1, mw1); mn1 = fminf(mn1, mw1);
  }
  const float invc = 1.0f / cntf[n];
  const float mean0 = sa0 * invc, mean1 = sa1 * invc;
  const float sd0 = sqrtf(fmaxf(qa0 * invc - mean0 * mean0, EPSF));
  const float sd1 = sqrtf(fmaxf(qa1 * invc - mean1 * mean1, EPSF));
  __half2* sp = statsH + (unsigned)n * 256 + lane;
  sp[0]   = __floats2half2_rn(mean0, mean1);
  sp[64]  = __floats2half2_rn(mx0, mx1);
  sp[128] = __floats2half2_rn(mn0, mn1);
  sp[192] = __floats2half2_rn(sd0, sd1);
}

// ---------------- phase 2: 416->32 linear via MFMA ----------------
// One wave = 16-row tile (4 nodes x 4 queries). 13 K-steps of 32 features.
// A: lane L -> row m=L&15 -> (n, b); 8 halfs from hinh/statsH (dwordx4),
// degree-scale folded in fp16. B: pre-packed Wm (L1-resident).
// D: col=lane&15, row=(lane>>4)*4+reg -> bias+relu -> fp16 store.
__global__ __launch_bounds__(128) void mfma_linear_kernel(const _Float16* __restrict__ hinh,
                                                          __half* __restrict__ houth,
                                                          const _Float16* __restrict__ statsH,
                                                          const float* __restrict__ scales,
                                                          const _Float16* __restrict__ Wm,
                                                          const float* __restrict__ bias) {
  const int lane = threadIdx.x & 63;
  const int wid  = threadIdx.x >> 6;
  const int nbase = blockIdx.x * 8 + wid * 4;    // NN % 8 == 0
  const int m = lane & 15;
  const int q = lane >> 4;
  const int n = nbase + (m >> 2);
  const int b = m & 3;
  const _Float16 one = (_Float16)1.f;
  const _Float16 s1h = (_Float16)scales[n * 2 + 0];
  const _Float16 s2h = (_Float16)scales[n * 2 + 1];
  const _Float16* hsrc = hinh   + (unsigned)n * BD  + b * 32 + q * 8;
  const _Float16* ssrc = statsH + (unsigned)n * 512 + b * 32 + q * 8;

  f32x4 c0 = {0.f, 0.f, 0.f, 0.f};
  f32x4 c1 = {0.f, 0.f, 0.f, 0.f};
  #pragma unroll
  for (int t = 0; t < 13; ++t) {
    half8 a;
    if (t == 0) {
      a = *(const half8*)hsrc;
    } else {
      const int slab = (t - 1) >> 2, s = (t - 1) & 3;
      a = *(const half8*)(ssrc + s * 128);
      const _Float16 sc = (slab == 0) ? one : ((slab == 1) ? s1h : s2h);
      half8 sv = {sc, sc, sc, sc, sc, sc, sc, sc};
      a = a * sv;
    }
    half8 b0 = *(const half8*)(Wm + (unsigned)(t * 2 + 0) * 512 + lane * 8);
    half8 b1 = *(const half8*)(Wm + (unsigned)(t * 2 + 1) * 512 + lane * 8);
    c0 = __builtin_amdgcn_mfma_f32_16x16x32_f16(a, b0, c0, 0, 0, 0);
    c1 = __builtin_amdgcn_mfma_f32_16x16x32_f16(a, b1, c1, 0, 0, 0);
  }
  const int col = lane & 15;
  const float bj0 = bias[col], bj1 = bias[col + 16];
  #pragma unroll
  for (int i = 0; i < 4; ++i) {
    const int mr = q * 4 + i;
    const int nl = mr >> 2, bq = mr & 3;
    __half* dst = houth + (unsigned)(nbase + nl) * BD + bq * 32 + col;
    dst[0]  = __float2half(fmaxf(c0[i] + bj0, 0.f));
    dst[16] = __float2half(fmaxf(c1[i] + bj1, 0.f));
  }
}

// final MLP: [hidden(fp16), query] (64) -> relu(64) -> 1, out[b*N + n]
__global__ __launch_bounds__(128) void mlp_kernel(const __half* __restrict__ hinh,
                                                  const float* __restrict__ query,
                                                  const float* __restrict__ W1,
                                                  const float* __restrict__ b1,
                                                  const float* __restrict__ W2,
                                                  const float* __restrict__ b2,
                                                  float* __restrict__ out) {
  __shared__ float f2[BB][2 * DD];
  const int t = threadIdx.x;
  const int b = t >> 5, d = t & 31;
  const float qv = query[t];
  const float w2a = W2[d], w2b = W2[DD + d];
  const float b1a = b1[d], b1b = b1[DD + d];
  const float b2v = b2[0];
  const int NPBM = 8;
  int n0 = blockIdx.x * NPBM, n1 = min(n0 + NPBM, NN);
  for (int n = n0; n < n1; ++n) {
    f2[b][d]      = __half2float(hinh[(unsigned)n * BD + t]);
    f2[b][DD + d] = qv;
    float a0 = b1a, a1 = b1b;
    #pragma unroll
    for (int i = 0; i < 2 * DD; ++i) {
      float v = f2[b][i];
      a0 = fmaf(v, W1[i * 2 * DD + d], a0);
      a1 = fmaf(v, W1[i * 2 * DD + DD + d], a1);
    }
    a0 = fmaxf(a0, 0.f); a1 = fmaxf(a1, 0.f);
    float part = a0 * w2a + a1 * w2b;
    #pragma unroll
    for (int off = 16; off > 0; off >>= 1) part += __shfl_down(part, off, 32);
    if (d == 0) out[b * NN + n] = part + b2v;
  }
}

extern "C" void kernel_launch(void* const* d_in, const int* in_sizes, int n_in,
                              void* d_out, int out_size, void* d_ws, size_t ws_size,
                              hipStream_t stream) {
  const int*   node_in  = (const int*)d_in[0];
  const int*   node_out = (const int*)d_in[1];
  const int*   relation = (const int*)d_in[2];
  const float* ew       = (const float*)d_in[3];
  const int*   h_index  = (const int*)d_in[4];
  const int*   r_index  = (const int*)d_in[5];
  const float* qemb     = (const float*)d_in[6];
  const float* relW     = (const float*)d_in[7];
  const float* relB     = (const float*)d_in[8];
  const float* linW     = (const float*)d_in[9];
  const float* linB     = (const float*)d_in[10];
  const float* W1       = (const float*)d_in[11];
  const float* b1       = (const float*)d_in[12];
  const float* W2       = (const float*)d_in[13];
  const float* b2       = (const float*)d_in[14];
  float* out = (float*)d_out;

  char* ws = (char*)d_ws;
  size_t off = 0;
  auto alloc = [&](size_t bytes) -> char* {
    char* p = ws + off;
    off += (bytes + 255) & ~(size_t)255;
    return p;
  };
  __half*   h0     = (__half*)  alloc((size_t)NN * BD * 2);
  __half*   h1     = (__half*)  alloc((size_t)NN * BD * 2);
  __half*   relIn  = (__half*)  alloc((size_t)LL * R2C * BD * 2);
  __half*   statsH = (__half*)  alloc((size_t)NN * 512 * 2);
  _Float16* Wm     = (_Float16*)alloc((size_t)LL * WMH * 2);
  int4*     ep     = (int4*)    alloc((size_t)EE * 16);
  int*      base   = (int*)     alloc((size_t)NN * 4);
  int*      cnti   = (int*)     alloc((size_t)NN * 4);
  int*      fill   = (int*)     alloc((size_t)NN * 4);
  float*    wdeg   = (float*)   alloc((size_t)NN * 4);
  float*    cntf   = (float*)   alloc((size_t)NN * 4);
  float*    scales = (float*)   alloc((size_t)NN * 2 * 4);
  float*    query  = (float*)   alloc((size_t)BD * 4);
  float*    stats  = (float*)   alloc(256);   // [0]=logsum (f32), [1]=gcnt (int)

  hipMemsetAsync(cnti, 0, (size_t)NN * 4, stream);
  hipMemsetAsync(fill, 0, (size_t)NN * 4, stream);
  hipMemsetAsync(wdeg, 0, (size_t)NN * 4, stream);
  hipMemsetAsync(stats, 0, 256, stream);
  hipMemsetAsync(h0,   0, (size_t)NN * BD * 2, stream);

  float* logsum = stats;
  int*   gcnt   = (int*)stats + 1;

  hist_kernel   <<<(EE + 255) / 256, 256, 0, stream>>>(node_out, ew, cnti, wdeg);
  prep_kernel   <<<(NN + 255) / 256, 256, 0, stream>>>(cnti, wdeg, base, cntf, gcnt, logsum);
  scales_kernel <<<(NN + 255) / 256, 256, 0, stream>>>(wdeg, logsum, scales);
  scatter_kernel<<<(EE + 255) / 256, 256, 0, stream>>>(node_in, node_out, relation, ew,
                                                       base, fill, ep);
  init_kernel   <<<1, 128, 0, stream>>>(h_index, r_index, qemb, query, h0);
  wmbuild_kernel<<<(LL * WMH + 255) / 256, 256, 0, stream>>>(linW, Wm);
  relin_all_kernel<<<(LL * R2C * BD + 255) / 256, 256, 0, stream>>>(query, relW, relB, relIn);

  __half* hin = h0; __half* hout = h1;
  for (int l = 0; l < LL; ++l) {
    gather_kernel<<<NN / 4, 256, 0, stream>>>(
        (const __half2*)hin, (const __half2*)relIn + (size_t)l * R2C * 64,
        ep, base, cnti, cntf, h_index, query, (__half2*)statsH);
    mfma_linear_kernel<<<NN / 8, 128, 0, stream>>>(
        (const _Float16*)hin, hout, (const _Float16*)statsH, scales,
        Wm + (size_t)l * WMH, linB + (size_t)l * DD);
    __half* tmp = hin; hin = hout; hout = tmp;
  }
  mlp_kernel<<<(NN + 7) / 8, 128, 0, stream>>>(hin, query, W1, b1, W2, b2, out);
}

// Round 9
// 329.034 us; speedup vs baseline: 3.8655x; 1.1145x over previous
//
#include <hip/hip_runtime.h>
#include <hip/hip_fp16.h>

#define NN  25000
#define EE  500000
#define BB  4
#define DD  32
#define LL  4
#define R2C 474
#define BD  128      // B*D
#define THD 416      // 13*D
#define EPSF 1e-6f
#define WMH 13312    // halfs per layer of MFMA-packed W: 13 t * 2 nt * 64 * 8

typedef _Float16 half8 __attribute__((ext_vector_type(8)));
typedef float    f32x4 __attribute__((ext_vector_type(4)));

// ---------------- graph build ----------------
// Fused count + slot assignment: atomicAdd's RETURN VALUE is the edge's
// within-segment position. Halves build atomics vs hist+scatter-fill.
__global__ __launch_bounds__(256) void pidx_kernel(const int* __restrict__ node_out,
                                                   int* __restrict__ cnt,
                                                   int* __restrict__ pidx) {
  int e = blockIdx.x * 256 + threadIdx.x;
  if (e < EE) pidx[e] = atomicAdd(&cnt[node_out[e]], 1);
}

// Order-free CSR: segments need not be in node order -> atomic bump alloc.
__global__ __launch_bounds__(256) void prep_kernel(const int* __restrict__ cnt,
                                                   int* __restrict__ base,
                                                   float* __restrict__ cntf,
                                                   int* __restrict__ gcnt) {
  int n = blockIdx.x * 256 + threadIdx.x;
  if (n >= NN) return;
  int c = cnt[n];
  base[n] = atomicAdd(gcnt, c);
  cntf[n] = (float)(c + 1);             // indeg + self entry
}

// atomic-free scatter: pos = base[dn] + pidx[e]
__global__ __launch_bounds__(256) void scatter_kernel(const int* __restrict__ node_in,
                                                      const int* __restrict__ node_out,
                                                      const int* __restrict__ relation,
                                                      const float* __restrict__ ew,
                                                      const int* __restrict__ base,
                                                      const int* __restrict__ pidx,
                                                      int4* __restrict__ ep) {
  int e = blockIdx.x * 256 + threadIdx.x;
  if (e >= EE) return;
  int pos = base[node_out[e]] + pidx[e];
  ep[pos] = make_int4(node_in[e], relation[e], __float_as_int(ew[e]), 0);
}

// per-node weighted degree from the packed segments (no float atomics);
// block-reduced logsum (98 atomics total).
__global__ __launch_bounds__(256) void wdeg_kernel(const int* __restrict__ base,
                                                   const int* __restrict__ cnt,
                                                   const int4* __restrict__ ep,
                                                   float* __restrict__ lg,
                                                   float* __restrict__ logsum) {
  int n = blockIdx.x * 256 + threadIdx.x;
  float v = 0.f;
  if (n < NN) {
    int b = base[n], c = cnt[n];
    float s = 0.f;
    for (int p = b; p < b + c; ++p) s += __int_as_float(ep[p].z);
    v = logf(s + 1.0f);
    lg[n] = v;
  }
  __shared__ float red[256];
  red[threadIdx.x] = v; __syncthreads();
  for (int o = 128; o > 0; o >>= 1) {
    if (threadIdx.x < o) red[threadIdx.x] += red[threadIdx.x + o];
    __syncthreads();
  }
  if (threadIdx.x == 0) atomicAdd(logsum, red[0]);
}

__global__ __launch_bounds__(256) void scales_kernel(const float* __restrict__ lg,
                                                     const float* __restrict__ logsum,
                                                     float* __restrict__ scales) {
  int n = blockIdx.x * 256 + threadIdx.x;
  if (n >= NN) return;
  float mean = logsum[0] / (float)NN;
  float sc = lg[n] / mean;
  scales[n * 2 + 0] = sc;
  scales[n * 2 + 1] = 1.0f / fmaxf(sc, 0.01f);
}

// query gather + boundary placement (h0 pre-zeroed; fp16 zero == 0x0000)
__global__ __launch_bounds__(128) void init_kernel(const int* __restrict__ h_index,
                                                   const int* __restrict__ r_index,
                                                   const float* __restrict__ qemb,
                                                   float* __restrict__ query,
                                                   __half* __restrict__ h0) {
  int t = threadIdx.x; int b = t >> 5, d = t & 31;
  float qv = qemb[r_index[b] * DD + d];
  query[t] = qv;
  h0[h_index[b] * BD + t] = __float2half(qv);
}

// rel_in for ALL layers upfront (depends only on query, not hidden)
__global__ __launch_bounds__(256) void relin_all_kernel(const float* __restrict__ query,
                                                        const float* __restrict__ relW,
                                                        const float* __restrict__ relB,
                                                        __half* __restrict__ relIn) {
  int o = blockIdx.x * 256 + threadIdx.x;
  if (o >= LL * R2C * BD) return;
  int l = o / (R2C * BD);
  int rest = o % (R2C * BD);
  int r = rest >> 7, b = (rest >> 5) & 3, d = rest & 31;
  int col = r * DD + d;
  const float* W = relW + (size_t)l * DD * R2C * DD;
  float acc = relB[(size_t)l * R2C * DD + col];
  #pragma unroll
  for (int k = 0; k < DD; ++k)
    acc = fmaf(query[b * DD + k], W[(size_t)k * (R2C * DD) + col], acc);
  relIn[o] = __float2half(acc);
}

// Pack lin_W into MFMA B-fragment order, fp16.
__global__ __launch_bounds__(256) void wmbuild_kernel(const float* __restrict__ linW,
                                                      _Float16* __restrict__ Wm) {
  int idx = blockIdx.x * 256 + threadIdx.x;
  if (idx >= LL * WMH) return;
  int l = idx / WMH, rest = idx % WMH;
  int t = rest >> 10;
  int nt = (rest >> 9) & 1;
  int L = (rest >> 3) & 63;
  int j = rest & 7;
  int k = t * 32 + (L >> 4) * 8 + j;
  int n = nt * 16 + (L & 15);
  int wrow;
  if (k < 32) wrow = k;
  else {
    int kk = k - 32;
    int slab = kk >> 7, s = (kk >> 5) & 3, dd = kk & 31;
    wrow = DD + (dd * 4 + s) * 3 + slab;
  }
  Wm[idx] = (_Float16)linW[(size_t)l * THD * DD + (size_t)wrow * DD + n];
}

// ---------------- phase 1: gather-reduce PNA stats ----------------
// One 64-lane wave per node; lane owns a half2. Wave-uniform ep stream via
// readfirstlane (scalar loads). Two-stage software pipeline: issue batch
// i+1's 8 row-loads before processing batch i -> ~16 loads in flight.
__global__ __launch_bounds__(256) void gather_kernel(const __half2* __restrict__ hin2,
                                                     const __half2* __restrict__ rel2,
                                                     const int4* __restrict__ ep,
                                                     const int* __restrict__ base,
                                                     const int* __restrict__ cnt,
                                                     const float* __restrict__ cntf,
                                                     const int* __restrict__ h_index,
                                                     const float* __restrict__ query,
                                                     __half2* __restrict__ statsH) {
  const int lane = threadIdx.x & 63;
  const int n = blockIdx.x * 4 + (threadIdx.x >> 6);   // NN % 4 == 0
  const int b = lane >> 4;
  const int d0 = (lane & 15) * 2;
  const float q0 = query[b * 32 + d0], q1 = query[b * 32 + d0 + 1];
  const int hb = h_index[b];
  const int beg = __builtin_amdgcn_readfirstlane(base[n]);
  const int cnn = __builtin_amdgcn_readfirstlane(cnt[n]);
  const float mb0 = (n == hb) ? q0 : 0.f;
  const float mb1 = (n == hb) ? q1 : 0.f;
  float sa0 = mb0, qa0 = mb0 * mb0, mx0 = mb0, mn0 = mb0;
  float sa1 = mb1, qa1 = mb1 * mb1, mx1 = mb1, mn1 = mb1;

#define PROC(Ez, Hv, Rv) {                                                   \
    float w = __int_as_float(Ez);                                            \
    float2 hf = __half22float2(Hv), rf = __half22float2(Rv);                 \
    float m0 = rf.x * hf.x, mw0 = m0 * w;                                    \
    float m1 = rf.y * hf.y, mw1 = m1 * w;                                    \
    sa0 += mw0; qa0 = fmaf(m0, mw0, qa0);                                    \
    mx0 = fmaxf(mx0, mw0); mn0 = fminf(mn0, mw0);                            \
    sa1 += mw1; qa1 = fmaf(m1, mw1, qa1);                                    \
    mx1 = fmaxf(mx1, mw1); mn1 = fminf(mn1, mw1); }

  const int nb = cnn >> 2;
  if (nb > 0) {
    int4 e0 = ep[beg], e1 = ep[beg + 1], e2 = ep[beg + 2], e3 = ep[beg + 3];
    __half2 h0v = hin2[(unsigned)e0.x * 64 + lane];
    __half2 r0v = rel2[(unsigned)e0.y * 64 + lane];
    __half2 h1v = hin2[(unsigned)e1.x * 64 + lane];
    __half2 r1v = rel2[(unsigned)e1.y * 64 + lane];
    __half2 h2v = hin2[(unsigned)e2.x * 64 + lane];
    __half2 r2v = rel2[(unsigned)e2.y * 64 + lane];
    __half2 h3v = hin2[(unsigned)e3.x * 64 + lane];
    __half2 r3v = rel2[(unsigned)e3.y * 64 + lane];
    for (int it = 1; it < nb; ++it) {
      const int q = beg + it * 4;
      int4 f0 = ep[q], f1 = ep[q + 1], f2 = ep[q + 2], f3 = ep[q + 3];
      __half2 g0 = hin2[(unsigned)f0.x * 64 + lane];
      __half2 s0 = rel2[(unsigned)f0.y * 64 + lane];
      __half2 g1 = hin2[(unsigned)f1.x * 64 + lane];
      __half2 s1 = rel2[(unsigned)f1.y * 64 + lane];
      __half2 g2 = hin2[(unsigned)f2.x * 64 + lane];
      __half2 s2 = rel2[(unsigned)f2.y * 64 + lane];
      __half2 g3 = hin2[(unsigned)f3.x * 64 + lane];
      __half2 s3 = rel2[(unsigned)f3.y * 64 + lane];
      PROC(e0.z, h0v, r0v); PROC(e1.z, h1v, r1v);
      PROC(e2.z, h2v, r2v); PROC(e3.z, h3v, r3v);
      e0 = f0; e1 = f1; e2 = f2; e3 = f3;
      h0v = g0; h1v = g1; h2v = g2; h3v = g3;
      r0v = s0; r1v = s1; r2v = s2; r3v = s3;
    }
    PROC(e0.z, h0v, r0v); PROC(e1.z, h1v, r1v);
    PROC(e2.z, h2v, r2v); PROC(e3.z, h3v, r3v);
  }
  for (int p = beg + (nb << 2); p < beg + cnn; ++p) {
    int4 e = ep[p];
    __half2 hv = hin2[(unsigned)e.x * 64 + lane];
    __half2 rv = rel2[(unsigned)e.y * 64 + lane];
    PROC(e.z, hv, rv);
  }
#undef PROC
  const float invc = 1.0f / cntf[n];
  const float mean0 = sa0 * invc, mean1 = sa1 * invc;
  const float sd0 = sqrtf(fmaxf(qa0 * invc - mean0 * mean0, EPSF));
  const float sd1 = sqrtf(fmaxf(qa1 * invc - mean1 * mean1, EPSF));
  __half2* sp = statsH + (unsigned)n * 256 + lane;
  sp[0]   = __floats2half2_rn(mean0, mean1);
  sp[64]  = __floats2half2_rn(mx0, mx1);
  sp[128] = __floats2half2_rn(mn0, mn1);
  sp[192] = __floats2half2_rn(sd0, sd1);
}

// ---------------- phase 2: 416->32 linear via MFMA ----------------
__global__ __launch_bounds__(128) void mfma_linear_kernel(const _Float16* __restrict__ hinh,
                                                          __half* __restrict__ houth,
                                                          const _Float16* __restrict__ statsH,
                                                          const float* __restrict__ scales,
                                                          const _Float16* __restrict__ Wm,
                                                          const float* __restrict__ bias) {
  const int lane = threadIdx.x & 63;
  const int wid  = threadIdx.x >> 6;
  const int nbase = blockIdx.x * 8 + wid * 4;    // NN % 8 == 0
  const int m = lane & 15;
  const int q = lane >> 4;
  const int n = nbase + (m >> 2);
  const int b = m & 3;
  const _Float16 one = (_Float16)1.f;
  const _Float16 s1h = (_Float16)scales[n * 2 + 0];
  const _Float16 s2h = (_Float16)scales[n * 2 + 1];
  const _Float16* hsrc = hinh   + (unsigned)n * BD  + b * 32 + q * 8;
  const _Float16* ssrc = statsH + (unsigned)n * 512 + b * 32 + q * 8;

  f32x4 c0 = {0.f, 0.f, 0.f, 0.f};
  f32x4 c1 = {0.f, 0.f, 0.f, 0.f};
  #pragma unroll
  for (int t = 0; t < 13; ++t) {
    half8 a;
    if (t == 0) {
      a = *(const half8*)hsrc;
    } else {
      const int slab = (t - 1) >> 2, s = (t - 1) & 3;
      a = *(const half8*)(ssrc + s * 128);
      const _Float16 sc = (slab == 0) ? one : ((slab == 1) ? s1h : s2h);
      half8 sv = {sc, sc, sc, sc, sc, sc, sc, sc};
      a = a * sv;
    }
    half8 b0 = *(const half8*)(Wm + (unsigned)(t * 2 + 0) * 512 + lane * 8);
    half8 b1 = *(const half8*)(Wm + (unsigned)(t * 2 + 1) * 512 + lane * 8);
    c0 = __builtin_amdgcn_mfma_f32_16x16x32_f16(a, b0, c0, 0, 0, 0);
    c1 = __builtin_amdgcn_mfma_f32_16x16x32_f16(a, b1, c1, 0, 0, 0);
  }
  const int col = lane & 15;
  const float bj0 = bias[col], bj1 = bias[col + 16];
  #pragma unroll
  for (int i = 0; i < 4; ++i) {
    const int mr = q * 4 + i;
    const int nl = mr >> 2, bq = mr & 3;
    __half* dst = houth + (unsigned)(nbase + nl) * BD + bq * 32 + col;
    dst[0]  = __float2half(fmaxf(c0[i] + bj0, 0.f));
    dst[16] = __float2half(fmaxf(c1[i] + bj1, 0.f));
  }
}

// final MLP: [hidden(fp16), query] (64) -> relu(64) -> 1, out[b*N + n]
__global__ __launch_bounds__(128) void mlp_kernel(const __half* __restrict__ hinh,
                                                  const float* __restrict__ query,
                                                  const float* __restrict__ W1,
                                                  const float* __restrict__ b1,
                                                  const float* __restrict__ W2,
                                                  const float* __restrict__ b2,
                                                  float* __restrict__ out) {
  __shared__ float f2[BB][2 * DD];
  const int t = threadIdx.x;
  const int b = t >> 5, d = t & 31;
  const float qv = query[t];
  const float w2a = W2[d], w2b = W2[DD + d];
  const float b1a = b1[d], b1b = b1[DD + d];
  const float b2v = b2[0];
  const int NPBM = 8;
  int n0 = blockIdx.x * NPBM, n1 = min(n0 + NPBM, NN);
  for (int n = n0; n < n1; ++n) {
    f2[b][d]      = __half2float(hinh[(unsigned)n * BD + t]);
    f2[b][DD + d] = qv;
    float a0 = b1a, a1 = b1b;
    #pragma unroll
    for (int i = 0; i < 2 * DD; ++i) {
      float v = f2[b][i];
      a0 = fmaf(v, W1[i * 2 * DD + d], a0);
      a1 = fmaf(v, W1[i * 2 * DD + DD + d], a1);
    }
    a0 = fmaxf(a0, 0.f); a1 = fmaxf(a1, 0.f);
    float part = a0 * w2a + a1 * w2b;
    #pragma unroll
    for (int off = 16; off > 0; off >>= 1) part += __shfl_down(part, off, 32);
    if (d == 0) out[b * NN + n] = part + b2v;
  }
}

extern "C" void kernel_launch(void* const* d_in, const int* in_sizes, int n_in,
                              void* d_out, int out_size, void* d_ws, size_t ws_size,
                              hipStream_t stream) {
  const int*   node_in  = (const int*)d_in[0];
  const int*   node_out = (const int*)d_in[1];
  const int*   relation = (const int*)d_in[2];
  const float* ew       = (const float*)d_in[3];
  const int*   h_index  = (const int*)d_in[4];
  const int*   r_index  = (const int*)d_in[5];
  const float* qemb     = (const float*)d_in[6];
  const float* relW     = (const float*)d_in[7];
  const float* relB     = (const float*)d_in[8];
  const float* linW     = (const float*)d_in[9];
  const float* linB     = (const float*)d_in[10];
  const float* W1       = (const float*)d_in[11];
  const float* b1       = (const float*)d_in[12];
  const float* W2       = (const float*)d_in[13];
  const float* b2       = (const float*)d_in[14];
  float* out = (float*)d_out;

  char* ws = (char*)d_ws;
  size_t off = 0;
  auto alloc = [&](size_t bytes) -> char* {
    char* p = ws + off;
    off += (bytes + 255) & ~(size_t)255;
    return p;
  };
  __half*   h0     = (__half*)  alloc((size_t)NN * BD * 2);
  __half*   h1     = (__half*)  alloc((size_t)NN * BD * 2);
  __half*   relIn  = (__half*)  alloc((size_t)LL * R2C * BD * 2);
  __half*   statsH = (__half*)  alloc((size_t)NN * 512 * 2);
  _Float16* Wm     = (_Float16*)alloc((size_t)LL * WMH * 2);
  int4*     ep     = (int4*)    alloc((size_t)EE * 16);
  int*      pidx   = (int*)     alloc((size_t)EE * 4);
  int*      base   = (int*)     alloc((size_t)NN * 4);
  int*      cnti   = (int*)     alloc((size_t)NN * 4);
  float*    lg     = (float*)   alloc((size_t)NN * 4);
  float*    cntf   = (float*)   alloc((size_t)NN * 4);
  float*    scales = (float*)   alloc((size_t)NN * 2 * 4);
  float*    query  = (float*)   alloc((size_t)BD * 4);
  float*    stats  = (float*)   alloc(256);   // [0]=logsum (f32), [1]=gcnt (int)

  hipMemsetAsync(cnti, 0, (size_t)NN * 4, stream);
  hipMemsetAsync(stats, 0, 256, stream);
  hipMemsetAsync(h0,   0, (size_t)NN * BD * 2, stream);

  float* logsum = stats;
  int*   gcnt   = (int*)stats + 1;

  pidx_kernel   <<<(EE + 255) / 256, 256, 0, stream>>>(node_out, cnti, pidx);
  prep_kernel   <<<(NN + 255) / 256, 256, 0, stream>>>(cnti, base, cntf, gcnt);
  scatter_kernel<<<(EE + 255) / 256, 256, 0, stream>>>(node_in, node_out, relation, ew,
                                                       base, pidx, ep);
  wdeg_kernel   <<<(NN + 255) / 256, 256, 0, stream>>>(base, cnti, ep, lg, logsum);
  scales_kernel <<<(NN + 255) / 256, 256, 0, stream>>>(lg, logsum, scales);
  init_kernel   <<<1, 128, 0, stream>>>(h_index, r_index, qemb, query, h0);
  wmbuild_kernel<<<(LL * WMH + 255) / 256, 256, 0, stream>>>(linW, Wm);
  relin_all_kernel<<<(LL * R2C * BD + 255) / 256, 256, 0, stream>>>(query, relW, relB, relIn);

  __half* hin = h0; __half* hout = h1;
  for (int l = 0; l < LL; ++l) {
    gather_kernel<<<NN / 4, 256, 0, stream>>>(
        (const __half2*)hin, (const __half2*)relIn + (size_t)l * R2C * 64,
        ep, base, cnti, cntf, h_index, query, (__half2*)statsH);
    mfma_linear_kernel<<<NN / 8, 128, 0, stream>>>(
        (const _Float16*)hin, hout, (const _Float16*)statsH, scales,
        Wm + (size_t)l * WMH, linB + (size_t)l * DD);
    __half* tmp = hin; hin = hout; hout = tmp;
  }
  mlp_kernel<<<(NN + 7) / 8, 128, 0, stream>>>(hin, query, W1, b1, W2, b2, out);
}

// Round 10
// 313.436 us; speedup vs baseline: 4.0579x; 1.0498x over previous
//
#include <hip/hip_runtime.h>
#include <hip/hip_fp16.h>

#define NN  25000
#define EE  500000
#define BB  4
#define DD  32
#define LL  4
#define R2C 474
#define BD  128      // B*D
#define THD 416      // 13*D
#define EPSF 1e-6f
#define WMH 13312    // halfs per layer of MFMA-packed W: 13 t * 2 nt * 64 * 8

typedef _Float16 half8 __attribute__((ext_vector_type(8)));
typedef float    f32x4 __attribute__((ext_vector_type(4)));

// ---------------- graph build ----------------
// Fused count + slot assignment: atomicAdd's return value is the edge's
// within-segment position.
__global__ __launch_bounds__(256) void pidx_kernel(const int* __restrict__ node_out,
                                                   int* __restrict__ cnt,
                                                   int* __restrict__ pidx) {
  int e = blockIdx.x * 256 + threadIdx.x;
  if (e < EE) pidx[e] = atomicAdd(&cnt[node_out[e]], 1);
}

// Order-free CSR with EVEN-aligned segments (for 64B-aligned batch loads).
__global__ __launch_bounds__(256) void prep_kernel(const int* __restrict__ cnt,
                                                   int* __restrict__ base,
                                                   float* __restrict__ cntf,
                                                   int* __restrict__ gcnt) {
  int n = blockIdx.x * 256 + threadIdx.x;
  if (n >= NN) return;
  int c = cnt[n];
  base[n] = atomicAdd(gcnt, (c + 1) & ~1);   // even-size bump alloc
  cntf[n] = (float)(c + 1);                  // indeg + self entry
}

// atomic-free scatter of 8B records: {node_in | rel<<15, w_bits}
__global__ __launch_bounds__(256) void scatter_kernel(const int* __restrict__ node_in,
                                                      const int* __restrict__ node_out,
                                                      const int* __restrict__ relation,
                                                      const float* __restrict__ ew,
                                                      const int* __restrict__ base,
                                                      const int* __restrict__ pidx,
                                                      int2* __restrict__ ep) {
  int e = blockIdx.x * 256 + threadIdx.x;
  if (e >= EE) return;
  int pos = base[node_out[e]] + pidx[e];
  ep[pos] = make_int2(node_in[e] | (relation[e] << 15), __float_as_int(ew[e]));
}

// per-node weighted degree from packed segments; block-reduced logsum.
__global__ __launch_bounds__(256) void wdeg_kernel(const int* __restrict__ base,
                                                   const int* __restrict__ cnt,
                                                   const int2* __restrict__ ep,
                                                   float* __restrict__ lg,
                                                   float* __restrict__ logsum) {
  int n = blockIdx.x * 256 + threadIdx.x;
  float v = 0.f;
  if (n < NN) {
    int b = base[n], c = cnt[n];
    float s = 0.f;
    for (int p = b; p < b + c; ++p) s += __int_as_float(ep[p].y);
    v = logf(s + 1.0f);
    lg[n] = v;
  }
  __shared__ float red[256];
  red[threadIdx.x] = v; __syncthreads();
  for (int o = 128; o > 0; o >>= 1) {
    if (threadIdx.x < o) red[threadIdx.x] += red[threadIdx.x + o];
    __syncthreads();
  }
  if (threadIdx.x == 0) atomicAdd(logsum, red[0]);
}

__global__ __launch_bounds__(256) void scales_kernel(const float* __restrict__ lg,
                                                     const float* __restrict__ logsum,
                                                     float* __restrict__ scales) {
  int n = blockIdx.x * 256 + threadIdx.x;
  if (n >= NN) return;
  float mean = logsum[0] / (float)NN;
  float sc = lg[n] / mean;
  scales[n * 2 + 0] = sc;
  scales[n * 2 + 1] = 1.0f / fmaxf(sc, 0.01f);
}

// query gather + boundary placement (h0 pre-zeroed; fp16 zero == 0x0000)
__global__ __launch_bounds__(128) void init_kernel(const int* __restrict__ h_index,
                                                   const int* __restrict__ r_index,
                                                   const float* __restrict__ qemb,
                                                   float* __restrict__ query,
                                                   __half* __restrict__ h0) {
  int t = threadIdx.x; int b = t >> 5, d = t & 31;
  float qv = qemb[r_index[b] * DD + d];
  query[t] = qv;
  h0[h_index[b] * BD + t] = __float2half(qv);
}

// rel_in for ALL layers upfront (depends only on query, not hidden)
__global__ __launch_bounds__(256) void relin_all_kernel(const float* __restrict__ query,
                                                        const float* __restrict__ relW,
                                                        const float* __restrict__ relB,
                                                        __half* __restrict__ relIn) {
  int o = blockIdx.x * 256 + threadIdx.x;
  if (o >= LL * R2C * BD) return;
  int l = o / (R2C * BD);
  int rest = o % (R2C * BD);
  int r = rest >> 7, b = (rest >> 5) & 3, d = rest & 31;
  int col = r * DD + d;
  const float* W = relW + (size_t)l * DD * R2C * DD;
  float acc = relB[(size_t)l * R2C * DD + col];
  #pragma unroll
  for (int k = 0; k < DD; ++k)
    acc = fmaf(query[b * DD + k], W[(size_t)k * (R2C * DD) + col], acc);
  relIn[o] = __float2half(acc);
}

// Pack lin_W into MFMA B-fragment order, fp16.
__global__ __launch_bounds__(256) void wmbuild_kernel(const float* __restrict__ linW,
                                                      _Float16* __restrict__ Wm) {
  int idx = blockIdx.x * 256 + threadIdx.x;
  if (idx >= LL * WMH) return;
  int l = idx / WMH, rest = idx % WMH;
  int t = rest >> 10;
  int nt = (rest >> 9) & 1;
  int L = (rest >> 3) & 63;
  int j = rest & 7;
  int k = t * 32 + (L >> 4) * 8 + j;
  int n = nt * 16 + (L & 15);
  int wrow;
  if (k < 32) wrow = k;
  else {
    int kk = k - 32;
    int slab = kk >> 7, s = (kk >> 5) & 3, dd = kk & 31;
    wrow = DD + (dd * 4 + s) * 3 + slab;
  }
  Wm[idx] = (_Float16)linW[(size_t)l * THD * DD + (size_t)wrow * DD + n];
}

// ---------------- phase 1: gather-reduce PNA stats ----------------
// One 64-lane wave per node; lane owns a half2. Wave-uniform 8B edge records
// (readfirstlane'd base -> scalar loads). Batch-8 two-stage pipeline: issue
// batch i+1's 16 row-loads before processing batch i (16-32 in flight).
__global__ __launch_bounds__(256) void gather_kernel(const __half2* __restrict__ hin2,
                                                     const __half2* __restrict__ rel2,
                                                     const int2* __restrict__ ep,
                                                     const int* __restrict__ base,
                                                     const int* __restrict__ cnt,
                                                     const float* __restrict__ cntf,
                                                     const int* __restrict__ h_index,
                                                     const float* __restrict__ query,
                                                     __half2* __restrict__ statsH) {
  const int lane = threadIdx.x & 63;
  const int n = blockIdx.x * 4 + (threadIdx.x >> 6);   // NN % 4 == 0
  const int b = lane >> 4;
  const int d0 = (lane & 15) * 2;
  const float q0 = query[b * 32 + d0], q1 = query[b * 32 + d0 + 1];
  const int hb = h_index[b];
  const int beg = __builtin_amdgcn_readfirstlane(base[n]);
  const int cnn = __builtin_amdgcn_readfirstlane(cnt[n]);
  const float mb0 = (n == hb) ? q0 : 0.f;
  const float mb1 = (n == hb) ? q1 : 0.f;
  float sa0 = mb0, qa0 = mb0 * mb0, mx0 = mb0, mn0 = mb0;
  float sa1 = mb1, qa1 = mb1 * mb1, mx1 = mb1, mn1 = mb1;

#define PROC(Ez, Hv, Rv) {                                                   \
    float w = __int_as_float(Ez);                                            \
    float2 hf = __half22float2(Hv), rf = __half22float2(Rv);                 \
    float m0 = rf.x * hf.x, mw0 = m0 * w;                                    \
    float m1 = rf.y * hf.y, mw1 = m1 * w;                                    \
    sa0 += mw0; qa0 = fmaf(m0, mw0, qa0);                                    \
    mx0 = fmaxf(mx0, mw0); mn0 = fminf(mn0, mw0);                            \
    sa1 += mw1; qa1 = fmaf(m1, mw1, qa1);                                    \
    mx1 = fmaxf(mx1, mw1); mn1 = fminf(mn1, mw1); }
#define ROWS(Ex, Hd, Rd) {                                                   \
    Hd = hin2[(unsigned)((Ex) & 0x7fff) * 64 + lane];                        \
    Rd = rel2[(unsigned)((unsigned)(Ex) >> 15) * 64 + lane]; }

  int p = beg;
  int rem = cnn;
  const int nb = rem >> 3;
  if (nb > 0) {
    int2 E0, E1, E2, E3, E4, E5, E6, E7;
    __half2 H0, H1, H2, H3, H4, H5, H6, H7;
    __half2 R0, R1, R2, R3, R4, R5, R6, R7;
    E0 = ep[p];     E1 = ep[p + 1]; E2 = ep[p + 2]; E3 = ep[p + 3];
    E4 = ep[p + 4]; E5 = ep[p + 5]; E6 = ep[p + 6]; E7 = ep[p + 7];
    ROWS(E0.x, H0, R0); ROWS(E1.x, H1, R1); ROWS(E2.x, H2, R2); ROWS(E3.x, H3, R3);
    ROWS(E4.x, H4, R4); ROWS(E5.x, H5, R5); ROWS(E6.x, H6, R6); ROWS(E7.x, H7, R7);
    for (int it = 1; it < nb; ++it) {
      const int pn = p + 8;
      int2 F0 = ep[pn],     F1 = ep[pn + 1], F2 = ep[pn + 2], F3 = ep[pn + 3];
      int2 F4 = ep[pn + 4], F5 = ep[pn + 5], F6 = ep[pn + 6], F7 = ep[pn + 7];
      __half2 G0, G1, G2, G3, G4, G5, G6, G7;
      __half2 S0, S1, S2, S3, S4, S5, S6, S7;
      ROWS(F0.x, G0, S0); ROWS(F1.x, G1, S1); ROWS(F2.x, G2, S2); ROWS(F3.x, G3, S3);
      ROWS(F4.x, G4, S4); ROWS(F5.x, G5, S5); ROWS(F6.x, G6, S6); ROWS(F7.x, G7, S7);
      PROC(E0.y, H0, R0); PROC(E1.y, H1, R1); PROC(E2.y, H2, R2); PROC(E3.y, H3, R3);
      PROC(E4.y, H4, R4); PROC(E5.y, H5, R5); PROC(E6.y, H6, R6); PROC(E7.y, H7, R7);
      E0 = F0; E1 = F1; E2 = F2; E3 = F3; E4 = F4; E5 = F5; E6 = F6; E7 = F7;
      H0 = G0; H1 = G1; H2 = G2; H3 = G3; H4 = G4; H5 = G5; H6 = G6; H7 = G7;
      R0 = S0; R1 = S1; R2 = S2; R3 = S3; R4 = S4; R5 = S5; R6 = S6; R7 = S7;
      p = pn;
    }
    PROC(E0.y, H0, R0); PROC(E1.y, H1, R1); PROC(E2.y, H2, R2); PROC(E3.y, H3, R3);
    PROC(E4.y, H4, R4); PROC(E5.y, H5, R5); PROC(E6.y, H6, R6); PROC(E7.y, H7, R7);
    p += 8;
    rem -= nb << 3;
  }
  if (rem >= 4) {
    int2 E0 = ep[p], E1 = ep[p + 1], E2 = ep[p + 2], E3 = ep[p + 3];
    __half2 H0, H1, H2, H3, R0, R1, R2, R3;
    ROWS(E0.x, H0, R0); ROWS(E1.x, H1, R1); ROWS(E2.x, H2, R2); ROWS(E3.x, H3, R3);
    PROC(E0.y, H0, R0); PROC(E1.y, H1, R1); PROC(E2.y, H2, R2); PROC(E3.y, H3, R3);
    p += 4; rem -= 4;
  }
  for (; rem > 0; --rem, ++p) {
    int2 e = ep[p];
    __half2 hv, rv;
    ROWS(e.x, hv, rv);
    PROC(e.y, hv, rv);
  }
#undef ROWS
#undef PROC
  const float invc = 1.0f / cntf[n];
  const float mean0 = sa0 * invc, mean1 = sa1 * invc;
  const float sd0 = sqrtf(fmaxf(qa0 * invc - mean0 * mean0, EPSF));
  const float sd1 = sqrtf(fmaxf(qa1 * invc - mean1 * mean1, EPSF));
  __half2* sp = statsH + (unsigned)n * 256 + lane;
  sp[0]   = __floats2half2_rn(mean0, mean1);
  sp[64]  = __floats2half2_rn(mx0, mx1);
  sp[128] = __floats2half2_rn(mn0, mn1);
  sp[192] = __floats2half2_rn(sd0, sd1);
}

// ---------------- phase 2: 416->32 linear via MFMA ----------------
__global__ __launch_bounds__(128) void mfma_linear_kernel(const _Float16* __restrict__ hinh,
                                                          __half* __restrict__ houth,
                                                          const _Float16* __restrict__ statsH,
                                                          const float* __restrict__ scales,
                                                          const _Float16* __restrict__ Wm,
                                                          const float* __restrict__ bias) {
  const int lane = threadIdx.x & 63;
  const int wid  = threadIdx.x >> 6;
  const int nbase = blockIdx.x * 8 + wid * 4;    // NN % 8 == 0
  const int m = lane & 15;
  const int q = lane >> 4;
  const int n = nbase + (m >> 2);
  const int b = m & 3;
  const _Float16 one = (_Float16)1.f;
  const _Float16 s1h = (_Float16)scales[n * 2 + 0];
  const _Float16 s2h = (_Float16)scales[n * 2 + 1];
  const _Float16* hsrc = hinh   + (unsigned)n * BD  + b * 32 + q * 8;
  const _Float16* ssrc = statsH + (unsigned)n * 512 + b * 32 + q * 8;

  f32x4 c0 = {0.f, 0.f, 0.f, 0.f};
  f32x4 c1 = {0.f, 0.f, 0.f, 0.f};
  #pragma unroll
  for (int t = 0; t < 13; ++t) {
    half8 a;
    if (t == 0) {
      a = *(const half8*)hsrc;
    } else {
      const int slab = (t - 1) >> 2, s = (t - 1) & 3;
      a = *(const half8*)(ssrc + s * 128);
      const _Float16 sc = (slab == 0) ? one : ((slab == 1) ? s1h : s2h);
      half8 sv = {sc, sc, sc, sc, sc, sc, sc, sc};
      a = a * sv;
    }
    half8 b0 = *(const half8*)(Wm + (unsigned)(t * 2 + 0) * 512 + lane * 8);
    half8 b1 = *(const half8*)(Wm + (unsigned)(t * 2 + 1) * 512 + lane * 8);
    c0 = __builtin_amdgcn_mfma_f32_16x16x32_f16(a, b0, c0, 0, 0, 0);
    c1 = __builtin_amdgcn_mfma_f32_16x16x32_f16(a, b1, c1, 0, 0, 0);
  }
  const int col = lane & 15;
  const float bj0 = bias[col], bj1 = bias[col + 16];
  #pragma unroll
  for (int i = 0; i < 4; ++i) {
    const int mr = q * 4 + i;
    const int nl = mr >> 2, bq = mr & 3;
    __half* dst = houth + (unsigned)(nbase + nl) * BD + bq * 32 + col;
    dst[0]  = __float2half(fmaxf(c0[i] + bj0, 0.f));
    dst[16] = __float2half(fmaxf(c1[i] + bj1, 0.f));
  }
}

// final MLP: [hidden(fp16), query] (64) -> relu(64) -> 1, out[b*N + n]
__global__ __launch_bounds__(128) void mlp_kernel(const __half* __restrict__ hinh,
                                                  const float* __restrict__ query,
                                                  const float* __restrict__ W1,
                                                  const float* __restrict__ b1,
                                                  const float* __restrict__ W2,
                                                  const float* __restrict__ b2,
                                                  float* __restrict__ out) {
  __shared__ float f2[BB][2 * DD];
  const int t = threadIdx.x;
  const int b = t >> 5, d = t & 31;
  const float qv = query[t];
  const float w2a = W2[d], w2b = W2[DD + d];
  const float b1a = b1[d], b1b = b1[DD + d];
  const float b2v = b2[0];
  const int NPBM = 8;
  int n0 = blockIdx.x * NPBM, n1 = min(n0 + NPBM, NN);
  for (int n = n0; n < n1; ++n) {
    f2[b][d]      = __half2float(hinh[(unsigned)n * BD + t]);
    f2[b][DD + d] = qv;
    float a0 = b1a, a1 = b1b;
    #pragma unroll
    for (int i = 0; i < 2 * DD; ++i) {
      float v = f2[b][i];
      a0 = fmaf(v, W1[i * 2 * DD + d], a0);
      a1 = fmaf(v, W1[i * 2 * DD + DD + d], a1);
    }
    a0 = fmaxf(a0, 0.f); a1 = fmaxf(a1, 0.f);
    float part = a0 * w2a + a1 * w2b;
    #pragma unroll
    for (int off = 16; off > 0; off >>= 1) part += __shfl_down(part, off, 32);
    if (d == 0) out[b * NN + n] = part + b2v;
  }
}

extern "C" void kernel_launch(void* const* d_in, const int* in_sizes, int n_in,
                              void* d_out, int out_size, void* d_ws, size_t ws_size,
                              hipStream_t stream) {
  const int*   node_in  = (const int*)d_in[0];
  const int*   node_out = (const int*)d_in[1];
  const int*   relation = (const int*)d_in[2];
  const float* ew       = (const float*)d_in[3];
  const int*   h_index  = (const int*)d_in[4];
  const int*   r_index  = (const int*)d_in[5];
  const float* qemb     = (const float*)d_in[6];
  const float* relW     = (const float*)d_in[7];
  const float* relB     = (const float*)d_in[8];
  const float* linW     = (const float*)d_in[9];
  const float* linB     = (const float*)d_in[10];
  const float* W1       = (const float*)d_in[11];
  const float* b1       = (const float*)d_in[12];
  const float* W2       = (const float*)d_in[13];
  const float* b2       = (const float*)d_in[14];
  float* out = (float*)d_out;

  char* ws = (char*)d_ws;
  size_t off = 0;
  auto alloc = [&](size_t bytes) -> char* {
    char* p = ws + off;
    off += (bytes + 255) & ~(size_t)255;
    return p;
  };
  __half*   h0     = (__half*)  alloc((size_t)NN * BD * 2);
  __half*   h1     = (__half*)  alloc((size_t)NN * BD * 2);
  __half*   relIn  = (__half*)  alloc((size_t)LL * R2C * BD * 2);
  __half*   statsH = (__half*)  alloc((size_t)NN * 512 * 2);
  _Float16* Wm     = (_Float16*)alloc((size_t)LL * WMH * 2);
  int2*     ep     = (int2*)    alloc(((size_t)EE + NN) * 8);  // even-aligned segs
  int*      pidx   = (int*)     alloc((size_t)EE * 4);
  int*      base   = (int*)     alloc((size_t)NN * 4);
  int*      cnti   = (int*)     alloc((size_t)NN * 4);
  float*    lg     = (float*)   alloc((size_t)NN * 4);
  float*    cntf   = (float*)   alloc((size_t)NN * 4);
  float*    scales = (float*)   alloc((size_t)NN * 2 * 4);
  float*    query  = (float*)   alloc((size_t)BD * 4);
  float*    stats  = (float*)   alloc(256);   // [0]=logsum (f32), [1]=gcnt (int)

  hipMemsetAsync(cnti, 0, (size_t)NN * 4, stream);
  hipMemsetAsync(stats, 0, 256, stream);
  hipMemsetAsync(h0,   0, (size_t)NN * BD * 2, stream);

  float* logsum = stats;
  int*   gcnt   = (int*)stats + 1;

  pidx_kernel   <<<(EE + 255) / 256, 256, 0, stream>>>(node_out, cnti, pidx);
  prep_kernel   <<<(NN + 255) / 256, 256, 0, stream>>>(cnti, base, cntf, gcnt);
  scatter_kernel<<<(EE + 255) / 256, 256, 0, stream>>>(node_in, node_out, relation, ew,
                                                       base, pidx, ep);
  wdeg_kernel   <<<(NN + 255) / 256, 256, 0, stream>>>(base, cnti, ep, lg, logsum);
  scales_kernel <<<(NN + 255) / 256, 256, 0, stream>>>(lg, logsum, scales);
  init_kernel   <<<1, 128, 0, stream>>>(h_index, r_index, qemb, query, h0);
  wmbuild_kernel<<<(LL * WMH + 255) / 256, 256, 0, stream>>>(linW, Wm);
  relin_all_kernel<<<(LL * R2C * BD + 255) / 256, 256, 0, stream>>>(query, relW, relB, relIn);

  __half* hin = h0; __half* hout = h1;
  for (int l = 0; l < LL; ++l) {
    gather_kernel<<<NN / 4, 256, 0, stream>>>(
        (const __half2*)hin, (const __half2*)relIn + (size_t)l * R2C * 64,
        ep, base, cnti, cntf, h_index, query, (__half2*)statsH);
    mfma_linear_kernel<<<NN / 8, 128, 0, stream>>>(
        (const _Float16*)hin, hout, (const _Float16*)statsH, scales,
        Wm + (size_t)l * WMH, linB + (size_t)l * DD);
    __half* tmp = hin; hin = hout; hout = tmp;
  }
  mlp_kernel<<<(NN + 7) / 8, 128, 0, stream>>>(hin, query, W1, b1, W2, b2, out);
}

// Round 11
// 302.509 us; speedup vs baseline: 4.2045x; 1.0361x over previous
//
#include <hip/hip_runtime.h>
#include <hip/hip_fp16.h>

#define NN  25000
#define EE  500000
#define BB  4
#define DD  32
#define LL  4
#define R2C 474
#define BD  128      // B*D
#define THD 416      // 13*D
#define EPSF 1e-6f
#define WMH 13312    // halfs per layer of MFMA-packed W: 13 t * 2 nt * 64 * 8

typedef _Float16 half8 __attribute__((ext_vector_type(8)));
typedef float    f32x4 __attribute__((ext_vector_type(4)));

// ---------------- graph build ----------------
// Fused count + slot assignment, 4 edges/thread (4 atomics in flight).
__global__ __launch_bounds__(256) void pidx_kernel(const int4* __restrict__ no4,
                                                   int* __restrict__ cnt,
                                                   int4* __restrict__ pidx4) {
  int i = blockIdx.x * 256 + threadIdx.x;
  if (i >= EE / 4) return;
  int4 d = no4[i];
  int4 r;
  r.x = atomicAdd(&cnt[d.x], 1);
  r.y = atomicAdd(&cnt[d.y], 1);
  r.z = atomicAdd(&cnt[d.z], 1);
  r.w = atomicAdd(&cnt[d.w], 1);
  pidx4[i] = r;
}

// Order-free CSR with EVEN-aligned segments (64B-aligned batch loads).
__global__ __launch_bounds__(256) void prep_kernel(const int* __restrict__ cnt,
                                                   int* __restrict__ base,
                                                   float* __restrict__ cntf,
                                                   int* __restrict__ gcnt) {
  int n = blockIdx.x * 256 + threadIdx.x;
  if (n >= NN) return;
  int c = cnt[n];
  base[n] = atomicAdd(gcnt, (c + 1) & ~1);   // even-size bump alloc
  cntf[n] = (float)(c + 1);                  // indeg + self entry
}

// atomic-free scatter of 8B records {node_in | rel<<15, w_bits}, 4 edges/thread
__global__ __launch_bounds__(256) void scatter_kernel(const int4* __restrict__ ni4,
                                                      const int4* __restrict__ no4,
                                                      const int4* __restrict__ rl4,
                                                      const float4* __restrict__ ew4,
                                                      const int* __restrict__ base,
                                                      const int4* __restrict__ pidx4,
                                                      int2* __restrict__ ep) {
  int i = blockIdx.x * 256 + threadIdx.x;
  if (i >= EE / 4) return;
  int4 ni = ni4[i], no = no4[i], rl = rl4[i], pi = pidx4[i];
  float4 w = ew4[i];
  ep[base[no.x] + pi.x] = make_int2(ni.x | (rl.x << 15), __float_as_int(w.x));
  ep[base[no.y] + pi.y] = make_int2(ni.y | (rl.y << 15), __float_as_int(w.y));
  ep[base[no.z] + pi.z] = make_int2(ni.z | (rl.z << 15), __float_as_int(w.z));
  ep[base[no.w] + pi.w] = make_int2(ni.w | (rl.w << 15), __float_as_int(w.w));
}

// per-node weighted degree from packed segments; block-reduced logsum.
__global__ __launch_bounds__(256) void wdeg_kernel(const int* __restrict__ base,
                                                   const int* __restrict__ cnt,
                                                   const int2* __restrict__ ep,
                                                   float* __restrict__ lg,
                                                   float* __restrict__ logsum) {
  int n = blockIdx.x * 256 + threadIdx.x;
  float v = 0.f;
  if (n < NN) {
    int b = base[n], c = cnt[n];
    float s = 0.f;
    for (int p = b; p < b + c; ++p) s += __int_as_float(ep[p].y);
    v = logf(s + 1.0f);
    lg[n] = v;
  }
  __shared__ float red[256];
  red[threadIdx.x] = v; __syncthreads();
  for (int o = 128; o > 0; o >>= 1) {
    if (threadIdx.x < o) red[threadIdx.x] += red[threadIdx.x + o];
    __syncthreads();
  }
  if (threadIdx.x == 0) atomicAdd(logsum, red[0]);
}

// query gather + boundary placement (h0 pre-zeroed; fp16 zero == 0x0000)
__global__ __launch_bounds__(128) void init_kernel(const int* __restrict__ h_index,
                                                   const int* __restrict__ r_index,
                                                   const float* __restrict__ qemb,
                                                   float* __restrict__ query,
                                                   __half* __restrict__ h0) {
  int t = threadIdx.x; int b = t >> 5, d = t & 31;
  float qv = qemb[r_index[b] * DD + d];
  query[t] = qv;
  h0[h_index[b] * BD + t] = __float2half(qv);
}

// rel_in for ALL layers upfront (depends only on query, not hidden)
__global__ __launch_bounds__(256) void relin_all_kernel(const float* __restrict__ query,
                                                        const float* __restrict__ relW,
                                                        const float* __restrict__ relB,
                                                        __half* __restrict__ relIn) {
  int o = blockIdx.x * 256 + threadIdx.x;
  if (o >= LL * R2C * BD) return;
  int l = o / (R2C * BD);
  int rest = o % (R2C * BD);
  int r = rest >> 7, b = (rest >> 5) & 3, d = rest & 31;
  int col = r * DD + d;
  const float* W = relW + (size_t)l * DD * R2C * DD;
  float acc = relB[(size_t)l * R2C * DD + col];
  #pragma unroll
  for (int k = 0; k < DD; ++k)
    acc = fmaf(query[b * DD + k], W[(size_t)k * (R2C * DD) + col], acc);
  relIn[o] = __float2half(acc);
}

// Pack lin_W into MFMA B-fragment order, fp16.
__global__ __launch_bounds__(256) void wmbuild_kernel(const float* __restrict__ linW,
                                                      _Float16* __restrict__ Wm) {
  int idx = blockIdx.x * 256 + threadIdx.x;
  if (idx >= LL * WMH) return;
  int l = idx / WMH, rest = idx % WMH;
  int t = rest >> 10;
  int nt = (rest >> 9) & 1;
  int L = (rest >> 3) & 63;
  int j = rest & 7;
  int k = t * 32 + (L >> 4) * 8 + j;
  int n = nt * 16 + (L & 15);
  int wrow;
  if (k < 32) wrow = k;
  else {
    int kk = k - 32;
    int slab = kk >> 7, s = (kk >> 5) & 3, dd = kk & 31;
    wrow = DD + (dd * 4 + s) * 3 + slab;
  }
  Wm[idx] = (_Float16)linW[(size_t)l * THD * DD + (size_t)wrow * DD + n];
}

// ---------------- layer-1 specialized gather ----------------
// hidden == boundary: message at lane slot (b,d) is nonzero iff
// node_in == h_index[b], and then equals rel_in[r][b][d] * query[b][d] * w.
// Zero messages only affect max/min (fold a single 0 post-loop).
__global__ __launch_bounds__(256) void gather1_kernel(const __half2* __restrict__ rel2,
                                                      const int2* __restrict__ ep,
                                                      const int* __restrict__ base,
                                                      const int* __restrict__ cnt,
                                                      const float* __restrict__ cntf,
                                                      const int* __restrict__ h_index,
                                                      const float* __restrict__ query,
                                                      __half2* __restrict__ statsH) {
  const int lane = threadIdx.x & 63;
  const int n = blockIdx.x * 4 + (threadIdx.x >> 6);   // NN % 4 == 0
  const int b = lane >> 4;
  const int d0 = (lane & 15) * 2;
  const float q0 = query[b * 32 + d0], q1 = query[b * 32 + d0 + 1];
  const int hb = h_index[b];
  const int beg = __builtin_amdgcn_readfirstlane(base[n]);
  const int cnn = __builtin_amdgcn_readfirstlane(cnt[n]);
  const float mb0 = (n == hb) ? q0 : 0.f;
  const float mb1 = (n == hb) ? q1 : 0.f;
  float sa0 = mb0, qa0 = mb0 * mb0, mx0 = mb0, mn0 = mb0;
  float sa1 = mb1, qa1 = mb1 * mb1, mx1 = mb1, mn1 = mb1;
  int matched = 0;
  for (int p = beg; p < beg + cnn; ++p) {
    int2 e = ep[p];
    int src = e.x & 0x7fff;
    if (src == hb) {
      __half2 rv = rel2[(unsigned)((unsigned)e.x >> 15) * 64 + lane];
      float w = __int_as_float(e.y);
      float2 rf = __half22float2(rv);
      float m0 = rf.x * q0, mw0 = m0 * w;
      float m1 = rf.y * q1, mw1 = m1 * w;
      sa0 += mw0; qa0 = fmaf(m0, mw0, qa0); mx0 = fmaxf(mx0, mw0); mn0 = fminf(mn0, mw0);
      sa1 += mw1; qa1 = fmaf(m1, mw1, qa1); mx1 = fmaxf(mx1, mw1); mn1 = fminf(mn1, mw1);
      ++matched;
    }
  }
  if (matched < cnn) {   // at least one zero message hit this lane's slots
    mx0 = fmaxf(mx0, 0.f); mn0 = fminf(mn0, 0.f);
    mx1 = fmaxf(mx1, 0.f); mn1 = fminf(mn1, 0.f);
  }
  const float invc = 1.0f / cntf[n];
  const float mean0 = sa0 * invc, mean1 = sa1 * invc;
  const float sd0 = sqrtf(fmaxf(qa0 * invc - mean0 * mean0, EPSF));
  const float sd1 = sqrtf(fmaxf(qa1 * invc - mean1 * mean1, EPSF));
  __half2* sp = statsH + (unsigned)n * 256 + lane;
  sp[0]   = __floats2half2_rn(mean0, mean1);
  sp[64]  = __floats2half2_rn(mx0, mx1);
  sp[128] = __floats2half2_rn(mn0, mn1);
  sp[192] = __floats2half2_rn(sd0, sd1);
}

// ---------------- generic gather (layers 2..L) ----------------
// One 64-lane wave per node; lane owns a half2. Wave-uniform 8B edge records;
// batch-8 two-stage pipeline (16-32 row loads in flight).
__global__ __launch_bounds__(256) void gather_kernel(const __half2* __restrict__ hin2,
                                                     const __half2* __restrict__ rel2,
                                                     const int2* __restrict__ ep,
                                                     const int* __restrict__ base,
                                                     const int* __restrict__ cnt,
                                                     const float* __restrict__ cntf,
                                                     const int* __restrict__ h_index,
                                                     const float* __restrict__ query,
                                                     __half2* __restrict__ statsH) {
  const int lane = threadIdx.x & 63;
  const int n = blockIdx.x * 4 + (threadIdx.x >> 6);   // NN % 4 == 0
  const int b = lane >> 4;
  const int d0 = (lane & 15) * 2;
  const float q0 = query[b * 32 + d0], q1 = query[b * 32 + d0 + 1];
  const int hb = h_index[b];
  const int beg = __builtin_amdgcn_readfirstlane(base[n]);
  const int cnn = __builtin_amdgcn_readfirstlane(cnt[n]);
  const float mb0 = (n == hb) ? q0 : 0.f;
  const float mb1 = (n == hb) ? q1 : 0.f;
  float sa0 = mb0, qa0 = mb0 * mb0, mx0 = mb0, mn0 = mb0;
  float sa1 = mb1, qa1 = mb1 * mb1, mx1 = mb1, mn1 = mb1;

#define PROC(Ez, Hv, Rv) {                                                   \
    float w = __int_as_float(Ez);                                            \
    float2 hf = __half22float2(Hv), rf = __half22float2(Rv);                 \
    float m0 = rf.x * hf.x, mw0 = m0 * w;                                    \
    float m1 = rf.y * hf.y, mw1 = m1 * w;                                    \
    sa0 += mw0; qa0 = fmaf(m0, mw0, qa0);                                    \
    mx0 = fmaxf(mx0, mw0); mn0 = fminf(mn0, mw0);                            \
    sa1 += mw1; qa1 = fmaf(m1, mw1, qa1);                                    \
    mx1 = fmaxf(mx1, mw1); mn1 = fminf(mn1, mw1); }
#define ROWS(Ex, Hd, Rd) {                                                   \
    Hd = hin2[(unsigned)((Ex) & 0x7fff) * 64 + lane];                        \
    Rd = rel2[(unsigned)((unsigned)(Ex) >> 15) * 64 + lane]; }

  int p = beg;
  int rem = cnn;
  const int nb = rem >> 3;
  if (nb > 0) {
    int2 E0, E1, E2, E3, E4, E5, E6, E7;
    __half2 H0, H1, H2, H3, H4, H5, H6, H7;
    __half2 R0, R1, R2, R3, R4, R5, R6, R7;
    E0 = ep[p];     E1 = ep[p + 1]; E2 = ep[p + 2]; E3 = ep[p + 3];
    E4 = ep[p + 4]; E5 = ep[p + 5]; E6 = ep[p + 6]; E7 = ep[p + 7];
    ROWS(E0.x, H0, R0); ROWS(E1.x, H1, R1); ROWS(E2.x, H2, R2); ROWS(E3.x, H3, R3);
    ROWS(E4.x, H4, R4); ROWS(E5.x, H5, R5); ROWS(E6.x, H6, R6); ROWS(E7.x, H7, R7);
    for (int it = 1; it < nb; ++it) {
      const int pn = p + 8;
      int2 F0 = ep[pn],     F1 = ep[pn + 1], F2 = ep[pn + 2], F3 = ep[pn + 3];
      int2 F4 = ep[pn + 4], F5 = ep[pn + 5], F6 = ep[pn + 6], F7 = ep[pn + 7];
      __half2 G0, G1, G2, G3, G4, G5, G6, G7;
      __half2 S0, S1, S2, S3, S4, S5, S6, S7;
      ROWS(F0.x, G0, S0); ROWS(F1.x, G1, S1); ROWS(F2.x, G2, S2); ROWS(F3.x, G3, S3);
      ROWS(F4.x, G4, S4); ROWS(F5.x, G5, S5); ROWS(F6.x, G6, S6); ROWS(F7.x, G7, S7);
      PROC(E0.y, H0, R0); PROC(E1.y, H1, R1); PROC(E2.y, H2, R2); PROC(E3.y, H3, R3);
      PROC(E4.y, H4, R4); PROC(E5.y, H5, R5); PROC(E6.y, H6, R6); PROC(E7.y, H7, R7);
      E0 = F0; E1 = F1; E2 = F2; E3 = F3; E4 = F4; E5 = F5; E6 = F6; E7 = F7;
      H0 = G0; H1 = G1; H2 = G2; H3 = G3; H4 = G4; H5 = G5; H6 = G6; H7 = G7;
      R0 = S0; R1 = S1; R2 = S2; R3 = S3; R4 = S4; R5 = S5; R6 = S6; R7 = S7;
      p = pn;
    }
    PROC(E0.y, H0, R0); PROC(E1.y, H1, R1); PROC(E2.y, H2, R2); PROC(E3.y, H3, R3);
    PROC(E4.y, H4, R4); PROC(E5.y, H5, R5); PROC(E6.y, H6, R6); PROC(E7.y, H7, R7);
    p += 8;
    rem -= nb << 3;
  }
  if (rem >= 4) {
    int2 E0 = ep[p], E1 = ep[p + 1], E2 = ep[p + 2], E3 = ep[p + 3];
    __half2 H0, H1, H2, H3, R0, R1, R2, R3;
    ROWS(E0.x, H0, R0); ROWS(E1.x, H1, R1); ROWS(E2.x, H2, R2); ROWS(E3.x, H3, R3);
    PROC(E0.y, H0, R0); PROC(E1.y, H1, R1); PROC(E2.y, H2, R2); PROC(E3.y, H3, R3);
    p += 4; rem -= 4;
  }
  for (; rem > 0; --rem, ++p) {
    int2 e = ep[p];
    __half2 hv, rv;
    ROWS(e.x, hv, rv);
    PROC(e.y, hv, rv);
  }
#undef ROWS
#undef PROC
  const float invc = 1.0f / cntf[n];
  const float mean0 = sa0 * invc, mean1 = sa1 * invc;
  const float sd0 = sqrtf(fmaxf(qa0 * invc - mean0 * mean0, EPSF));
  const float sd1 = sqrtf(fmaxf(qa1 * invc - mean1 * mean1, EPSF));
  __half2* sp = statsH + (unsigned)n * 256 + lane;
  sp[0]   = __floats2half2_rn(mean0, mean1);
  sp[64]  = __floats2half2_rn(mx0, mx1);
  sp[128] = __floats2half2_rn(mn0, mn1);
  sp[192] = __floats2half2_rn(sd0, sd1);
}

// ---------------- 416->32 linear via MFMA ----------------
// Degree scales computed inline from lg/logsum (scales kernel dropped).
__global__ __launch_bounds__(128) void mfma_linear_kernel(const _Float16* __restrict__ hinh,
                                                          __half* __restrict__ houth,
                                                          const _Float16* __restrict__ statsH,
                                                          const float* __restrict__ lg,
                                                          const float* __restrict__ logsum,
                                                          const _Float16* __restrict__ Wm,
                                                          const float* __restrict__ bias) {
  const int lane = threadIdx.x & 63;
  const int wid  = threadIdx.x >> 6;
  const int nbase = blockIdx.x * 8 + wid * 4;    // NN % 8 == 0
  const int m = lane & 15;
  const int q = lane >> 4;
  const int n = nbase + (m >> 2);
  const int b = m & 3;
  const float invmean = (float)NN / logsum[0];
  const float sc = lg[n] * invmean;
  const _Float16 one = (_Float16)1.f;
  const _Float16 s1h = (_Float16)sc;
  const _Float16 s2h = (_Float16)(1.0f / fmaxf(sc, 0.01f));
  const _Float16* hsrc = hinh   + (unsigned)n * BD  + b * 32 + q * 8;
  const _Float16* ssrc = statsH + (unsigned)n * 512 + b * 32 + q * 8;

  f32x4 c0 = {0.f, 0.f, 0.f, 0.f};
  f32x4 c1 = {0.f, 0.f, 0.f, 0.f};
  #pragma unroll
  for (int t = 0; t < 13; ++t) {
    half8 a;
    if (t == 0) {
      a = *(const half8*)hsrc;
    } else {
      const int slab = (t - 1) >> 2, s = (t - 1) & 3;
      a = *(const half8*)(ssrc + s * 128);
      const _Float16 sch = (slab == 0) ? one : ((slab == 1) ? s1h : s2h);
      half8 sv = {sch, sch, sch, sch, sch, sch, sch, sch};
      a = a * sv;
    }
    half8 b0 = *(const half8*)(Wm + (unsigned)(t * 2 + 0) * 512 + lane * 8);
    half8 b1 = *(const half8*)(Wm + (unsigned)(t * 2 + 1) * 512 + lane * 8);
    c0 = __builtin_amdgcn_mfma_f32_16x16x32_f16(a, b0, c0, 0, 0, 0);
    c1 = __builtin_amdgcn_mfma_f32_16x16x32_f16(a, b1, c1, 0, 0, 0);
  }
  const int col = lane & 15;
  const float bj0 = bias[col], bj1 = bias[col + 16];
  #pragma unroll
  for (int i = 0; i < 4; ++i) {
    const int mr = q * 4 + i;
    const int nl = mr >> 2, bq = mr & 3;
    __half* dst = houth + (unsigned)(nbase + nl) * BD + bq * 32 + col;
    dst[0]  = __float2half(fmaxf(c0[i] + bj0, 0.f));
    dst[16] = __float2half(fmaxf(c1[i] + bj1, 0.f));
  }
}

// final MLP: [hidden(fp16), query] (64) -> relu(64) -> 1, out[b*N + n]
__global__ __launch_bounds__(128) void mlp_kernel(const __half* __restrict__ hinh,
                                                  const float* __restrict__ query,
                                                  const float* __restrict__ W1,
                                                  const float* __restrict__ b1,
                                                  const float* __restrict__ W2,
                                                  const float* __restrict__ b2,
                                                  float* __restrict__ out) {
  __shared__ float f2[BB][2 * DD];
  const int t = threadIdx.x;
  const int b = t >> 5, d = t & 31;
  const float qv = query[t];
  const float w2a = W2[d], w2b = W2[DD + d];
  const float b1a = b1[d], b1b = b1[DD + d];
  const float b2v = b2[0];
  const int NPBM = 8;
  int n0 = blockIdx.x * NPBM, n1 = min(n0 + NPBM, NN);
  for (int n = n0; n < n1; ++n) {
    f2[b][d]      = __half2float(hinh[(unsigned)n * BD + t]);
    f2[b][DD + d] = qv;
    float a0 = b1a, a1 = b1b;
    #pragma unroll
    for (int i = 0; i < 2 * DD; ++i) {
      float v = f2[b][i];
      a0 = fmaf(v, W1[i * 2 * DD + d], a0);
      a1 = fmaf(v, W1[i * 2 * DD + DD + d], a1);
    }
    a0 = fmaxf(a0, 0.f); a1 = fmaxf(a1, 0.f);
    float part = a0 * w2a + a1 * w2b;
    #pragma unroll
    for (int off = 16; off > 0; off >>= 1) part += __shfl_down(part, off, 32);
    if (d == 0) out[b * NN + n] = part + b2v;
  }
}

extern "C" void kernel_launch(void* const* d_in, const int* in_sizes, int n_in,
                              void* d_out, int out_size, void* d_ws, size_t ws_size,
                              hipStream_t stream) {
  const int*   node_in  = (const int*)d_in[0];
  const int*   node_out = (const int*)d_in[1];
  const int*   relation = (const int*)d_in[2];
  const float* ew       = (const float*)d_in[3];
  const int*   h_index  = (const int*)d_in[4];
  const int*   r_index  = (const int*)d_in[5];
  const float* qemb     = (const float*)d_in[6];
  const float* relW     = (const float*)d_in[7];
  const float* relB     = (const float*)d_in[8];
  const float* linW     = (const float*)d_in[9];
  const float* linB     = (const float*)d_in[10];
  const float* W1       = (const float*)d_in[11];
  const float* b1       = (const float*)d_in[12];
  const float* W2       = (const float*)d_in[13];
  const float* b2       = (const float*)d_in[14];
  float* out = (float*)d_out;

  char* ws = (char*)d_ws;
  size_t off = 0;
  auto alloc = [&](size_t bytes) -> char* {
    char* p = ws + off;
    off += (bytes + 255) & ~(size_t)255;
    return p;
  };
  __half*   h0     = (__half*)  alloc((size_t)NN * BD * 2);
  __half*   h1     = (__half*)  alloc((size_t)NN * BD * 2);
  __half*   relIn  = (__half*)  alloc((size_t)LL * R2C * BD * 2);
  __half*   statsH = (__half*)  alloc((size_t)NN * 512 * 2);
  _Float16* Wm     = (_Float16*)alloc((size_t)LL * WMH * 2);
  int2*     ep     = (int2*)    alloc(((size_t)EE + NN) * 8);  // even-aligned segs
  int*      pidx   = (int*)     alloc((size_t)EE * 4);
  int*      base   = (int*)     alloc((size_t)NN * 4);
  int*      cnti   = (int*)     alloc((size_t)NN * 4);
  float*    lg     = (float*)   alloc((size_t)NN * 4);
  float*    cntf   = (float*)   alloc((size_t)NN * 4);
  float*    query  = (float*)   alloc((size_t)BD * 4);
  float*    stats  = (float*)   alloc(256);   // [0]=logsum (f32), [1]=gcnt (int)

  hipMemsetAsync(cnti, 0, (size_t)NN * 4, stream);
  hipMemsetAsync(stats, 0, 256, stream);
  hipMemsetAsync(h0,   0, (size_t)NN * BD * 2, stream);

  float* logsum = stats;
  int*   gcnt   = (int*)stats + 1;

  pidx_kernel   <<<(EE / 4 + 255) / 256, 256, 0, stream>>>((const int4*)node_out,
                                                           cnti, (int4*)pidx);
  prep_kernel   <<<(NN + 255) / 256, 256, 0, stream>>>(cnti, base, cntf, gcnt);
  scatter_kernel<<<(EE / 4 + 255) / 256, 256, 0, stream>>>(
      (const int4*)node_in, (const int4*)node_out, (const int4*)relation,
      (const float4*)ew, base, (const int4*)pidx, ep);
  wdeg_kernel   <<<(NN + 255) / 256, 256, 0, stream>>>(base, cnti, ep, lg, logsum);
  init_kernel   <<<1, 128, 0, stream>>>(h_index, r_index, qemb, query, h0);
  wmbuild_kernel<<<(LL * WMH + 255) / 256, 256, 0, stream>>>(linW, Wm);
  relin_all_kernel<<<(LL * R2C * BD + 255) / 256, 256, 0, stream>>>(query, relW, relB, relIn);

  __half* hin = h0; __half* hout = h1;
  for (int l = 0; l < LL; ++l) {
    if (l == 0) {
      gather1_kernel<<<NN / 4, 256, 0, stream>>>(
          (const __half2*)relIn, ep, base, cnti, cntf, h_index, query,
          (__half2*)statsH);
    } else {
      gather_kernel<<<NN / 4, 256, 0, stream>>>(
          (const __half2*)hin, (const __half2*)relIn + (size_t)l * R2C * 64,
          ep, base, cnti, cntf, h_index, query, (__half2*)statsH);
    }
    mfma_linear_kernel<<<NN / 8, 128, 0, stream>>>(
        (const _Float16*)hin, hout, (const _Float16*)statsH, lg, logsum,
        Wm + (size_t)l * WMH, linB + (size_t)l * DD);
    __half* tmp = hin; hin = hout; hout = tmp;
  }
  mlp_kernel<<<(NN + 7) / 8, 128, 0, stream>>>(hin, query, W1, b1, W2, b2, out);
}

// Round 12
// 288.497 us; speedup vs baseline: 4.4087x; 1.0486x over previous
//
#include <hip/hip_runtime.h>
#include <hip/hip_fp16.h>

#define NN  25000
#define EE  500000
#define BB  4
#define DD  32
#define LL  4
#define R2C 474
#define BD  128      // B*D
#define THD 416      // 13*D
#define EPSF 1e-6f
#define WMH 13312    // halfs per layer of MFMA-packed W: 13 t * 2 nt * 64 * 8

typedef _Float16 half8 __attribute__((ext_vector_type(8)));
typedef float    f32x4 __attribute__((ext_vector_type(4)));

// ---------------- graph build ----------------
// Fused count + slot assignment, 4 edges/thread (4 atomics in flight).
__global__ __launch_bounds__(256) void pidx_kernel(const int4* __restrict__ no4,
                                                   int* __restrict__ cnt,
                                                   int4* __restrict__ pidx4) {
  int i = blockIdx.x * 256 + threadIdx.x;
  if (i >= EE / 4) return;
  int4 d = no4[i];
  int4 r;
  r.x = atomicAdd(&cnt[d.x], 1);
  r.y = atomicAdd(&cnt[d.y], 1);
  r.z = atomicAdd(&cnt[d.z], 1);
  r.w = atomicAdd(&cnt[d.w], 1);
  pidx4[i] = r;
}

// Order-free CSR with EVEN-aligned segments.
__global__ __launch_bounds__(256) void prep_kernel(const int* __restrict__ cnt,
                                                   int* __restrict__ base,
                                                   int* __restrict__ gcnt) {
  int n = blockIdx.x * 256 + threadIdx.x;
  if (n >= NN) return;
  base[n] = atomicAdd(gcnt, (cnt[n] + 1) & ~1);
}

// atomic-free scatter of 8B records {node_in | rel<<15, w_bits}, 4 edges/thread
__global__ __launch_bounds__(256) void scatter_kernel(const int4* __restrict__ ni4,
                                                      const int4* __restrict__ no4,
                                                      const int4* __restrict__ rl4,
                                                      const float4* __restrict__ ew4,
                                                      const int* __restrict__ base,
                                                      const int4* __restrict__ pidx4,
                                                      int2* __restrict__ ep) {
  int i = blockIdx.x * 256 + threadIdx.x;
  if (i >= EE / 4) return;
  int4 ni = ni4[i], no = no4[i], rl = rl4[i], pi = pidx4[i];
  float4 w = ew4[i];
  ep[base[no.x] + pi.x] = make_int2(ni.x | (rl.x << 15), __float_as_int(w.x));
  ep[base[no.y] + pi.y] = make_int2(ni.y | (rl.y << 15), __float_as_int(w.y));
  ep[base[no.z] + pi.z] = make_int2(ni.z | (rl.z << 15), __float_as_int(w.z));
  ep[base[no.w] + pi.w] = make_int2(ni.w | (rl.w << 15), __float_as_int(w.w));
}

// per-node weighted degree from packed segments; block-reduced logsum.
__global__ __launch_bounds__(256) void wdeg_kernel(const int* __restrict__ base,
                                                   const int* __restrict__ cnt,
                                                   const int2* __restrict__ ep,
                                                   float* __restrict__ lg,
                                                   float* __restrict__ logsum) {
  int n = blockIdx.x * 256 + threadIdx.x;
  float v = 0.f;
  if (n < NN) {
    int b = base[n], c = cnt[n];
    float s = 0.f;
    for (int p = b; p < b + c; ++p) s += __int_as_float(ep[p].y);
    v = logf(s + 1.0f);
    lg[n] = v;
  }
  __shared__ float red[256];
  red[threadIdx.x] = v; __syncthreads();
  for (int o = 128; o > 0; o >>= 1) {
    if (threadIdx.x < o) red[threadIdx.x] += red[threadIdx.x + o];
    __syncthreads();
  }
  if (threadIdx.x == 0) atomicAdd(logsum, red[0]);
}

// query gather only (boundary handled analytically in layer 1)
__global__ __launch_bounds__(128) void init_kernel(const int* __restrict__ r_index,
                                                   const float* __restrict__ qemb,
                                                   float* __restrict__ query) {
  int t = threadIdx.x; int b = t >> 5, d = t & 31;
  query[t] = qemb[r_index[b] * DD + d];
}

// rel_in for ALL layers upfront (depends only on query, not hidden)
__global__ __launch_bounds__(256) void relin_all_kernel(const float* __restrict__ query,
                                                        const float* __restrict__ relW,
                                                        const float* __restrict__ relB,
                                                        __half* __restrict__ relIn) {
  int o = blockIdx.x * 256 + threadIdx.x;
  if (o >= LL * R2C * BD) return;
  int l = o / (R2C * BD);
  int rest = o % (R2C * BD);
  int r = rest >> 7, b = (rest >> 5) & 3, d = rest & 31;
  int col = r * DD + d;
  const float* W = relW + (size_t)l * DD * R2C * DD;
  float acc = relB[(size_t)l * R2C * DD + col];
  #pragma unroll
  for (int k = 0; k < DD; ++k)
    acc = fmaf(query[b * DD + k], W[(size_t)k * (R2C * DD) + col], acc);
  relIn[o] = __float2half(acc);
}

// Pack lin_W into MFMA B-fragment order, fp16.
__global__ __launch_bounds__(256) void wmbuild_kernel(const float* __restrict__ linW,
                                                      _Float16* __restrict__ Wm) {
  int idx = blockIdx.x * 256 + threadIdx.x;
  if (idx >= LL * WMH) return;
  int l = idx / WMH, rest = idx % WMH;
  int t = rest >> 10;
  int nt = (rest >> 9) & 1;
  int L = (rest >> 3) & 63;
  int j = rest & 7;
  int k = t * 32 + (L >> 4) * 8 + j;
  int n = nt * 16 + (L & 15);
  int wrow;
  if (k < 32) wrow = k;
  else {
    int kk = k - 32;
    int slab = kk >> 7, s = (kk >> 5) & 3, dd = kk & 31;
    wrow = DD + (dd * 4 + s) * 3 + slab;
  }
  Wm[idx] = (_Float16)linW[(size_t)l * THD * DD + (size_t)wrow * DD + n];
}

// ---- shared MFMA epilogue: one wave computes 16x32 linear for 4 nodes ----
// sh layout: [nl][s*128 + b*32 + d] halfs (s = mean,max,min,std).
// hzero: if true, t=0 A-fragment is analytic boundary (layer 1).
__device__ __forceinline__ void mfma_epilogue(const _Float16* sh,
                                              const _Float16* hinh,
                                              __half* houth,
                                              const float* lg,
                                              const float* logsum,
                                              const _Float16* Wm,
                                              const float* bias,
                                              const float* query,
                                              const int* h_index,
                                              int nbase, int lane, bool hzero) {
  const int m = lane & 15;
  const int q = lane >> 4;
  const int nl = m >> 2;
  const int n = nbase + nl;
  const int b = m & 3;
  const float sc = lg[n] * ((float)NN / logsum[0]);
  const _Float16 one = (_Float16)1.f;
  const _Float16 s1h = (_Float16)sc;
  const _Float16 s2h = (_Float16)(1.0f / fmaxf(sc, 0.01f));
  const _Float16* ssrc = sh + nl * 512 + b * 32 + q * 8;

  f32x4 c0 = {0.f, 0.f, 0.f, 0.f};
  f32x4 c1 = {0.f, 0.f, 0.f, 0.f};
  half8 a;
  if (hzero) {
    a = (half8)(_Float16)0.f;
    if (n == h_index[b]) {
      const float* qp = query + b * 32 + q * 8;
      #pragma unroll
      for (int j = 0; j < 8; ++j) a[j] = (_Float16)qp[j];
    }
  } else {
    a = *(const half8*)(hinh + (unsigned)n * BD + b * 32 + q * 8);
  }
  #pragma unroll
  for (int t = 0; t < 13; ++t) {
    if (t > 0) {
      const int slab = (t - 1) >> 2, s = (t - 1) & 3;
      a = *(const half8*)(ssrc + s * 128);
      const _Float16 sch = (slab == 0) ? one : ((slab == 1) ? s1h : s2h);
      half8 sv = {sch, sch, sch, sch, sch, sch, sch, sch};
      a = a * sv;
    }
    half8 b0 = *(const half8*)(Wm + (unsigned)(t * 2 + 0) * 512 + lane * 8);
    half8 b1 = *(const half8*)(Wm + (unsigned)(t * 2 + 1) * 512 + lane * 8);
    c0 = __builtin_amdgcn_mfma_f32_16x16x32_f16(a, b0, c0, 0, 0, 0);
    c1 = __builtin_amdgcn_mfma_f32_16x16x32_f16(a, b1, c1, 0, 0, 0);
  }
  const int col = lane & 15;
  const float bj0 = bias[col], bj1 = bias[col + 16];
  #pragma unroll
  for (int i = 0; i < 4; ++i) {
    const int mr = q * 4 + i;
    __half* dst = houth + (unsigned)(nbase + (mr >> 2)) * BD + (mr & 3) * 32 + col;
    dst[0]  = __float2half(fmaxf(c0[i] + bj0, 0.f));
    dst[16] = __float2half(fmaxf(c1[i] + bj1, 0.f));
  }
}

// ---------------- fused layer 1: analytic sparse gather + MFMA linear ------
__global__ __launch_bounds__(256) void layer1_fused_kernel(
    const __half2* __restrict__ rel2, const int2* __restrict__ ep,
    const int* __restrict__ base, const int* __restrict__ cnt,
    const int* __restrict__ h_index, const float* __restrict__ query,
    const float* __restrict__ lg, const float* __restrict__ logsum,
    const _Float16* __restrict__ Wm, const float* __restrict__ bias,
    __half* __restrict__ houth) {
  __shared__ __align__(16) __half2 sh[4][256];   // [wave][s*64 + lane]
  const int lane = threadIdx.x & 63;
  const int wid  = threadIdx.x >> 6;
  const int nbase = blockIdx.x * 4;
  const int n = nbase + wid;
  const int b = lane >> 4;
  const int d0 = (lane & 15) * 2;
  const float q0 = query[b * 32 + d0], q1 = query[b * 32 + d0 + 1];
  const int hb = h_index[b];
  const int beg = __builtin_amdgcn_readfirstlane(base[n]);
  const int cnn = __builtin_amdgcn_readfirstlane(cnt[n]);
  const float mb0 = (n == hb) ? q0 : 0.f;
  const float mb1 = (n == hb) ? q1 : 0.f;
  float sa0 = mb0, qa0 = mb0 * mb0, mx0 = mb0, mn0 = mb0;
  float sa1 = mb1, qa1 = mb1 * mb1, mx1 = mb1, mn1 = mb1;
  int matched = 0;
  for (int p = beg; p < beg + cnn; ++p) {
    int2 e = ep[p];
    if ((e.x & 0x7fff) == hb) {
      __half2 rv = rel2[(unsigned)((unsigned)e.x >> 15) * 64 + lane];
      float w = __int_as_float(e.y);
      float2 rf = __half22float2(rv);
      float m0 = rf.x * q0, mw0 = m0 * w;
      float m1 = rf.y * q1, mw1 = m1 * w;
      sa0 += mw0; qa0 = fmaf(m0, mw0, qa0); mx0 = fmaxf(mx0, mw0); mn0 = fminf(mn0, mw0);
      sa1 += mw1; qa1 = fmaf(m1, mw1, qa1); mx1 = fmaxf(mx1, mw1); mn1 = fminf(mn1, mw1);
      ++matched;
    }
  }
  if (matched < cnn) {
    mx0 = fmaxf(mx0, 0.f); mn0 = fminf(mn0, 0.f);
    mx1 = fmaxf(mx1, 0.f); mn1 = fminf(mn1, 0.f);
  }
  const float invc = 1.0f / (float)(cnn + 1);
  const float mean0 = sa0 * invc, mean1 = sa1 * invc;
  const float sd0 = sqrtf(fmaxf(qa0 * invc - mean0 * mean0, EPSF));
  const float sd1 = sqrtf(fmaxf(qa1 * invc - mean1 * mean1, EPSF));
  sh[wid][lane]       = __floats2half2_rn(mean0, mean1);
  sh[wid][64 + lane]  = __floats2half2_rn(mx0, mx1);
  sh[wid][128 + lane] = __floats2half2_rn(mn0, mn1);
  sh[wid][192 + lane] = __floats2half2_rn(sd0, sd1);
  __syncthreads();
  if (threadIdx.x >= 64) return;
  mfma_epilogue((const _Float16*)&sh[0][0], nullptr, houth, lg, logsum,
                Wm, bias, query, h_index, nbase, lane, true);
}

// ---------------- fused generic layer: gather + MFMA linear ----------------
__global__ __launch_bounds__(256) void layer_fused_kernel(
    const __half2* __restrict__ hin2, const __half2* __restrict__ rel2,
    const int2* __restrict__ ep, const int* __restrict__ base,
    const int* __restrict__ cnt, const int* __restrict__ h_index,
    const float* __restrict__ query, const float* __restrict__ lg,
    const float* __restrict__ logsum, const _Float16* __restrict__ Wm,
    const float* __restrict__ bias, __half* __restrict__ houth) {
  __shared__ __align__(16) __half2 sh[4][256];
  const int lane = threadIdx.x & 63;
  const int wid  = threadIdx.x >> 6;
  const int nbase = blockIdx.x * 4;
  const int n = nbase + wid;
  const int b = lane >> 4;
  const int d0 = (lane & 15) * 2;
  const float q0 = query[b * 32 + d0], q1 = query[b * 32 + d0 + 1];
  const int hb = h_index[b];
  const int beg = __builtin_amdgcn_readfirstlane(base[n]);
  const int cnn = __builtin_amdgcn_readfirstlane(cnt[n]);
  const float mb0 = (n == hb) ? q0 : 0.f;
  const float mb1 = (n == hb) ? q1 : 0.f;
  float sa0 = mb0, qa0 = mb0 * mb0, mx0 = mb0, mn0 = mb0;
  float sa1 = mb1, qa1 = mb1 * mb1, mx1 = mb1, mn1 = mb1;

#define PROC(Ez, Hv, Rv) {                                                   \
    float w = __int_as_float(Ez);                                            \
    float2 hf = __half22float2(Hv), rf = __half22float2(Rv);                 \
    float m0 = rf.x * hf.x, mw0 = m0 * w;                                    \
    float m1 = rf.y * hf.y, mw1 = m1 * w;                                    \
    sa0 += mw0; qa0 = fmaf(m0, mw0, qa0);                                    \
    mx0 = fmaxf(mx0, mw0); mn0 = fminf(mn0, mw0);                            \
    sa1 += mw1; qa1 = fmaf(m1, mw1, qa1);                                    \
    mx1 = fmaxf(mx1, mw1); mn1 = fminf(mn1, mw1); }
#define ROWS(Ex, Hd, Rd) {                                                   \
    Hd = hin2[(unsigned)((Ex) & 0x7fff) * 64 + lane];                        \
    Rd = rel2[(unsigned)((unsigned)(Ex) >> 15) * 64 + lane]; }

  int p = beg;
  int rem = cnn;
  const int nb = rem >> 3;
  if (nb > 0) {
    int2 E0, E1, E2, E3, E4, E5, E6, E7;
    __half2 H0, H1, H2, H3, H4, H5, H6, H7;
    __half2 R0, R1, R2, R3, R4, R5, R6, R7;
    E0 = ep[p];     E1 = ep[p + 1]; E2 = ep[p + 2]; E3 = ep[p + 3];
    E4 = ep[p + 4]; E5 = ep[p + 5]; E6 = ep[p + 6]; E7 = ep[p + 7];
    ROWS(E0.x, H0, R0); ROWS(E1.x, H1, R1); ROWS(E2.x, H2, R2); ROWS(E3.x, H3, R3);
    ROWS(E4.x, H4, R4); ROWS(E5.x, H5, R5); ROWS(E6.x, H6, R6); ROWS(E7.x, H7, R7);
    for (int it = 1; it < nb; ++it) {
      const int pn = p + 8;
      int2 F0 = ep[pn],     F1 = ep[pn + 1], F2 = ep[pn + 2], F3 = ep[pn + 3];
      int2 F4 = ep[pn + 4], F5 = ep[pn + 5], F6 = ep[pn + 6], F7 = ep[pn + 7];
      __half2 G0, G1, G2, G3, G4, G5, G6, G7;
      __half2 S0, S1, S2, S3, S4, S5, S6, S7;
      ROWS(F0.x, G0, S0); ROWS(F1.x, G1, S1); ROWS(F2.x, G2, S2); ROWS(F3.x, G3, S3);
      ROWS(F4.x, G4, S4); ROWS(F5.x, G5, S5); ROWS(F6.x, G6, S6); ROWS(F7.x, G7, S7);
      PROC(E0.y, H0, R0); PROC(E1.y, H1, R1); PROC(E2.y, H2, R2); PROC(E3.y, H3, R3);
      PROC(E4.y, H4, R4); PROC(E5.y, H5, R5); PROC(E6.y, H6, R6); PROC(E7.y, H7, R7);
      E0 = F0; E1 = F1; E2 = F2; E3 = F3; E4 = F4; E5 = F5; E6 = F6; E7 = F7;
      H0 = G0; H1 = G1; H2 = G2; H3 = G3; H4 = G4; H5 = G5; H6 = G6; H7 = G7;
      R0 = S0; R1 = S1; R2 = S2; R3 = S3; R4 = S4; R5 = S5; R6 = S6; R7 = S7;
      p = pn;
    }
    PROC(E0.y, H0, R0); PROC(E1.y, H1, R1); PROC(E2.y, H2, R2); PROC(E3.y, H3, R3);
    PROC(E4.y, H4, R4); PROC(E5.y, H5, R5); PROC(E6.y, H6, R6); PROC(E7.y, H7, R7);
    p += 8;
    rem -= nb << 3;
  }
  if (rem >= 4) {
    int2 E0 = ep[p], E1 = ep[p + 1], E2 = ep[p + 2], E3 = ep[p + 3];
    __half2 H0, H1, H2, H3, R0, R1, R2, R3;
    ROWS(E0.x, H0, R0); ROWS(E1.x, H1, R1); ROWS(E2.x, H2, R2); ROWS(E3.x, H3, R3);
    PROC(E0.y, H0, R0); PROC(E1.y, H1, R1); PROC(E2.y, H2, R2); PROC(E3.y, H3, R3);
    p += 4; rem -= 4;
  }
  for (; rem > 0; --rem, ++p) {
    int2 e = ep[p];
    __half2 hv, rv;
    ROWS(e.x, hv, rv);
    PROC(e.y, hv, rv);
  }
#undef ROWS
#undef PROC
  const float invc = 1.0f / (float)(cnn + 1);
  const float mean0 = sa0 * invc, mean1 = sa1 * invc;
  const float sd0 = sqrtf(fmaxf(qa0 * invc - mean0 * mean0, EPSF));
  const float sd1 = sqrtf(fmaxf(qa1 * invc - mean1 * mean1, EPSF));
  sh[wid][lane]       = __floats2half2_rn(mean0, mean1);
  sh[wid][64 + lane]  = __floats2half2_rn(mx0, mx1);
  sh[wid][128 + lane] = __floats2half2_rn(mn0, mn1);
  sh[wid][192 + lane] = __floats2half2_rn(sd0, sd1);
  __syncthreads();
  if (threadIdx.x >= 64) return;
  mfma_epilogue((const _Float16*)&sh[0][0], (const _Float16*)hin2, houth,
                lg, logsum, Wm, bias, query, h_index, nbase, lane, false);
}

// final MLP: [hidden(fp16), query] (64) -> relu(64) -> 1, out[b*N + n]
__global__ __launch_bounds__(128) void mlp_kernel(const __half* __restrict__ hinh,
                                                  const float* __restrict__ query,
                                                  const float* __restrict__ W1,
                                                  const float* __restrict__ b1,
                                                  const float* __restrict__ W2,
                                                  const float* __restrict__ b2,
                                                  float* __restrict__ out) {
  __shared__ float f2[BB][2 * DD];
  const int t = threadIdx.x;
  const int b = t >> 5, d = t & 31;
  const float qv = query[t];
  const float w2a = W2[d], w2b = W2[DD + d];
  const float b1a = b1[d], b1b = b1[DD + d];
  const float b2v = b2[0];
  const int NPBM = 8;
  int n0 = blockIdx.x * NPBM, n1 = min(n0 + NPBM, NN);
  for (int n = n0; n < n1; ++n) {
    f2[b][d]      = __half2float(hinh[(unsigned)n * BD + t]);
    f2[b][DD + d] = qv;
    float a0 = b1a, a1 = b1b;
    #pragma unroll
    for (int i = 0; i < 2 * DD; ++i) {
      float v = f2[b][i];
      a0 = fmaf(v, W1[i * 2 * DD + d], a0);
      a1 = fmaf(v, W1[i * 2 * DD + DD + d], a1);
    }
    a0 = fmaxf(a0, 0.f); a1 = fmaxf(a1, 0.f);
    float part = a0 * w2a + a1 * w2b;
    #pragma unroll
    for (int off = 16; off > 0; off >>= 1) part += __shfl_down(part, off, 32);
    if (d == 0) out[b * NN + n] = part + b2v;
  }
}

extern "C" void kernel_launch(void* const* d_in, const int* in_sizes, int n_in,
                              void* d_out, int out_size, void* d_ws, size_t ws_size,
                              hipStream_t stream) {
  const int*   node_in  = (const int*)d_in[0];
  const int*   node_out = (const int*)d_in[1];
  const int*   relation = (const int*)d_in[2];
  const float* ew       = (const float*)d_in[3];
  const int*   h_index  = (const int*)d_in[4];
  const int*   r_index  = (const int*)d_in[5];
  const float* qemb     = (const float*)d_in[6];
  const float* relW     = (const float*)d_in[7];
  const float* relB     = (const float*)d_in[8];
  const float* linW     = (const float*)d_in[9];
  const float* linB     = (const float*)d_in[10];
  const float* W1       = (const float*)d_in[11];
  const float* b1       = (const float*)d_in[12];
  const float* W2       = (const float*)d_in[13];
  const float* b2       = (const float*)d_in[14];
  float* out = (float*)d_out;

  char* ws = (char*)d_ws;
  size_t off = 0;
  auto alloc = [&](size_t bytes) -> char* {
    char* p = ws + off;
    off += (bytes + 255) & ~(size_t)255;
    return p;
  };
  __half*   h0     = (__half*)  alloc((size_t)NN * BD * 2);
  __half*   h1     = (__half*)  alloc((size_t)NN * BD * 2);
  __half*   relIn  = (__half*)  alloc((size_t)LL * R2C * BD * 2);
  _Float16* Wm     = (_Float16*)alloc((size_t)LL * WMH * 2);
  int2*     ep     = (int2*)    alloc(((size_t)EE + NN) * 8);  // even-aligned segs
  int*      pidx   = (int*)     alloc((size_t)EE * 4);
  int*      base   = (int*)     alloc((size_t)NN * 4);
  int*      cnti   = (int*)     alloc((size_t)NN * 4);
  float*    lg     = (float*)   alloc((size_t)NN * 4);
  float*    query  = (float*)   alloc((size_t)BD * 4);
  float*    stats  = (float*)   alloc(256);   // [0]=logsum (f32), [1]=gcnt (int)

  hipMemsetAsync(cnti, 0, (size_t)NN * 4, stream);
  hipMemsetAsync(stats, 0, 256, stream);

  float* logsum = stats;
  int*   gcnt   = (int*)stats + 1;

  pidx_kernel   <<<(EE / 4 + 255) / 256, 256, 0, stream>>>((const int4*)node_out,
                                                           cnti, (int4*)pidx);
  prep_kernel   <<<(NN + 255) / 256, 256, 0, stream>>>(cnti, base, gcnt);
  scatter_kernel<<<(EE / 4 + 255) / 256, 256, 0, stream>>>(
      (const int4*)node_in, (const int4*)node_out, (const int4*)relation,
      (const float4*)ew, base, (const int4*)pidx, ep);
  wdeg_kernel   <<<(NN + 255) / 256, 256, 0, stream>>>(base, cnti, ep, lg, logsum);
  init_kernel   <<<1, 128, 0, stream>>>(r_index, qemb, query);
  wmbuild_kernel<<<(LL * WMH + 255) / 256, 256, 0, stream>>>(linW, Wm);
  relin_all_kernel<<<(LL * R2C * BD + 255) / 256, 256, 0, stream>>>(query, relW, relB, relIn);

  __half* hin = h0; __half* hout = h1;
  for (int l = 0; l < LL; ++l) {
    if (l == 0) {
      layer1_fused_kernel<<<NN / 4, 256, 0, stream>>>(
          (const __half2*)relIn, ep, base, cnti, h_index, query, lg, logsum,
          Wm, linB, hout);
    } else {
      layer_fused_kernel<<<NN / 4, 256, 0, stream>>>(
          (const __half2*)hin, (const __half2*)relIn + (size_t)l * R2C * 64,
          ep, base, cnti, h_index, query, lg, logsum,
          Wm + (size_t)l * WMH, linB + (size_t)l * DD, hout);
    }
    __half* tmp = hin; hin = hout; hout = tmp;
  }
  mlp_kernel<<<(NN + 7) / 8, 128, 0, stream>>>(hin, query, W1, b1, W2, b2, out);
}